// Round 1
// baseline (1359.035 us; speedup 1.0000x reference)
//
#include <hip/hip_runtime.h>
#include <stdint.h>

#define B_ 4
#define S_ 2048
#define D_ 2048
#define H_ 16
#define DH_ 128

typedef short bf8_t __attribute__((ext_vector_type(8)));   // 8 bf16 (4 VGPRs)
typedef float f4_t  __attribute__((ext_vector_type(4)));   // MFMA C/D

__device__ __forceinline__ unsigned short f2bf(float f) {
  unsigned int x = __float_as_uint(f);
  unsigned int r = (x + 0x7FFFu + ((x >> 16) & 1u)) >> 16;   // RNE
  return (unsigned short)r;
}
__device__ __forceinline__ float bf2f(unsigned short u) {
  return __uint_as_float(((unsigned int)u) << 16);
}

// async global->LDS, 16B per lane. LDS dest must be (wave-uniform base + lane*16).
__device__ __forceinline__ void gload_lds16(const void* g, void* lds) {
  __builtin_amdgcn_global_load_lds(
      (const __attribute__((address_space(1))) unsigned int*)(uintptr_t)g,
      (__attribute__((address_space(3))) unsigned int*)(unsigned int)(uintptr_t)lds,
      16, 0, 0);
}

// ---------------- f32 -> bf16 conversion (x4 vectorized) ----------------
__global__ __launch_bounds__(256) void conv_bf16(const float* __restrict__ in,
                                                 unsigned short* __restrict__ out,
                                                 int n4) {
  int i = blockIdx.x * 256 + threadIdx.x;
  if (i >= n4) return;
  float4 v = ((const float4*)in)[i];
  ushort4 u;
  u.x = f2bf(v.x); u.y = f2bf(v.y); u.z = f2bf(v.z); u.w = f2bf(v.w);
  ((ushort4*)out)[i] = u;
}

// ---------------- GEMM: C[m][n] = sum_k A[m][k] * Bt[n][k]  (both bf16 row-major)
// m97 structure: 128x128 tile, BK=32, 256 thr (4 waves 2x2, each 64x64 = 4x4 frags).
// EPI=0: f32 row-major to Cf.  EPI=1: bf16 scatter into qkv [c][b][h][s][dh] at Cb.
template <int EPI>
__global__ __launch_bounds__(256) void gemm_bt(
    const unsigned short* __restrict__ A, const unsigned short* __restrict__ Bt,
    float* __restrict__ Cf, unsigned short* __restrict__ Cb,
    int M, int N, int K) {
  __shared__ unsigned short As[128 * 32];
  __shared__ unsigned short Bs[128 * 32];
  const int tid  = threadIdx.x;
  const int lane = tid & 63;
  const int wv   = tid >> 6;
  const int wm   = (wv >> 1) * 64;
  const int wn   = (wv & 1) * 64;
  const int bm   = blockIdx.y * 128;
  const int bn   = blockIdx.x * 128;

  f4_t acc[4][4];
#pragma unroll
  for (int i = 0; i < 4; ++i)
#pragma unroll
    for (int j = 0; j < 4; ++j) acc[i][j] = (f4_t){0.f, 0.f, 0.f, 0.f};

  // staging: tile is 128 rows x 32 bf16 (64B/row); thread t copies 16B at linear
  // byte offset (c*256+t)*16  ->  LDS linear == wave-uniform base + lane*16.
  const int ob0 = tid * 16;
  const int ob1 = ob0 + 4096;
  const unsigned short* Ag0 = A + (size_t)(bm + (ob0 >> 6)) * K + ((ob0 & 63) >> 1);
  const unsigned short* Ag1 = A + (size_t)(bm + (ob1 >> 6)) * K + ((ob1 & 63) >> 1);
  const unsigned short* Bg0 = Bt + (size_t)(bn + (ob0 >> 6)) * K + ((ob0 & 63) >> 1);
  const unsigned short* Bg1 = Bt + (size_t)(bn + (ob1 >> 6)) * K + ((ob1 & 63) >> 1);
  char* AsB = (char*)As;
  char* BsB = (char*)Bs;

  const int rsel = lane & 15;
  const int kof  = (lane >> 4) * 8;   // k elem offset within BK=32

  for (int kt = 0; kt < K; kt += 32) {
    gload_lds16(Ag0 + kt, AsB + ob0);
    gload_lds16(Ag1 + kt, AsB + ob1);
    gload_lds16(Bg0 + kt, BsB + ob0);
    gload_lds16(Bg1 + kt, BsB + ob1);
    __syncthreads();   // drains vmcnt(0) before any wave reads LDS

    bf8_t af[4], bfr[4];
#pragma unroll
    for (int i = 0; i < 4; ++i)
      af[i] = *(const bf8_t*)&As[(wm + i * 16 + rsel) * 32 + kof];
#pragma unroll
    for (int j = 0; j < 4; ++j)
      bfr[j] = *(const bf8_t*)&Bs[(wn + j * 16 + rsel) * 32 + kof];
#pragma unroll
    for (int i = 0; i < 4; ++i)
#pragma unroll
      for (int j = 0; j < 4; ++j)
        acc[i][j] = __builtin_amdgcn_mfma_f32_16x16x32_bf16(af[i], bfr[j], acc[i][j], 0, 0, 0);
    __syncthreads();   // protect LDS reuse by next K-step
  }

  const int r0 = (lane >> 4) * 4;
#pragma unroll
  for (int i = 0; i < 4; ++i) {
#pragma unroll
    for (int j = 0; j < 4; ++j) {
#pragma unroll
      for (int r = 0; r < 4; ++r) {
        int row = bm + wm + i * 16 + r0 + r;   // C/D: row=(lane>>4)*4+reg
        int col = bn + wn + j * 16 + rsel;     //      col=lane&15
        float v = acc[i][j][r];
        if (EPI == 0) {
          Cf[(size_t)row * N + col] = v;
        } else {
          int c = col >> 11, h = (col >> 7) & (H_ - 1), dh = col & (DH_ - 1);
          int b = row >> 11, s = row & (S_ - 1);
          size_t dst = ((((size_t)c * B_ + b) * H_ + h) * S_ + s) * DH_ + dh;
          Cb[dst] = f2bf(v);
        }
      }
    }
  }
}

// ---------------- RoPE tables: cos/sin[s][i], i<64, freq = s * 10000^(-i/64)
__global__ void rope_tab(float* __restrict__ tc, float* __restrict__ ts) {
  int s = blockIdx.x;
  int i = threadIdx.x;   // 64 threads
  float inv = powf(10000.0f, -(float)i / 64.0f);
  float f   = (float)s * inv;
  tc[s * 64 + i] = cosf(f);
  ts[s * 64 + i] = sinf(f);
}

// ---------------- RoPE apply in-place on q and k ([b][h][s][dh] bf16)
__global__ __launch_bounds__(256) void rope_apply(
    unsigned short* __restrict__ Q, unsigned short* __restrict__ Kk,
    const float* __restrict__ tc, const float* __restrict__ ts) {
  int idx  = blockIdx.x * 256 + threadIdx.x;   // 2^24 total
  int i    = idx & 63;
  int s    = (idx >> 6) & (S_ - 1);
  int bh   = (idx >> 17) & 63;
  int tsel = idx >> 23;
  unsigned short* T = tsel ? Kk : Q;
  size_t base = ((size_t)bh * S_ + s) * DH_;
  float x1 = bf2f(T[base + i]);
  float x2 = bf2f(T[base + i + 64]);
  float c  = tc[s * 64 + i], sn = ts[s * 64 + i];
  T[base + i]      = f2bf(x1 * c - x2 * sn);
  T[base + i + 64] = f2bf(x2 * c + x1 * sn);
}

// ---------------- causal flash attention
// grid (S/64, B*H), 256 thr. Wave wv owns q rows [q0+16*wv, +16). KVBLK=64.
// Z out layout: [b][s][h*128+dh] bf16 (row-major M x D for the final GEMM).
__global__ __launch_bounds__(256) void attn_fwd(
    const unsigned short* __restrict__ Q, const unsigned short* __restrict__ Kk,
    const unsigned short* __restrict__ V, unsigned short* __restrict__ Z) {
  __shared__ unsigned short Ks[64 * 128];     // K tile row-major [kv][dh]
  __shared__ unsigned short Vt[128 * 64];     // V tile transposed [dh][kv]
  __shared__ unsigned short Pw[4][16 * 64];   // per-wave P (D-layout -> A-layout hop)
  const int tid  = threadIdx.x;
  const int lane = tid & 63;
  const int wv   = tid >> 6;
  const int bh   = blockIdx.y;                // b*H + h
  const int q0   = blockIdx.x * 64;
  const size_t base = (size_t)bh * S_ * DH_;
  const int rsel = lane & 15;
  const int kof  = (lane >> 4) * 8;
  const int qr0  = (lane >> 4) * 4;
  const int qrow = q0 + wv * 16 + rsel;

  bf8_t aq[4];   // Q A-frags over DH=128 (4 k-chunks of 32)
#pragma unroll
  for (int kc = 0; kc < 4; ++kc)
    aq[kc] = *(const bf8_t*)&Q[base + (size_t)qrow * DH_ + kc * 32 + kof];

  f4_t o[8];
#pragma unroll
  for (int nf = 0; nf < 8; ++nf) o[nf] = (f4_t){0.f, 0.f, 0.f, 0.f};
  float mrow[4] = {-3e30f, -3e30f, -3e30f, -3e30f};
  float lrow[4] = {0.f, 0.f, 0.f, 0.f};
  const float scale = 0.08838834764831845f;   // 1/sqrt(128)
  const float l2e   = 1.4426950408889634f;

  for (int kv0 = 0; kv0 < q0 + 64; kv0 += 64) {
    __syncthreads();   // protect K/Vt reuse from previous iteration's readers
    // stage K tile (16KB) via global_load_lds, linear
#pragma unroll
    for (int c = 0; c < 4; ++c) {
      int ob = (c * 256 + tid) * 16;
      int row = ob >> 8, colb = ob & 255;
      gload_lds16(&Kk[base + (size_t)(kv0 + row) * DH_ + (colb >> 1)], (char*)Ks + ob);
    }
    // stage V transposed (reg path; gload_lds can't scatter)
#pragma unroll
    for (int c = 0; c < 4; ++c) {
      int r  = c * 16 + (tid >> 4);
      int c0 = (tid & 15) * 8;
      bf8_t vvv = *(const bf8_t*)&V[base + (size_t)(kv0 + r) * DH_ + c0];
#pragma unroll
      for (int e = 0; e < 8; ++e) Vt[(c0 + e) * 64 + r] = (unsigned short)vvv[e];
    }
    __syncthreads();

    // S = Q K^T : A=Q (m=q,k=dh), B[k=dh][n=kv] = K[kv][dh]
    f4_t sacc[4];
#pragma unroll
    for (int cf = 0; cf < 4; ++cf) sacc[cf] = (f4_t){0.f, 0.f, 0.f, 0.f};
#pragma unroll
    for (int cf = 0; cf < 4; ++cf)
#pragma unroll
      for (int kc = 0; kc < 4; ++kc) {
        bf8_t bk = *(const bf8_t*)&Ks[(cf * 16 + rsel) * 128 + kc * 32 + kof];
        sacc[cf] = __builtin_amdgcn_mfma_f32_16x16x32_bf16(aq[kc], bk, sacc[cf], 0, 0, 0);
      }

    // online softmax (rows live in 16-lane groups; 4 rows/lane via regs)
    float sc[4];
#pragma unroll
    for (int r = 0; r < 4; ++r) {
      const int qabs = q0 + wv * 16 + qr0 + r;
      float tm = -3e30f;
#pragma unroll
      for (int cf = 0; cf < 4; ++cf) {
        int kvabs = kv0 + cf * 16 + rsel;
        float sv = sacc[cf][r] * scale;
        sv = (kvabs <= qabs) ? sv : -3e30f;   // causal mask
        sacc[cf][r] = sv;
        tm = fmaxf(tm, sv);
      }
#pragma unroll
      for (int d = 1; d < 16; d <<= 1) tm = fmaxf(tm, __shfl_xor(tm, d, 16));
      float mn = fmaxf(mrow[r], tm);
      sc[r] = exp2f((mrow[r] - mn) * l2e);
      float ps = 0.f;
#pragma unroll
      for (int cf = 0; cf < 4; ++cf) {
        float p = exp2f((sacc[cf][r] - mn) * l2e);   // masked -> exp(-huge) = 0
        sacc[cf][r] = p;
        ps += p;
      }
#pragma unroll
      for (int d = 1; d < 16; d <<= 1) ps += __shfl_xor(ps, d, 16);
      lrow[r] = lrow[r] * sc[r] + ps;
      mrow[r] = mn;
    }
#pragma unroll
    for (int nf = 0; nf < 8; ++nf)
#pragma unroll
      for (int r = 0; r < 4; ++r) o[nf][r] *= sc[r];

    // P (D-layout) -> per-wave LDS -> A-frags. Same-wave LDS is in-order; the
    // compiler keeps program order through the may-aliasing array accesses.
    unsigned short* P = &Pw[wv][0];
#pragma unroll
    for (int cf = 0; cf < 4; ++cf)
#pragma unroll
      for (int r = 0; r < 4; ++r)
        P[(qr0 + r) * 64 + cf * 16 + rsel] = f2bf(sacc[cf][r]);

    // O += P V : A=P (m=q,k=kv), B[k=kv][n=dh] = V[kv][dh] = Vt[dh][kv]
#pragma unroll
    for (int kc2 = 0; kc2 < 2; ++kc2) {
      bf8_t pa = *(const bf8_t*)&P[rsel * 64 + kc2 * 32 + kof];
#pragma unroll
      for (int nf = 0; nf < 8; ++nf) {
        bf8_t bv = *(const bf8_t*)&Vt[(nf * 16 + rsel) * 64 + kc2 * 32 + kof];
        o[nf] = __builtin_amdgcn_mfma_f32_16x16x32_bf16(pa, bv, o[nf], 0, 0, 0);
      }
    }
  }

  const int b = bh >> 4, h = bh & 15;
#pragma unroll
  for (int r = 0; r < 4; ++r) {
    float inv = 1.0f / lrow[r];
    int s = q0 + wv * 16 + qr0 + r;
    size_t rowo = ((size_t)b * S_ + s) * D_ + h * DH_;
#pragma unroll
    for (int nf = 0; nf < 8; ++nf)
      Z[rowo + nf * 16 + rsel] = f2bf(o[nf][r] * inv);
  }
}

// ---------------- orchestration ----------------
extern "C" void kernel_launch(void* const* d_in, const int* in_sizes, int n_in,
                              void* d_out, int out_size, void* d_ws, size_t ws_size,
                              hipStream_t stream) {
  const float* x    = (const float*)d_in[0];
  const float* Wqkv = (const float*)d_in[1];
  const float* Wo   = (const float*)d_in[2];
  float* out = (float*)d_out;

  const size_t QKV_ELEMS = (size_t)B_ * H_ * S_ * DH_;   // 16,777,216 per tensor
  char* w = (char*)d_ws;
  unsigned short* xb = (unsigned short*)w;   // x bf16 [8192][2048]; z aliases it later
  unsigned short* z  = xb;
  w += (size_t)8192 * 2048 * 2;
  unsigned short* wqkvb = (unsigned short*)w; w += (size_t)6144 * 2048 * 2;
  unsigned short* wob   = (unsigned short*)w; w += (size_t)2048 * 2048 * 2;
  unsigned short* qq = (unsigned short*)w;    w += QKV_ELEMS * 2;
  unsigned short* kk = (unsigned short*)w;    w += QKV_ELEMS * 2;
  unsigned short* vv = (unsigned short*)w;    w += QKV_ELEMS * 2;
  float* tabc = (float*)w; w += (size_t)S_ * 64 * 4;
  float* tabs = (float*)w; w += (size_t)S_ * 64 * 4;
  if ((size_t)(w - (char*)d_ws) > ws_size) return;   // workspace too small: bail cleanly

  // 1) casts to bf16
  conv_bf16<<<16384, 256, 0, stream>>>(x, xb, 8192 * 2048 / 4);
  conv_bf16<<<12288, 256, 0, stream>>>(Wqkv, wqkvb, 6144 * 2048 / 4);
  conv_bf16<<<4096, 256, 0, stream>>>(Wo, wob, 2048 * 2048 / 4);
  // 2) QKV projection, scatter-epilogue into q/k/v [b][h][s][dh]
  gemm_bt<1><<<dim3(48, 64), 256, 0, stream>>>(xb, wqkvb, nullptr, qq, 8192, 6144, 2048);
  // 3) RoPE
  rope_tab<<<2048, 64, 0, stream>>>(tabc, tabs);
  rope_apply<<<65536, 256, 0, stream>>>(qq, kk, tabc, tabs);
  // 4) causal attention -> z [b][s][h*128+dh]
  attn_fwd<<<dim3(S_ / 64, B_ * H_), 256, 0, stream>>>(qq, kk, vv, z);
  // 5) output projection -> f32 d_out
  gemm_bt<0><<<dim3(16, 64), 256, 0, stream>>>(z, wob, out, nullptr, 8192, 2048, 2048);
}

// Round 2
// 924.761 us; speedup vs baseline: 1.4696x; 1.4696x over previous
//
#include <hip/hip_runtime.h>
#include <stdint.h>

#define B_ 4
#define S_ 2048
#define D_ 2048
#define H_ 16
#define DH_ 128

typedef short bf8_t __attribute__((ext_vector_type(8)));   // 8 bf16 (4 VGPRs)
typedef float f4_t  __attribute__((ext_vector_type(4)));   // MFMA C/D

__device__ __forceinline__ unsigned short f2bf(float f) {
  unsigned int x = __float_as_uint(f);
  unsigned int r = (x + 0x7FFFu + ((x >> 16) & 1u)) >> 16;   // RNE
  return (unsigned short)r;
}
__device__ __forceinline__ float bf2f(unsigned short u) {
  return __uint_as_float(((unsigned int)u) << 16);
}

// async global->LDS, 16B per lane. LDS dest must be (wave-uniform base + lane*16).
__device__ __forceinline__ void gload_lds16(const void* g, void* lds) {
  __builtin_amdgcn_global_load_lds(
      (const __attribute__((address_space(1))) unsigned int*)(uintptr_t)g,
      (__attribute__((address_space(3))) unsigned int*)(unsigned int)(uintptr_t)lds,
      16, 0, 0);
}

// ---------------- f32 -> bf16 conversion (x4 vectorized) ----------------
__global__ __launch_bounds__(256) void conv_bf16(const float* __restrict__ in,
                                                 unsigned short* __restrict__ out,
                                                 int n4) {
  int i = blockIdx.x * 256 + threadIdx.x;
  if (i >= n4) return;
  float4 v = ((const float4*)in)[i];
  ushort4 u;
  u.x = f2bf(v.x); u.y = f2bf(v.y); u.z = f2bf(v.z); u.w = f2bf(v.w);
  ((ushort4*)out)[i] = u;
}

// ---------------- GEMM: C[m][n] = sum_k A[m][k] * Bt[n][k]  (both bf16 row-major)
// m97 structure: 128x128 tile, BK=32, 256 thr (4 waves 2x2, each 64x64 = 4x4 frags).
// EPI=0: f32 row-major to Cf.  EPI=1: bf16 scatter into qkv [c][b][h][s][dh] at Cb.
template <int EPI>
__global__ __launch_bounds__(256) void gemm_bt(
    const unsigned short* __restrict__ A, const unsigned short* __restrict__ Bt,
    float* __restrict__ Cf, unsigned short* __restrict__ Cb,
    int M, int N, int K) {
  __shared__ unsigned short As[128 * 32];
  __shared__ unsigned short Bs[128 * 32];
  const int tid  = threadIdx.x;
  const int lane = tid & 63;
  const int wv   = tid >> 6;
  const int wm   = (wv >> 1) * 64;
  const int wn   = (wv & 1) * 64;
  const int bm   = blockIdx.y * 128;
  const int bn   = blockIdx.x * 128;

  f4_t acc[4][4];
#pragma unroll
  for (int i = 0; i < 4; ++i)
#pragma unroll
    for (int j = 0; j < 4; ++j) acc[i][j] = (f4_t){0.f, 0.f, 0.f, 0.f};

  // staging: tile is 128 rows x 32 bf16 (64B/row); thread t copies 16B at linear
  // byte offset (c*256+t)*16  ->  LDS linear == wave-uniform base + lane*16.
  const int ob0 = tid * 16;
  const int ob1 = ob0 + 4096;
  const unsigned short* Ag0 = A + (size_t)(bm + (ob0 >> 6)) * K + ((ob0 & 63) >> 1);
  const unsigned short* Ag1 = A + (size_t)(bm + (ob1 >> 6)) * K + ((ob1 & 63) >> 1);
  const unsigned short* Bg0 = Bt + (size_t)(bn + (ob0 >> 6)) * K + ((ob0 & 63) >> 1);
  const unsigned short* Bg1 = Bt + (size_t)(bn + (ob1 >> 6)) * K + ((ob1 & 63) >> 1);
  char* AsB = (char*)As;
  char* BsB = (char*)Bs;

  const int rsel = lane & 15;
  const int kof  = (lane >> 4) * 8;   // k elem offset within BK=32

  for (int kt = 0; kt < K; kt += 32) {
    gload_lds16(Ag0 + kt, AsB + ob0);
    gload_lds16(Ag1 + kt, AsB + ob1);
    gload_lds16(Bg0 + kt, BsB + ob0);
    gload_lds16(Bg1 + kt, BsB + ob1);
    __syncthreads();   // drains vmcnt(0) before any wave reads LDS

    bf8_t af[4], bfr[4];
#pragma unroll
    for (int i = 0; i < 4; ++i)
      af[i] = *(const bf8_t*)&As[(wm + i * 16 + rsel) * 32 + kof];
#pragma unroll
    for (int j = 0; j < 4; ++j)
      bfr[j] = *(const bf8_t*)&Bs[(wn + j * 16 + rsel) * 32 + kof];
#pragma unroll
    for (int i = 0; i < 4; ++i)
#pragma unroll
      for (int j = 0; j < 4; ++j)
        acc[i][j] = __builtin_amdgcn_mfma_f32_16x16x32_bf16(af[i], bfr[j], acc[i][j], 0, 0, 0);
    __syncthreads();   // protect LDS reuse by next K-step
  }

  const int r0 = (lane >> 4) * 4;
#pragma unroll
  for (int i = 0; i < 4; ++i) {
#pragma unroll
    for (int j = 0; j < 4; ++j) {
#pragma unroll
      for (int r = 0; r < 4; ++r) {
        int row = bm + wm + i * 16 + r0 + r;   // C/D: row=(lane>>4)*4+reg
        int col = bn + wn + j * 16 + rsel;     //      col=lane&15
        float v = acc[i][j][r];
        if (EPI == 0) {
          Cf[(size_t)row * N + col] = v;
        } else {
          int c = col >> 11, h = (col >> 7) & (H_ - 1), dh = col & (DH_ - 1);
          int b = row >> 11, s = row & (S_ - 1);
          size_t dst = ((((size_t)c * B_ + b) * H_ + h) * S_ + s) * DH_ + dh;
          Cb[dst] = f2bf(v);
        }
      }
    }
  }
}

// ---------------- RoPE tables: cos/sin[s][i], i<64, freq = s * 10000^(-i/64)
__global__ void rope_tab(float* __restrict__ tc, float* __restrict__ ts) {
  int s = blockIdx.x;
  int i = threadIdx.x;   // 64 threads
  float inv = powf(10000.0f, -(float)i / 64.0f);
  float f   = (float)s * inv;
  tc[s * 64 + i] = cosf(f);
  ts[s * 64 + i] = sinf(f);
}

// ---------------- RoPE apply in-place on q and k ([b][h][s][dh] bf16)
__global__ __launch_bounds__(256) void rope_apply(
    unsigned short* __restrict__ Q, unsigned short* __restrict__ Kk,
    const float* __restrict__ tc, const float* __restrict__ ts) {
  int idx  = blockIdx.x * 256 + threadIdx.x;   // 2^24 total
  int i    = idx & 63;
  int s    = (idx >> 6) & (S_ - 1);
  int bh   = (idx >> 17) & 63;
  int tsel = idx >> 23;
  unsigned short* T = tsel ? Kk : Q;
  size_t base = ((size_t)bh * S_ + s) * DH_;
  float x1 = bf2f(T[base + i]);
  float x2 = bf2f(T[base + i + 64]);
  float c  = tc[s * 64 + i], sn = ts[s * 64 + i];
  T[base + i]      = f2bf(x1 * c - x2 * sn);
  T[base + i + 64] = f2bf(x2 * c + x1 * sn);
}

// ---------------- causal flash attention
// grid (S/64, B*H), 256 thr. Wave wv owns q rows [q0+16*wv, +16). KVBLK=64.
// Z out layout: [b][s][h*128+dh] bf16 (row-major M x D for the final GEMM).
// All LDS tiles XOR-swizzled (T2): byte colb ^= ((row&7)<<4) to kill the
// 16-way row-stride bank conflicts. Ks is swizzled via pre-swizzled GLOBAL
// source (gload_lds dest must stay linear); Vt/P are reg-path, swizzled direct.
__global__ __launch_bounds__(256) void attn_fwd(
    const unsigned short* __restrict__ Q, const unsigned short* __restrict__ Kk,
    const unsigned short* __restrict__ V, unsigned short* __restrict__ Z) {
  __shared__ unsigned short Ks[64 * 128];     // K tile [kv][dh], swizzled
  __shared__ unsigned short Vt[128 * 64];     // V^T tile [dh][kv], swizzled
  __shared__ unsigned short Pw[4][16 * 64];   // per-wave P, swizzled
  const int tid  = threadIdx.x;
  const int lane = tid & 63;
  const int wv   = tid >> 6;
  const int bh   = blockIdx.y;                // b*H + h
  const int q0   = (gridDim.x - 1 - blockIdx.x) * 64;   // longest blocks first
  const size_t base = (size_t)bh * S_ * DH_;
  const int rsel = lane & 15;
  const int g    = lane >> 4;
  const int kof  = g * 8;
  const int qr0  = g * 4;
  const int qrow = q0 + wv * 16 + rsel;

  bf8_t aq[4];   // Q A-frags over DH=128 (4 k-chunks of 32)
#pragma unroll
  for (int kc = 0; kc < 4; ++kc)
    aq[kc] = *(const bf8_t*)&Q[base + (size_t)qrow * DH_ + kc * 32 + kof];

  f4_t o[8];
#pragma unroll
  for (int nf = 0; nf < 8; ++nf) o[nf] = (f4_t){0.f, 0.f, 0.f, 0.f};
  float mrow[4] = {-3e30f, -3e30f, -3e30f, -3e30f};
  float lrow[4] = {0.f, 0.f, 0.f, 0.f};
  const float scale = 0.08838834764831845f;   // 1/sqrt(128)
  const float l2e   = 1.4426950408889634f;

  for (int kv0 = 0; kv0 < q0 + 64; kv0 += 64) {
    __syncthreads();   // protect K/Vt reuse from previous iteration's readers
    // stage K tile (16KB) via global_load_lds; LDS dest linear, global source
    // pre-swizzled so LDS content is the swizzled layout (rule #21 / m173).
#pragma unroll
    for (int c = 0; c < 4; ++c) {
      int ob   = (c * 256 + tid) * 16;      // linear LDS dest byte
      int row  = ob >> 8;
      int scol = (ob & 255) ^ ((row & 7) << 4);   // involution
      gload_lds16(&Kk[base + (size_t)(kv0 + row) * DH_ + (scol >> 1)], (char*)Ks + ob);
    }
    // stage V transposed (reg path), swizzled write; rotate element order so
    // per-instruction writes span 8 swizzle slots (else 16-way write conflict).
#pragma unroll
    for (int c = 0; c < 4; ++c) {
      int r  = c * 16 + (tid >> 4);
      int c0 = (tid & 15) * 8;
      bf8_t vvv = *(const bf8_t*)&V[base + (size_t)(kv0 + r) * DH_ + c0];
#pragma unroll
      for (int e = 0; e < 8; ++e) {
        int ee = (e + (tid & 15)) & 7;
        int dh = c0 + ee;
        Vt[dh * 64 + (r ^ ((dh & 7) << 3))] = (unsigned short)vvv[ee];
      }
    }
    __syncthreads();

    // S = Q K^T : A=Q (m=q,k=dh), B[k=dh][n=kv] = K[kv][dh]
    f4_t sacc[4];
#pragma unroll
    for (int cf = 0; cf < 4; ++cf) sacc[cf] = (f4_t){0.f, 0.f, 0.f, 0.f};
#pragma unroll
    for (int cf = 0; cf < 4; ++cf)
#pragma unroll
      for (int kc = 0; kc < 4; ++kc) {
        int krow = cf * 16 + rsel;
        bf8_t bk = *(const bf8_t*)&Ks[krow * 128 + ((kc * 32 + kof) ^ ((krow & 7) << 3))];
        sacc[cf] = __builtin_amdgcn_mfma_f32_16x16x32_bf16(aq[kc], bk, sacc[cf], 0, 0, 0);
      }

    // online softmax (rows live in 16-lane groups; 4 rows/lane via regs)
    float sc[4];
#pragma unroll
    for (int r = 0; r < 4; ++r) {
      const int qabs = q0 + wv * 16 + qr0 + r;
      float tm = -3e30f;
#pragma unroll
      for (int cf = 0; cf < 4; ++cf) {
        int kvabs = kv0 + cf * 16 + rsel;
        float sv = sacc[cf][r] * scale;
        sv = (kvabs <= qabs) ? sv : -3e30f;   // causal mask
        sacc[cf][r] = sv;
        tm = fmaxf(tm, sv);
      }
#pragma unroll
      for (int d = 1; d < 16; d <<= 1) tm = fmaxf(tm, __shfl_xor(tm, d, 16));
      float mn = fmaxf(mrow[r], tm);
      sc[r] = exp2f((mrow[r] - mn) * l2e);
      float ps = 0.f;
#pragma unroll
      for (int cf = 0; cf < 4; ++cf) {
        float p = exp2f((sacc[cf][r] - mn) * l2e);   // masked -> exp(-huge) = 0
        sacc[cf][r] = p;
        ps += p;
      }
#pragma unroll
      for (int d = 1; d < 16; d <<= 1) ps += __shfl_xor(ps, d, 16);
      lrow[r] = lrow[r] * sc[r] + ps;
      mrow[r] = mn;
    }
#pragma unroll
    for (int nf = 0; nf < 8; ++nf)
#pragma unroll
      for (int r = 0; r < 4; ++r) o[nf][r] *= sc[r];

    // P (D-layout) -> per-wave LDS (swizzled) -> A-frags.
    unsigned short* P = &Pw[wv][0];
#pragma unroll
    for (int cf = 0; cf < 4; ++cf)
#pragma unroll
      for (int r = 0; r < 4; ++r) {
        int prow = qr0 + r;
        P[prow * 64 + ((cf * 16 + rsel) ^ ((prow & 7) << 3))] = f2bf(sacc[cf][r]);
      }

    // O += P V : A=P (m=q,k=kv), B[k=kv][n=dh] = V[kv][dh] = Vt[dh][kv]
#pragma unroll
    for (int kc2 = 0; kc2 < 2; ++kc2) {
      bf8_t pa = *(const bf8_t*)&P[rsel * 64 + ((kc2 * 32 + kof) ^ ((rsel & 7) << 3))];
#pragma unroll
      for (int nf = 0; nf < 8; ++nf) {
        int vrow = nf * 16 + rsel;
        bf8_t bv = *(const bf8_t*)&Vt[vrow * 64 + ((kc2 * 32 + kof) ^ ((vrow & 7) << 3))];
        o[nf] = __builtin_amdgcn_mfma_f32_16x16x32_bf16(pa, bv, o[nf], 0, 0, 0);
      }
    }
  }

  const int b = bh >> 4, h = bh & 15;
#pragma unroll
  for (int r = 0; r < 4; ++r) {
    float inv = 1.0f / lrow[r];
    int s = q0 + wv * 16 + qr0 + r;
    size_t rowo = ((size_t)b * S_ + s) * D_ + h * DH_;
#pragma unroll
    for (int nf = 0; nf < 8; ++nf)
      Z[rowo + nf * 16 + rsel] = f2bf(o[nf][r] * inv);
  }
}

// ---------------- orchestration ----------------
extern "C" void kernel_launch(void* const* d_in, const int* in_sizes, int n_in,
                              void* d_out, int out_size, void* d_ws, size_t ws_size,
                              hipStream_t stream) {
  const float* x    = (const float*)d_in[0];
  const float* Wqkv = (const float*)d_in[1];
  const float* Wo   = (const float*)d_in[2];
  float* out = (float*)d_out;

  const size_t QKV_ELEMS = (size_t)B_ * H_ * S_ * DH_;   // 16,777,216 per tensor
  char* w = (char*)d_ws;
  unsigned short* xb = (unsigned short*)w;   // x bf16 [8192][2048]; z aliases it later
  unsigned short* z  = xb;
  w += (size_t)8192 * 2048 * 2;
  unsigned short* wqkvb = (unsigned short*)w; w += (size_t)6144 * 2048 * 2;
  unsigned short* wob   = (unsigned short*)w; w += (size_t)2048 * 2048 * 2;
  unsigned short* qq = (unsigned short*)w;    w += QKV_ELEMS * 2;
  unsigned short* kk = (unsigned short*)w;    w += QKV_ELEMS * 2;
  unsigned short* vv = (unsigned short*)w;    w += QKV_ELEMS * 2;
  float* tabc = (float*)w; w += (size_t)S_ * 64 * 4;
  float* tabs = (float*)w; w += (size_t)S_ * 64 * 4;
  if ((size_t)(w - (char*)d_ws) > ws_size) return;   // workspace too small: bail cleanly

  // 1) casts to bf16
  conv_bf16<<<16384, 256, 0, stream>>>(x, xb, 8192 * 2048 / 4);
  conv_bf16<<<12288, 256, 0, stream>>>(Wqkv, wqkvb, 6144 * 2048 / 4);
  conv_bf16<<<4096, 256, 0, stream>>>(Wo, wob, 2048 * 2048 / 4);
  // 2) QKV projection, scatter-epilogue into q/k/v [b][h][s][dh]
  gemm_bt<1><<<dim3(48, 64), 256, 0, stream>>>(xb, wqkvb, nullptr, qq, 8192, 6144, 2048);
  // 3) RoPE
  rope_tab<<<2048, 64, 0, stream>>>(tabc, tabs);
  rope_apply<<<65536, 256, 0, stream>>>(qq, kk, tabc, tabs);
  // 4) causal attention -> z [b][s][h*128+dh]
  attn_fwd<<<dim3(S_ / 64, B_ * H_), 256, 0, stream>>>(qq, kk, vv, z);
  // 5) output projection -> f32 d_out
  gemm_bt<0><<<dim3(16, 64), 256, 0, stream>>>(z, wob, out, nullptr, 8192, 2048, 2048);
}

// Round 4
// 873.471 us; speedup vs baseline: 1.5559x; 1.0587x over previous
//
#include <hip/hip_runtime.h>
#include <hip/hip_bf16.h>
#include <stdint.h>

#define B_ 4
#define S_ 2048
#define D_ 2048
#define H_ 16
#define DH_ 128

typedef short bf8_t __attribute__((ext_vector_type(8)));   // 8 bf16 (4 VGPRs)
typedef float f4_t  __attribute__((ext_vector_type(4)));   // MFMA C/D

__device__ __forceinline__ unsigned short f2bf(float f) {
  __hip_bfloat16 h = __float2bfloat16(f);   // RNE
  return *reinterpret_cast<const unsigned short*>(&h);
}
__device__ __forceinline__ float bf2f(unsigned short u) {
  return __uint_as_float(((unsigned int)u) << 16);
}

// async global->LDS, 16B per lane. LDS dest must be (wave-uniform base + lane*16).
__device__ __forceinline__ void gload_lds16(const void* g, void* lds) {
  __builtin_amdgcn_global_load_lds(
      (const __attribute__((address_space(1))) unsigned int*)(uintptr_t)g,
      (__attribute__((address_space(3))) unsigned int*)(unsigned int)(uintptr_t)lds,
      16, 0, 0);
}

// ---------------- f32 -> bf16 conversion (x4 vectorized) ----------------
__global__ __launch_bounds__(256) void conv_bf16(const float* __restrict__ in,
                                                 unsigned short* __restrict__ out,
                                                 int n4) {
  int i = blockIdx.x * 256 + threadIdx.x;
  if (i >= n4) return;
  float4 v = ((const float4*)in)[i];
  ushort4 u;
  u.x = f2bf(v.x); u.y = f2bf(v.y); u.z = f2bf(v.z); u.w = f2bf(v.w);
  ((ushort4*)out)[i] = u;
}

// ---------------- GEMM: C[m][n] = sum_k A[m][k] * Bt[n][k]  (both bf16 row-major)
// m97 structure: 128x128 tile, BK=32, 256 thr (4 waves 2x2, each 64x64 = 4x4 frags).
// EPI=0: f32 row-major to Cf.  EPI=1: bf16 scatter into qkv [c][b][h][s][dh] at Cb.
template <int EPI>
__global__ __launch_bounds__(256) void gemm_bt(
    const unsigned short* __restrict__ A, const unsigned short* __restrict__ Bt,
    float* __restrict__ Cf, unsigned short* __restrict__ Cb,
    int M, int N, int K) {
  __shared__ unsigned short As[128 * 32];
  __shared__ unsigned short Bs[128 * 32];
  const int tid  = threadIdx.x;
  const int lane = tid & 63;
  const int wv   = tid >> 6;
  const int wm   = (wv >> 1) * 64;
  const int wn   = (wv & 1) * 64;
  const int bm   = blockIdx.y * 128;
  const int bn   = blockIdx.x * 128;

  f4_t acc[4][4];
#pragma unroll
  for (int i = 0; i < 4; ++i)
#pragma unroll
    for (int j = 0; j < 4; ++j) acc[i][j] = (f4_t){0.f, 0.f, 0.f, 0.f};

  const int ob0 = tid * 16;
  const int ob1 = ob0 + 4096;
  const unsigned short* Ag0 = A + (size_t)(bm + (ob0 >> 6)) * K + ((ob0 & 63) >> 1);
  const unsigned short* Ag1 = A + (size_t)(bm + (ob1 >> 6)) * K + ((ob1 & 63) >> 1);
  const unsigned short* Bg0 = Bt + (size_t)(bn + (ob0 >> 6)) * K + ((ob0 & 63) >> 1);
  const unsigned short* Bg1 = Bt + (size_t)(bn + (ob1 >> 6)) * K + ((ob1 & 63) >> 1);
  char* AsB = (char*)As;
  char* BsB = (char*)Bs;

  const int rsel = lane & 15;
  const int kof  = (lane >> 4) * 8;

  for (int kt = 0; kt < K; kt += 32) {
    gload_lds16(Ag0 + kt, AsB + ob0);
    gload_lds16(Ag1 + kt, AsB + ob1);
    gload_lds16(Bg0 + kt, BsB + ob0);
    gload_lds16(Bg1 + kt, BsB + ob1);
    __syncthreads();

    bf8_t af[4], bfr[4];
#pragma unroll
    for (int i = 0; i < 4; ++i)
      af[i] = *(const bf8_t*)&As[(wm + i * 16 + rsel) * 32 + kof];
#pragma unroll
    for (int j = 0; j < 4; ++j)
      bfr[j] = *(const bf8_t*)&Bs[(wn + j * 16 + rsel) * 32 + kof];
#pragma unroll
    for (int i = 0; i < 4; ++i)
#pragma unroll
      for (int j = 0; j < 4; ++j)
        acc[i][j] = __builtin_amdgcn_mfma_f32_16x16x32_bf16(af[i], bfr[j], acc[i][j], 0, 0, 0);
    __syncthreads();
  }

  const int r0 = (lane >> 4) * 4;
#pragma unroll
  for (int i = 0; i < 4; ++i) {
#pragma unroll
    for (int j = 0; j < 4; ++j) {
#pragma unroll
      for (int r = 0; r < 4; ++r) {
        int row = bm + wm + i * 16 + r0 + r;   // C/D: row=(lane>>4)*4+reg
        int col = bn + wn + j * 16 + rsel;     //      col=lane&15
        float v = acc[i][j][r];
        if (EPI == 0) {
          Cf[(size_t)row * N + col] = v;
        } else {
          int c = col >> 11, h = (col >> 7) & (H_ - 1), dh = col & (DH_ - 1);
          int b = row >> 11, s = row & (S_ - 1);
          size_t dst = ((((size_t)c * B_ + b) * H_ + h) * S_ + s) * DH_ + dh;
          Cb[dst] = f2bf(v);
        }
      }
    }
  }
}

// ---------------- RoPE tables ----------------
__global__ void rope_tab(float* __restrict__ tc, float* __restrict__ ts) {
  int s = blockIdx.x;
  int i = threadIdx.x;   // 64 threads
  float inv = powf(10000.0f, -(float)i / 64.0f);
  float f   = (float)s * inv;
  tc[s * 64 + i] = cosf(f);
  ts[s * 64 + i] = sinf(f);
}

// ---------------- RoPE apply in-place on q and k ([b][h][s][dh] bf16)
__global__ __launch_bounds__(256) void rope_apply(
    unsigned short* __restrict__ Q, unsigned short* __restrict__ Kk,
    const float* __restrict__ tc, const float* __restrict__ ts) {
  int idx  = blockIdx.x * 256 + threadIdx.x;   // 2^24 total
  int i    = idx & 63;
  int s    = (idx >> 6) & (S_ - 1);
  int bh   = (idx >> 17) & 63;
  int tsel = idx >> 23;
  unsigned short* T = tsel ? Kk : Q;
  size_t base = ((size_t)bh * S_ + s) * DH_;
  float x1 = bf2f(T[base + i]);
  float x2 = bf2f(T[base + i + 64]);
  float c  = tc[s * 64 + i], sn = ts[s * 64 + i];
  T[base + i]      = f2bf(x1 * c - x2 * sn);
  T[base + i + 64] = f2bf(x2 * c + x1 * sn);
}

// ---------------- causal flash attention ----------------
// grid (S/64, B*H), 256 thr = 4 waves x 16 q-rows. KVBLK=64.
// K,V double-buffered. Per iter t: issue V(t+1)->regs and K(t+1)->LDS at top
// (latency hides under compute), QK^T -> softmax(defer-max, log2 domain) ->
// Vt[nxt] ds_write -> PV -> __syncthreads (drains vmcnt0/lgkm0: K landed).
__global__ __launch_bounds__(256) void attn_fwd(
    const unsigned short* __restrict__ Q, const unsigned short* __restrict__ Kk,
    const unsigned short* __restrict__ V, unsigned short* __restrict__ Z) {
  __shared__ unsigned short Ks[2][64 * 128];  // 32 KB, XOR-swizzled (src-side)
  __shared__ unsigned short Vt[2][128 * 64];  // 32 KB, [dh][kv], XOR-swizzled
  __shared__ unsigned short Pw[4][16 * 64];   // 8 KB, per-wave, swizzled
  const int tid  = threadIdx.x;
  const int lane = tid & 63;
  const int wv   = tid >> 6;
  const int bh   = blockIdx.y;
  const int q0   = (gridDim.x - 1 - blockIdx.x) * 64;   // longest blocks first
  const size_t base = (size_t)bh * S_ * DH_;
  const int rsel = lane & 15;
  const int g    = lane >> 4;
  const int kof  = g * 8;
  const int qr0  = g * 4;
  const int qrow = q0 + wv * 16 + rsel;

  bf8_t aq[4];
#pragma unroll
  for (int kc = 0; kc < 4; ++kc)
    aq[kc] = *(const bf8_t*)&Q[base + (size_t)qrow * DH_ + kc * 32 + kof];

  f4_t o[8];
#pragma unroll
  for (int nf = 0; nf < 8; ++nf) o[nf] = (f4_t){0.f, 0.f, 0.f, 0.f};
  float mrow[4] = {-3e30f, -3e30f, -3e30f, -3e30f};
  float lrow[4] = {0.f, 0.f, 0.f, 0.f};
  const float sl2 = 0.08838834764831845f * 1.4426950408889634f;  // scale*log2(e)
  const int nt = q0 / 64 + 1;

  // V staging geometry (reg path): 4 rows per thread, 8 cols each
  const int vr_r = tid >> 4;          // row-within-16
  const int vc0  = (tid & 15) * 8;    // col base

  // ---- prologue: V(0)->regs, K(0)->Ks[0]; write Vt[0]; sync ----
  bf8_t vr[4];
#pragma unroll
  for (int c = 0; c < 4; ++c)
    vr[c] = *(const bf8_t*)&V[base + (size_t)(c * 16 + vr_r) * DH_ + vc0];
#pragma unroll
  for (int c = 0; c < 4; ++c) {
    int ob = (c * 256 + tid) * 16;
    int row = ob >> 8;
    int scol = (ob & 255) ^ ((row & 7) << 4);
    gload_lds16(Kk + base + (size_t)row * DH_ + (scol >> 1), (char*)&Ks[0][0] + ob);
  }
#pragma unroll
  for (int c = 0; c < 4; ++c) {
    int r = c * 16 + vr_r;
#pragma unroll
    for (int e = 0; e < 8; ++e) {
      int ee = (e + (tid & 15)) & 7;
      int dh = vc0 + ee;
      Vt[0][dh * 64 + (r ^ ((dh & 7) << 3))] = (unsigned short)vr[c][ee];
    }
  }
  __syncthreads();

  for (int t = 0; t < nt; ++t) {
    const int cur = t & 1;
    const int kv0 = t * 64;
    const bool diag = (t == nt - 1);
    const bool pf   = (t + 1 < nt);

    // ---- issue next tile's loads (V->regs first, then K->LDS) ----
    if (pf) {
      const unsigned short* gV = V + base + (size_t)(kv0 + 64) * DH_;
#pragma unroll
      for (int c = 0; c < 4; ++c)
        vr[c] = *(const bf8_t*)&gV[(size_t)(c * 16 + vr_r) * DH_ + vc0];
      const unsigned short* gK = Kk + base + (size_t)(kv0 + 64) * DH_;
#pragma unroll
      for (int c = 0; c < 4; ++c) {
        int ob = (c * 256 + tid) * 16;
        int row = ob >> 8;
        int scol = (ob & 255) ^ ((row & 7) << 4);
        gload_lds16(gK + (size_t)row * DH_ + (scol >> 1), (char*)&Ks[cur ^ 1][0] + ob);
      }
    }

    // ---- S = Q K^T ----
    f4_t sacc[4];
#pragma unroll
    for (int cf = 0; cf < 4; ++cf) sacc[cf] = (f4_t){0.f, 0.f, 0.f, 0.f};
    __builtin_amdgcn_s_setprio(1);
#pragma unroll
    for (int cf = 0; cf < 4; ++cf)
#pragma unroll
      for (int kc = 0; kc < 4; ++kc) {
        int krow = cf * 16 + rsel;
        bf8_t bk = *(const bf8_t*)&Ks[cur][krow * 128 + ((kc * 32 + kof) ^ ((krow & 7) << 3))];
        sacc[cf] = __builtin_amdgcn_mfma_f32_16x16x32_bf16(aq[kc], bk, sacc[cf], 0, 0, 0);
      }
    __builtin_amdgcn_s_setprio(0);

    // scale into log2 domain; causal mask only on the diagonal tile
#pragma unroll
    for (int cf = 0; cf < 4; ++cf)
#pragma unroll
      for (int r = 0; r < 4; ++r) sacc[cf][r] *= sl2;
    if (diag) {
#pragma unroll
      for (int cf = 0; cf < 4; ++cf) {
        int kvabs = kv0 + cf * 16 + rsel;
#pragma unroll
        for (int r = 0; r < 4; ++r) {
          int qabs = q0 + wv * 16 + qr0 + r;
          if (kvabs > qabs) sacc[cf][r] = -3e30f;
        }
      }
    }

    // ---- online softmax, defer-max (T13, THR=11 in log2 domain) ----
    float tm[4];
#pragma unroll
    for (int r = 0; r < 4; ++r) {
      float a = fmaxf(sacc[0][r], sacc[1][r]);
      float b = fmaxf(sacc[2][r], sacc[3][r]);
      float m = fmaxf(a, b);
#pragma unroll
      for (int d = 1; d < 16; d <<= 1) m = fmaxf(m, __shfl_xor(m, d, 16));
      tm[r] = m;
    }
    bool needr = (tm[0] > mrow[0] + 11.f) || (tm[1] > mrow[1] + 11.f) ||
                 (tm[2] > mrow[2] + 11.f) || (tm[3] > mrow[3] + 11.f);
    if (__any(needr)) {   // rare after the first tile
#pragma unroll
      for (int r = 0; r < 4; ++r) {
        float nm = fmaxf(mrow[r], tm[r]);
        float sc = exp2f(mrow[r] - nm);
        lrow[r] *= sc;
        mrow[r] = nm;
#pragma unroll
        for (int nf = 0; nf < 8; ++nf) o[nf][r] *= sc;
      }
    }
#pragma unroll
    for (int r = 0; r < 4; ++r) {
      float ps = 0.f;
#pragma unroll
      for (int cf = 0; cf < 4; ++cf) {
        float p = exp2f(sacc[cf][r] - mrow[r]);   // bounded by 2^11
        sacc[cf][r] = p;
        ps += p;
      }
#pragma unroll
      for (int d = 1; d < 16; d <<= 1) ps += __shfl_xor(ps, d, 16);
      lrow[r] += ps;
    }

    // ---- P -> per-wave LDS (swizzled) ----
    unsigned short* P = &Pw[wv][0];
#pragma unroll
    for (int cf = 0; cf < 4; ++cf)
#pragma unroll
      for (int r = 0; r < 4; ++r) {
        int prow = qr0 + r;
        P[prow * 64 + ((cf * 16 + rsel) ^ ((prow & 7) << 3))] = f2bf(sacc[cf][r]);
      }

    // ---- write V(t+1) into Vt[nxt] (compiler waits vr's loads only) ----
    if (pf) {
      unsigned short* Vn = &Vt[cur ^ 1][0];
#pragma unroll
      for (int c = 0; c < 4; ++c) {
        int r = c * 16 + vr_r;
#pragma unroll
        for (int e = 0; e < 8; ++e) {
          int ee = (e + (tid & 15)) & 7;
          int dh = vc0 + ee;
          Vn[dh * 64 + (r ^ ((dh & 7) << 3))] = (unsigned short)vr[c][ee];
        }
      }
    }

    // ---- O += P V  (reads Pw + Vt[cur]) ----
    __builtin_amdgcn_s_setprio(1);
#pragma unroll
    for (int kc2 = 0; kc2 < 2; ++kc2) {
      bf8_t pa = *(const bf8_t*)&P[rsel * 64 + ((kc2 * 32 + kof) ^ ((rsel & 7) << 3))];
#pragma unroll
      for (int nf = 0; nf < 8; ++nf) {
        int vrow = nf * 16 + rsel;
        bf8_t bv = *(const bf8_t*)&Vt[cur][vrow * 64 + ((kc2 * 32 + kof) ^ ((vrow & 7) << 3))];
        o[nf] = __builtin_amdgcn_mfma_f32_16x16x32_bf16(pa, bv, o[nf], 0, 0, 0);
      }
    }
    __builtin_amdgcn_s_setprio(0);

    // ---- end of iter: drains vmcnt(0) (K(t+1) landed) + lgkm, sync ----
    __syncthreads();
  }

  const int b = bh >> 4, h = bh & 15;
#pragma unroll
  for (int r = 0; r < 4; ++r) {
    float inv = 1.0f / lrow[r];
    int s = q0 + wv * 16 + qr0 + r;
    size_t rowo = ((size_t)b * S_ + s) * D_ + h * DH_;
#pragma unroll
    for (int nf = 0; nf < 8; ++nf)
      Z[rowo + nf * 16 + rsel] = f2bf(o[nf][r] * inv);
  }
}

// ---------------- orchestration ----------------
extern "C" void kernel_launch(void* const* d_in, const int* in_sizes, int n_in,
                              void* d_out, int out_size, void* d_ws, size_t ws_size,
                              hipStream_t stream) {
  const float* x    = (const float*)d_in[0];
  const float* Wqkv = (const float*)d_in[1];
  const float* Wo   = (const float*)d_in[2];
  float* out = (float*)d_out;

  const size_t QKV_ELEMS = (size_t)B_ * H_ * S_ * DH_;
  char* w = (char*)d_ws;
  unsigned short* xb = (unsigned short*)w;   // x bf16; z aliases it later
  unsigned short* z  = xb;
  w += (size_t)8192 * 2048 * 2;
  unsigned short* wqkvb = (unsigned short*)w; w += (size_t)6144 * 2048 * 2;
  unsigned short* wob   = (unsigned short*)w; w += (size_t)2048 * 2048 * 2;
  unsigned short* qq = (unsigned short*)w;    w += QKV_ELEMS * 2;
  unsigned short* kk = (unsigned short*)w;    w += QKV_ELEMS * 2;
  unsigned short* vv = (unsigned short*)w;    w += QKV_ELEMS * 2;
  float* tabc = (float*)w; w += (size_t)S_ * 64 * 4;
  float* tabs = (float*)w; w += (size_t)S_ * 64 * 4;
  if ((size_t)(w - (char*)d_ws) > ws_size) return;

  conv_bf16<<<16384, 256, 0, stream>>>(x, xb, 8192 * 2048 / 4);
  conv_bf16<<<12288, 256, 0, stream>>>(Wqkv, wqkvb, 6144 * 2048 / 4);
  conv_bf16<<<4096, 256, 0, stream>>>(Wo, wob, 2048 * 2048 / 4);
  gemm_bt<1><<<dim3(48, 64), 256, 0, stream>>>(xb, wqkvb, nullptr, qq, 8192, 6144, 2048);
  rope_tab<<<2048, 64, 0, stream>>>(tabc, tabs);
  rope_apply<<<65536, 256, 0, stream>>>(qq, kk, tabc, tabs);
  attn_fwd<<<dim3(S_ / 64, B_ * H_), 256, 0, stream>>>(qq, kk, vv, z);
  gemm_bt<0><<<dim3(16, 64), 256, 0, stream>>>(z, wob, out, nullptr, 8192, 2048, 2048);
}

// Round 5
// 785.973 us; speedup vs baseline: 1.7291x; 1.1113x over previous
//
#include <hip/hip_runtime.h>
#include <hip/hip_bf16.h>
#include <stdint.h>

#define B_ 4
#define S_ 2048
#define D_ 2048
#define H_ 16
#define DH_ 128

typedef short bf8_t __attribute__((ext_vector_type(8)));   // 8 bf16 (4 VGPRs)
typedef float f4_t  __attribute__((ext_vector_type(4)));   // MFMA C/D

__device__ __forceinline__ unsigned short f2bf(float f) {
  __hip_bfloat16 h = __float2bfloat16(f);   // RNE
  return *reinterpret_cast<const unsigned short*>(&h);
}
__device__ __forceinline__ float bf2f(unsigned short u) {
  return __uint_as_float(((unsigned int)u) << 16);
}

// async global->LDS, 16B per lane. LDS dest must be (wave-uniform base + lane*16).
__device__ __forceinline__ void gload_lds16(const void* g, void* lds) {
  __builtin_amdgcn_global_load_lds(
      (const __attribute__((address_space(1))) unsigned int*)(uintptr_t)g,
      (__attribute__((address_space(3))) unsigned int*)(unsigned int)(uintptr_t)lds,
      16, 0, 0);
}

// ---------------- f32 -> bf16 conversion (x4 vectorized) ----------------
__global__ __launch_bounds__(256) void conv_bf16(const float* __restrict__ in,
                                                 unsigned short* __restrict__ out,
                                                 int n4) {
  int i = blockIdx.x * 256 + threadIdx.x;
  if (i >= n4) return;
  float4 v = ((const float4*)in)[i];
  ushort4 u;
  u.x = f2bf(v.x); u.y = f2bf(v.y); u.z = f2bf(v.z); u.w = f2bf(v.w);
  ((ushort4*)out)[i] = u;
}

// ---------------- GEMM: C[m][n] = sum_k A[m][k] * Bt[n][k]  (both bf16 row-major)
template <int EPI>
__global__ __launch_bounds__(256) void gemm_bt(
    const unsigned short* __restrict__ A, const unsigned short* __restrict__ Bt,
    float* __restrict__ Cf, unsigned short* __restrict__ Cb,
    int M, int N, int K) {
  __shared__ unsigned short As[128 * 32];
  __shared__ unsigned short Bs[128 * 32];
  const int tid  = threadIdx.x;
  const int lane = tid & 63;
  const int wv   = tid >> 6;
  const int wm   = (wv >> 1) * 64;
  const int wn   = (wv & 1) * 64;
  const int bm   = blockIdx.y * 128;
  const int bn   = blockIdx.x * 128;

  f4_t acc[4][4];
#pragma unroll
  for (int i = 0; i < 4; ++i)
#pragma unroll
    for (int j = 0; j < 4; ++j) acc[i][j] = (f4_t){0.f, 0.f, 0.f, 0.f};

  const int ob0 = tid * 16;
  const int ob1 = ob0 + 4096;
  const unsigned short* Ag0 = A + (size_t)(bm + (ob0 >> 6)) * K + ((ob0 & 63) >> 1);
  const unsigned short* Ag1 = A + (size_t)(bm + (ob1 >> 6)) * K + ((ob1 & 63) >> 1);
  const unsigned short* Bg0 = Bt + (size_t)(bn + (ob0 >> 6)) * K + ((ob0 & 63) >> 1);
  const unsigned short* Bg1 = Bt + (size_t)(bn + (ob1 >> 6)) * K + ((ob1 & 63) >> 1);
  char* AsB = (char*)As;
  char* BsB = (char*)Bs;

  const int rsel = lane & 15;
  const int kof  = (lane >> 4) * 8;

  for (int kt = 0; kt < K; kt += 32) {
    gload_lds16(Ag0 + kt, AsB + ob0);
    gload_lds16(Ag1 + kt, AsB + ob1);
    gload_lds16(Bg0 + kt, BsB + ob0);
    gload_lds16(Bg1 + kt, BsB + ob1);
    __syncthreads();

    bf8_t af[4], bfr[4];
#pragma unroll
    for (int i = 0; i < 4; ++i)
      af[i] = *(const bf8_t*)&As[(wm + i * 16 + rsel) * 32 + kof];
#pragma unroll
    for (int j = 0; j < 4; ++j)
      bfr[j] = *(const bf8_t*)&Bs[(wn + j * 16 + rsel) * 32 + kof];
#pragma unroll
    for (int i = 0; i < 4; ++i)
#pragma unroll
      for (int j = 0; j < 4; ++j)
        acc[i][j] = __builtin_amdgcn_mfma_f32_16x16x32_bf16(af[i], bfr[j], acc[i][j], 0, 0, 0);
    __syncthreads();
  }

  const int r0 = (lane >> 4) * 4;
#pragma unroll
  for (int i = 0; i < 4; ++i) {
#pragma unroll
    for (int j = 0; j < 4; ++j) {
#pragma unroll
      for (int r = 0; r < 4; ++r) {
        int row = bm + wm + i * 16 + r0 + r;   // C/D: row=(lane>>4)*4+reg
        int col = bn + wn + j * 16 + rsel;     //      col=lane&15
        float v = acc[i][j][r];
        if (EPI == 0) {
          Cf[(size_t)row * N + col] = v;
        } else {
          int c = col >> 11, h = (col >> 7) & (H_ - 1), dh = col & (DH_ - 1);
          int b = row >> 11, s = row & (S_ - 1);
          size_t dst = ((((size_t)c * B_ + b) * H_ + h) * S_ + s) * DH_ + dh;
          Cb[dst] = f2bf(v);
        }
      }
    }
  }
}

// ---------------- RoPE tables ----------------
__global__ void rope_tab(float* __restrict__ tc, float* __restrict__ ts) {
  int s = blockIdx.x;
  int i = threadIdx.x;   // 64 threads
  float inv = powf(10000.0f, -(float)i / 64.0f);
  float f   = (float)s * inv;
  tc[s * 64 + i] = cosf(f);
  ts[s * 64 + i] = sinf(f);
}

// ---------------- RoPE apply in-place on q and k ([b][h][s][dh] bf16)
__global__ __launch_bounds__(256) void rope_apply(
    unsigned short* __restrict__ Q, unsigned short* __restrict__ Kk,
    const float* __restrict__ tc, const float* __restrict__ ts) {
  int idx  = blockIdx.x * 256 + threadIdx.x;   // 2^24 total
  int i    = idx & 63;
  int s    = (idx >> 6) & (S_ - 1);
  int bh   = (idx >> 17) & 63;
  int tsel = idx >> 23;
  unsigned short* T = tsel ? Kk : Q;
  size_t base = ((size_t)bh * S_ + s) * DH_;
  float x1 = bf2f(T[base + i]);
  float x2 = bf2f(T[base + i + 64]);
  float c  = tc[s * 64 + i], sn = ts[s * 64 + i];
  T[base + i]      = f2bf(x1 * c - x2 * sn);
  T[base + i + 64] = f2bf(x2 * c + x1 * sn);
}

// ---------------- causal flash attention ----------------
// grid (S/64, B*H), 256 thr = 4 waves x 16 q-rows. KVBLK=64.
// K,V double-buffered. V staged as kv-PAIR u32 packs (static extracts,
// conflict-free b32 writes). P swizzle ((prow>>1)<<3): conflict-free writes,
// 2-way reads. Q pre-scaled by scale*log2(e) at prologue.
__global__ __launch_bounds__(256) void attn_fwd(
    const unsigned short* __restrict__ Q, const unsigned short* __restrict__ Kk,
    const unsigned short* __restrict__ V, unsigned short* __restrict__ Z) {
  __shared__ unsigned short Ks[2][64 * 128];  // 32 KB, XOR-swizzled (src-side)
  __shared__ unsigned short Vt[2][128 * 64];  // 32 KB, [dh][kv], XOR-swizzled
  __shared__ unsigned short Pw[4][16 * 64];   // 8 KB, per-wave, swizzled
  const int tid  = threadIdx.x;
  const int lane = tid & 63;
  const int wv   = tid >> 6;
  const int bh   = blockIdx.y;
  const int q0   = (gridDim.x - 1 - blockIdx.x) * 64;   // longest blocks first
  const size_t base = (size_t)bh * S_ * DH_;
  const int rsel = lane & 15;
  const int g    = lane >> 4;
  const int kof  = g * 8;
  const int qr0  = g * 4;
  const int qrow = q0 + wv * 16 + rsel;
  const float sl2 = 0.08838834764831845f * 1.4426950408889634f;  // scale*log2(e)

  // Q A-frags, pre-scaled by sl2 (folds the per-iter scale pass into prologue)
  bf8_t aq[4];
#pragma unroll
  for (int kc = 0; kc < 4; ++kc) {
    aq[kc] = *(const bf8_t*)&Q[base + (size_t)qrow * DH_ + kc * 32 + kof];
#pragma unroll
    for (int e = 0; e < 8; ++e)
      aq[kc][e] = (short)f2bf(bf2f((unsigned short)aq[kc][e]) * sl2);
  }

  f4_t o[8];
#pragma unroll
  for (int nf = 0; nf < 8; ++nf) o[nf] = (f4_t){0.f, 0.f, 0.f, 0.f};
  float mrow[4] = {-3e30f, -3e30f, -3e30f, -3e30f};
  float lrow[4] = {0.f, 0.f, 0.f, 0.f};
  const int nt = q0 / 64 + 1;

  // V staging geometry: unit id = u*256+tid covers kv rows {2*kvp, 2*kvp+1} x
  // dh [c0, c0+8). Packs pairs into u32 -> Vt32[dh*32 + (kvp ^ (e<<2))].
  const int kvp = tid & 31;
  const int vch = tid >> 5;   // chunk base; unit u adds 8

  bf8_t vlo[2], vhi[2];
#pragma unroll
  for (int u = 0; u < 2; ++u) {
    int c0 = (u * 8 + vch) * 8;
    vlo[u] = *(const bf8_t*)&V[base + (size_t)(2 * kvp) * DH_ + c0];
    vhi[u] = *(const bf8_t*)&V[base + (size_t)(2 * kvp + 1) * DH_ + c0];
  }
#pragma unroll
  for (int c = 0; c < 4; ++c) {
    int ob = (c * 256 + tid) * 16;
    int row = ob >> 8;
    int scol = (ob & 255) ^ ((row & 7) << 4);
    gload_lds16(Kk + base + (size_t)row * DH_ + (scol >> 1), (char*)&Ks[0][0] + ob);
  }
  {
    unsigned int* Vt32 = (unsigned int*)&Vt[0][0];
#pragma unroll
    for (int u = 0; u < 2; ++u) {
      int c0 = (u * 8 + vch) * 8;
#pragma unroll
      for (int e = 0; e < 8; ++e) {
        unsigned int val = (unsigned short)vlo[u][e] |
                           ((unsigned int)(unsigned short)vhi[u][e] << 16);
        Vt32[(c0 + e) * 32 + (kvp ^ (e << 2))] = val;
      }
    }
  }
  __syncthreads();

  for (int t = 0; t < nt; ++t) {
    const int cur = t & 1;
    const int kv0 = t * 64;
    const bool diag = (t == nt - 1);
    const bool pf   = (t + 1 < nt);

    // ---- issue next tile's loads (V->regs first, then K->LDS) ----
    if (pf) {
      const unsigned short* gV = V + base + (size_t)(kv0 + 64) * DH_;
#pragma unroll
      for (int u = 0; u < 2; ++u) {
        int c0 = (u * 8 + vch) * 8;
        vlo[u] = *(const bf8_t*)&gV[(size_t)(2 * kvp) * DH_ + c0];
        vhi[u] = *(const bf8_t*)&gV[(size_t)(2 * kvp + 1) * DH_ + c0];
      }
      const unsigned short* gK = Kk + base + (size_t)(kv0 + 64) * DH_;
#pragma unroll
      for (int c = 0; c < 4; ++c) {
        int ob = (c * 256 + tid) * 16;
        int row = ob >> 8;
        int scol = (ob & 255) ^ ((row & 7) << 4);
        gload_lds16(gK + (size_t)row * DH_ + (scol >> 1), (char*)&Ks[cur ^ 1][0] + ob);
      }
    }

    // ---- S = Q K^T  (Q pre-scaled, result already in log2 domain) ----
    f4_t sacc[4];
#pragma unroll
    for (int cf = 0; cf < 4; ++cf) sacc[cf] = (f4_t){0.f, 0.f, 0.f, 0.f};
    __builtin_amdgcn_s_setprio(1);
#pragma unroll
    for (int cf = 0; cf < 4; ++cf)
#pragma unroll
      for (int kc = 0; kc < 4; ++kc) {
        int krow = cf * 16 + rsel;
        bf8_t bk = *(const bf8_t*)&Ks[cur][krow * 128 + ((kc * 32 + kof) ^ ((krow & 7) << 3))];
        sacc[cf] = __builtin_amdgcn_mfma_f32_16x16x32_bf16(aq[kc], bk, sacc[cf], 0, 0, 0);
      }
    __builtin_amdgcn_s_setprio(0);

    // causal mask only on the diagonal tile
    if (diag) {
#pragma unroll
      for (int cf = 0; cf < 4; ++cf) {
        int kvabs = kv0 + cf * 16 + rsel;
#pragma unroll
        for (int r = 0; r < 4; ++r) {
          int qabs = q0 + wv * 16 + qr0 + r;
          if (kvabs > qabs) sacc[cf][r] = -3e30f;
        }
      }
    }

    // ---- online softmax, defer-max (T13, THR=11 in log2 domain) ----
    float tm[4];
#pragma unroll
    for (int r = 0; r < 4; ++r) {
      float a = fmaxf(sacc[0][r], sacc[1][r]);
      float b = fmaxf(sacc[2][r], sacc[3][r]);
      float m = fmaxf(a, b);
#pragma unroll
      for (int d = 1; d < 16; d <<= 1) m = fmaxf(m, __shfl_xor(m, d, 16));
      tm[r] = m;
    }
    bool needr = (tm[0] > mrow[0] + 11.f) || (tm[1] > mrow[1] + 11.f) ||
                 (tm[2] > mrow[2] + 11.f) || (tm[3] > mrow[3] + 11.f);
    if (__any(needr)) {   // rare after the first tile
#pragma unroll
      for (int r = 0; r < 4; ++r) {
        float nm = fmaxf(mrow[r], tm[r]);
        float sc = exp2f(mrow[r] - nm);
        lrow[r] *= sc;
        mrow[r] = nm;
#pragma unroll
        for (int nf = 0; nf < 8; ++nf) o[nf][r] *= sc;
      }
    }
#pragma unroll
    for (int r = 0; r < 4; ++r) {
      float ps = 0.f;
#pragma unroll
      for (int cf = 0; cf < 4; ++cf) {
        float p = exp2f(sacc[cf][r] - mrow[r]);   // bounded by 2^11
        sacc[cf][r] = p;
        ps += p;
      }
#pragma unroll
      for (int d = 1; d < 16; d <<= 1) ps += __shfl_xor(ps, d, 16);
      lrow[r] += ps;
    }

    // ---- P -> per-wave LDS (swizzle ((prow>>1)<<3): conflict-free) ----
    unsigned short* P = &Pw[wv][0];
#pragma unroll
    for (int cf = 0; cf < 4; ++cf)
#pragma unroll
      for (int r = 0; r < 4; ++r) {
        int prow = qr0 + r;
        P[prow * 64 + ((cf * 16 + rsel) ^ ((prow >> 1) << 3))] = f2bf(sacc[cf][r]);
      }

    // ---- write V(t+1) into Vt[nxt] (u32 pair-packs, conflict-free) ----
    if (pf) {
      unsigned int* Vt32 = (unsigned int*)&Vt[cur ^ 1][0];
#pragma unroll
      for (int u = 0; u < 2; ++u) {
        int c0 = (u * 8 + vch) * 8;
#pragma unroll
        for (int e = 0; e < 8; ++e) {
          unsigned int val = (unsigned short)vlo[u][e] |
                             ((unsigned int)(unsigned short)vhi[u][e] << 16);
          Vt32[(c0 + e) * 32 + (kvp ^ (e << 2))] = val;
        }
      }
    }

    // ---- O += P V  (reads Pw + Vt[cur]) ----
    __builtin_amdgcn_s_setprio(1);
#pragma unroll
    for (int kc2 = 0; kc2 < 2; ++kc2) {
      bf8_t pa = *(const bf8_t*)&P[rsel * 64 + ((kc2 * 32 + kof) ^ ((rsel >> 1) << 3))];
#pragma unroll
      for (int nf = 0; nf < 8; ++nf) {
        int vrow = nf * 16 + rsel;
        bf8_t bv = *(const bf8_t*)&Vt[cur][vrow * 64 + ((kc2 * 32 + kof) ^ ((vrow & 7) << 3))];
        o[nf] = __builtin_amdgcn_mfma_f32_16x16x32_bf16(pa, bv, o[nf], 0, 0, 0);
      }
    }
    __builtin_amdgcn_s_setprio(0);

    // ---- end of iter: drains vmcnt(0) (K(t+1) landed) + lgkm, sync ----
    __syncthreads();
  }

  const int b = bh >> 4, h = bh & 15;
#pragma unroll
  for (int r = 0; r < 4; ++r) {
    float inv = 1.0f / lrow[r];
    int s = q0 + wv * 16 + qr0 + r;
    size_t rowo = ((size_t)b * S_ + s) * D_ + h * DH_;
#pragma unroll
    for (int nf = 0; nf < 8; ++nf)
      Z[rowo + nf * 16 + rsel] = f2bf(o[nf][r] * inv);
  }
}

// ---------------- orchestration ----------------
extern "C" void kernel_launch(void* const* d_in, const int* in_sizes, int n_in,
                              void* d_out, int out_size, void* d_ws, size_t ws_size,
                              hipStream_t stream) {
  const float* x    = (const float*)d_in[0];
  const float* Wqkv = (const float*)d_in[1];
  const float* Wo   = (const float*)d_in[2];
  float* out = (float*)d_out;

  const size_t QKV_ELEMS = (size_t)B_ * H_ * S_ * DH_;
  char* w = (char*)d_ws;
  unsigned short* xb = (unsigned short*)w;   // x bf16; z aliases it later
  unsigned short* z  = xb;
  w += (size_t)8192 * 2048 * 2;
  unsigned short* wqkvb = (unsigned short*)w; w += (size_t)6144 * 2048 * 2;
  unsigned short* wob   = (unsigned short*)w; w += (size_t)2048 * 2048 * 2;
  unsigned short* qq = (unsigned short*)w;    w += QKV_ELEMS * 2;
  unsigned short* kk = (unsigned short*)w;    w += QKV_ELEMS * 2;
  unsigned short* vv = (unsigned short*)w;    w += QKV_ELEMS * 2;
  float* tabc = (float*)w; w += (size_t)S_ * 64 * 4;
  float* tabs = (float*)w; w += (size_t)S_ * 64 * 4;
  if ((size_t)(w - (char*)d_ws) > ws_size) return;

  conv_bf16<<<16384, 256, 0, stream>>>(x, xb, 8192 * 2048 / 4);
  conv_bf16<<<12288, 256, 0, stream>>>(Wqkv, wqkvb, 6144 * 2048 / 4);
  conv_bf16<<<4096, 256, 0, stream>>>(Wo, wob, 2048 * 2048 / 4);
  gemm_bt<1><<<dim3(48, 64), 256, 0, stream>>>(xb, wqkvb, nullptr, qq, 8192, 6144, 2048);
  rope_tab<<<2048, 64, 0, stream>>>(tabc, tabs);
  rope_apply<<<65536, 256, 0, stream>>>(qq, kk, tabc, tabs);
  attn_fwd<<<dim3(S_ / 64, B_ * H_), 256, 0, stream>>>(qq, kk, vv, z);
  gemm_bt<0><<<dim3(16, 64), 256, 0, stream>>>(z, wob, out, nullptr, 8192, 2048, 2048);
}

// Round 6
// 683.719 us; speedup vs baseline: 1.9877x; 1.1496x over previous
//
#include <hip/hip_runtime.h>
#include <hip/hip_bf16.h>
#include <stdint.h>

#define B_ 4
#define S_ 2048
#define D_ 2048
#define H_ 16
#define DH_ 128

typedef short bf8_t __attribute__((ext_vector_type(8)));   // 8 bf16 (4 VGPRs)
typedef float f4_t  __attribute__((ext_vector_type(4)));   // MFMA C/D

__device__ __forceinline__ unsigned short f2bf(float f) {
  __hip_bfloat16 h = __float2bfloat16(f);   // RNE
  return *reinterpret_cast<const unsigned short*>(&h);
}
__device__ __forceinline__ float bf2f(unsigned short u) {
  return __uint_as_float(((unsigned int)u) << 16);
}

// async global->LDS, 16B per lane. LDS dest must be (wave-uniform base + lane*16).
__device__ __forceinline__ void gload_lds16(const void* g, void* lds) {
  __builtin_amdgcn_global_load_lds(
      (const __attribute__((address_space(1))) unsigned int*)(uintptr_t)g,
      (__attribute__((address_space(3))) unsigned int*)(unsigned int)(uintptr_t)lds,
      16, 0, 0);
}

// ---------------- f32 -> bf16 conversion (x4 vectorized) ----------------
__global__ __launch_bounds__(256) void conv_bf16(const float* __restrict__ in,
                                                 unsigned short* __restrict__ out,
                                                 int n4) {
  int i = blockIdx.x * 256 + threadIdx.x;
  if (i >= n4) return;
  float4 v = ((const float4*)in)[i];
  ushort4 u;
  u.x = f2bf(v.x); u.y = f2bf(v.y); u.z = f2bf(v.z); u.w = f2bf(v.w);
  ((ushort4*)out)[i] = u;
}

// ---------------- GEMM: C[m][n] = sum_k A[m][k] * Bt[n][k]  (both bf16 row-major)
template <int EPI>
__global__ __launch_bounds__(256) void gemm_bt(
    const unsigned short* __restrict__ A, const unsigned short* __restrict__ Bt,
    float* __restrict__ Cf, unsigned short* __restrict__ Cb,
    int M, int N, int K) {
  __shared__ unsigned short As[128 * 32];
  __shared__ unsigned short Bs[128 * 32];
  const int tid  = threadIdx.x;
  const int lane = tid & 63;
  const int wv   = tid >> 6;
  const int wm   = (wv >> 1) * 64;
  const int wn   = (wv & 1) * 64;
  const int bm   = blockIdx.y * 128;
  const int bn   = blockIdx.x * 128;

  f4_t acc[4][4];
#pragma unroll
  for (int i = 0; i < 4; ++i)
#pragma unroll
    for (int j = 0; j < 4; ++j) acc[i][j] = (f4_t){0.f, 0.f, 0.f, 0.f};

  const int ob0 = tid * 16;
  const int ob1 = ob0 + 4096;
  const unsigned short* Ag0 = A + (size_t)(bm + (ob0 >> 6)) * K + ((ob0 & 63) >> 1);
  const unsigned short* Ag1 = A + (size_t)(bm + (ob1 >> 6)) * K + ((ob1 & 63) >> 1);
  const unsigned short* Bg0 = Bt + (size_t)(bn + (ob0 >> 6)) * K + ((ob0 & 63) >> 1);
  const unsigned short* Bg1 = Bt + (size_t)(bn + (ob1 >> 6)) * K + ((ob1 & 63) >> 1);
  char* AsB = (char*)As;
  char* BsB = (char*)Bs;

  const int rsel = lane & 15;
  const int kof  = (lane >> 4) * 8;

  for (int kt = 0; kt < K; kt += 32) {
    gload_lds16(Ag0 + kt, AsB + ob0);
    gload_lds16(Ag1 + kt, AsB + ob1);
    gload_lds16(Bg0 + kt, BsB + ob0);
    gload_lds16(Bg1 + kt, BsB + ob1);
    __syncthreads();

    bf8_t af[4], bfr[4];
#pragma unroll
    for (int i = 0; i < 4; ++i)
      af[i] = *(const bf8_t*)&As[(wm + i * 16 + rsel) * 32 + kof];
#pragma unroll
    for (int j = 0; j < 4; ++j)
      bfr[j] = *(const bf8_t*)&Bs[(wn + j * 16 + rsel) * 32 + kof];
#pragma unroll
    for (int i = 0; i < 4; ++i)
#pragma unroll
      for (int j = 0; j < 4; ++j)
        acc[i][j] = __builtin_amdgcn_mfma_f32_16x16x32_bf16(af[i], bfr[j], acc[i][j], 0, 0, 0);
    __syncthreads();
  }

  const int r0 = (lane >> 4) * 4;
#pragma unroll
  for (int i = 0; i < 4; ++i) {
#pragma unroll
    for (int j = 0; j < 4; ++j) {
#pragma unroll
      for (int r = 0; r < 4; ++r) {
        int row = bm + wm + i * 16 + r0 + r;   // C/D: row=(lane>>4)*4+reg
        int col = bn + wn + j * 16 + rsel;     //      col=lane&15
        float v = acc[i][j][r];
        if (EPI == 0) {
          Cf[(size_t)row * N + col] = v;
        } else {
          int c = col >> 11, h = (col >> 7) & (H_ - 1), dh = col & (DH_ - 1);
          int b = row >> 11, s = row & (S_ - 1);
          size_t dst = ((((size_t)c * B_ + b) * H_ + h) * S_ + s) * DH_ + dh;
          Cb[dst] = f2bf(v);
        }
      }
    }
  }
}

// ---------------- RoPE tables ----------------
__global__ void rope_tab(float* __restrict__ tc, float* __restrict__ ts) {
  int s = blockIdx.x;
  int i = threadIdx.x;   // 64 threads
  float inv = powf(10000.0f, -(float)i / 64.0f);
  float f   = (float)s * inv;
  tc[s * 64 + i] = cosf(f);
  ts[s * 64 + i] = sinf(f);
}

// ---------------- RoPE apply in-place on q and k ([b][h][s][dh] bf16)
__global__ __launch_bounds__(256) void rope_apply(
    unsigned short* __restrict__ Q, unsigned short* __restrict__ Kk,
    const float* __restrict__ tc, const float* __restrict__ ts) {
  int idx  = blockIdx.x * 256 + threadIdx.x;   // 2^24 total
  int i    = idx & 63;
  int s    = (idx >> 6) & (S_ - 1);
  int bh   = (idx >> 17) & 63;
  int tsel = idx >> 23;
  unsigned short* T = tsel ? Kk : Q;
  size_t base = ((size_t)bh * S_ + s) * DH_;
  float x1 = bf2f(T[base + i]);
  float x2 = bf2f(T[base + i + 64]);
  float c  = tc[s * 64 + i], sn = ts[s * 64 + i];
  T[base + i]      = f2bf(x1 * c - x2 * sn);
  T[base + i + 64] = f2bf(x2 * c + x1 * sn);
}

// ---------------- causal flash attention ----------------
// grid (S/64, B*H), 256 thr = 4 waves x 16 q-rows. KVBLK=64.
// K,V double-buffered, prefetch at iter top. Softmax: Q pre-scaled into log2
// domain; denominator via ones-column MFMA (o[8]); defer-max with common-path
// max-tree skip (only per-lane cmps + __any; full 16-lane tree on rare trip).
__global__ __launch_bounds__(256) void attn_fwd(
    const unsigned short* __restrict__ Q, const unsigned short* __restrict__ Kk,
    const unsigned short* __restrict__ V, unsigned short* __restrict__ Z) {
  __shared__ unsigned short Ks[2][64 * 128];  // 32 KB, XOR-swizzled (src-side)
  __shared__ unsigned short Vt[2][128 * 64];  // 32 KB, [dh][kv], XOR-swizzled
  __shared__ unsigned short Pw[4][16 * 64];   // 8 KB, per-wave, swizzled
  const int tid  = threadIdx.x;
  const int lane = tid & 63;
  const int wv   = tid >> 6;
  const int bh   = blockIdx.y;
  const int q0   = (gridDim.x - 1 - blockIdx.x) * 64;   // longest blocks first
  const size_t base = (size_t)bh * S_ * DH_;
  const int rsel = lane & 15;
  const int g    = lane >> 4;
  const int kof  = g * 8;
  const int qr0  = g * 4;
  const int qrow = q0 + wv * 16 + rsel;
  const float sl2 = 0.08838834764831845f * 1.4426950408889634f;  // scale*log2(e)

  // Q A-frags, pre-scaled by sl2
  bf8_t aq[4];
#pragma unroll
  for (int kc = 0; kc < 4; ++kc) {
    aq[kc] = *(const bf8_t*)&Q[base + (size_t)qrow * DH_ + kc * 32 + kof];
#pragma unroll
    for (int e = 0; e < 8; ++e)
      aq[kc][e] = (short)f2bf(bf2f((unsigned short)aq[kc][e]) * sl2);
  }

  // ones B-frag for the denominator MFMA (bf16 1.0 = 0x3F80)
  bf8_t vones;
#pragma unroll
  for (int e = 0; e < 8; ++e) vones[e] = (short)0x3F80;

  f4_t o[9];   // o[0..7] = output frags, o[8] = row-sum (softmax denom)
#pragma unroll
  for (int nf = 0; nf < 9; ++nf) o[nf] = (f4_t){0.f, 0.f, 0.f, 0.f};
  float mrow[4] = {-3e30f, -3e30f, -3e30f, -3e30f};
  const int nt = q0 / 64 + 1;

  // V staging geometry: unit u*256+tid covers kv rows {2*kvp,2*kvp+1} x 8 dh.
  const int kvp = tid & 31;
  const int vch = tid >> 5;

  bf8_t vlo[2], vhi[2];
#pragma unroll
  for (int u = 0; u < 2; ++u) {
    int c0 = (u * 8 + vch) * 8;
    vlo[u] = *(const bf8_t*)&V[base + (size_t)(2 * kvp) * DH_ + c0];
    vhi[u] = *(const bf8_t*)&V[base + (size_t)(2 * kvp + 1) * DH_ + c0];
  }
#pragma unroll
  for (int c = 0; c < 4; ++c) {
    int ob = (c * 256 + tid) * 16;
    int row = ob >> 8;
    int scol = (ob & 255) ^ ((row & 7) << 4);
    gload_lds16(Kk + base + (size_t)row * DH_ + (scol >> 1), (char*)&Ks[0][0] + ob);
  }
  {
    unsigned int* Vt32 = (unsigned int*)&Vt[0][0];
#pragma unroll
    for (int u = 0; u < 2; ++u) {
      int c0 = (u * 8 + vch) * 8;
#pragma unroll
      for (int e = 0; e < 8; ++e) {
        unsigned int val = (unsigned short)vlo[u][e] |
                           ((unsigned int)(unsigned short)vhi[u][e] << 16);
        Vt32[(c0 + e) * 32 + (kvp ^ (e << 2))] = val;
      }
    }
  }
  __syncthreads();

  for (int t = 0; t < nt; ++t) {
    const int cur = t & 1;
    const int kv0 = t * 64;
    const bool diag = (t == nt - 1);
    const bool pf   = (t + 1 < nt);

    // ---- issue next tile's loads (V->regs first, then K->LDS) ----
    if (pf) {
      const unsigned short* gV = V + base + (size_t)(kv0 + 64) * DH_;
#pragma unroll
      for (int u = 0; u < 2; ++u) {
        int c0 = (u * 8 + vch) * 8;
        vlo[u] = *(const bf8_t*)&gV[(size_t)(2 * kvp) * DH_ + c0];
        vhi[u] = *(const bf8_t*)&gV[(size_t)(2 * kvp + 1) * DH_ + c0];
      }
      const unsigned short* gK = Kk + base + (size_t)(kv0 + 64) * DH_;
#pragma unroll
      for (int c = 0; c < 4; ++c) {
        int ob = (c * 256 + tid) * 16;
        int row = ob >> 8;
        int scol = (ob & 255) ^ ((row & 7) << 4);
        gload_lds16(gK + (size_t)row * DH_ + (scol >> 1), (char*)&Ks[cur ^ 1][0] + ob);
      }
    }

    // ---- S = Q K^T  (Q pre-scaled: result in log2 domain) ----
    f4_t sacc[4];
#pragma unroll
    for (int cf = 0; cf < 4; ++cf) sacc[cf] = (f4_t){0.f, 0.f, 0.f, 0.f};
    __builtin_amdgcn_s_setprio(1);
#pragma unroll
    for (int cf = 0; cf < 4; ++cf)
#pragma unroll
      for (int kc = 0; kc < 4; ++kc) {
        int krow = cf * 16 + rsel;
        bf8_t bk = *(const bf8_t*)&Ks[cur][krow * 128 + ((kc * 32 + kof) ^ ((krow & 7) << 3))];
        sacc[cf] = __builtin_amdgcn_mfma_f32_16x16x32_bf16(aq[kc], bk, sacc[cf], 0, 0, 0);
      }
    __builtin_amdgcn_s_setprio(0);

    // causal mask only on the diagonal tile
    if (diag) {
#pragma unroll
      for (int cf = 0; cf < 4; ++cf) {
        int kvabs = kv0 + cf * 16 + rsel;
#pragma unroll
        for (int r = 0; r < 4; ++r) {
          int qabs = q0 + wv * 16 + qr0 + r;
          if (kvabs > qabs) sacc[cf][r] = -3e30f;
        }
      }
    }

    // ---- defer-max softmax: common path has NO cross-lane reduction ----
    float tmr[4];
#pragma unroll
    for (int r = 0; r < 4; ++r)
      tmr[r] = fmaxf(fmaxf(sacc[0][r], sacc[1][r]), fmaxf(sacc[2][r], sacc[3][r]));
    bool needr = (tmr[0] > mrow[0] + 11.f) || (tmr[1] > mrow[1] + 11.f) ||
                 (tmr[2] > mrow[2] + 11.f) || (tmr[3] > mrow[3] + 11.f);
    if (__any(needr)) {   // first tile, then ~never
#pragma unroll
      for (int r = 0; r < 4; ++r) {
        float m = tmr[r];
#pragma unroll
        for (int d = 1; d < 16; d <<= 1) m = fmaxf(m, __shfl_xor(m, d, 16));
        float nm = fmaxf(mrow[r], m);
        float sc = exp2f(mrow[r] - nm);
        mrow[r] = nm;
#pragma unroll
        for (int nf = 0; nf < 9; ++nf) o[nf][r] *= sc;
      }
    }
#pragma unroll
    for (int cf = 0; cf < 4; ++cf)
#pragma unroll
      for (int r = 0; r < 4; ++r)
        sacc[cf][r] = exp2f(sacc[cf][r] - mrow[r]);   // bounded by 2^11

    // ---- P -> per-wave LDS (swizzle ((prow>>1)<<3)) ----
    unsigned short* P = &Pw[wv][0];
#pragma unroll
    for (int cf = 0; cf < 4; ++cf)
#pragma unroll
      for (int r = 0; r < 4; ++r) {
        int prow = qr0 + r;
        P[prow * 64 + ((cf * 16 + rsel) ^ ((prow >> 1) << 3))] = f2bf(sacc[cf][r]);
      }

    // ---- write V(t+1) into Vt[nxt] (u32 pair-packs) ----
    if (pf) {
      unsigned int* Vt32 = (unsigned int*)&Vt[cur ^ 1][0];
#pragma unroll
      for (int u = 0; u < 2; ++u) {
        int c0 = (u * 8 + vch) * 8;
#pragma unroll
        for (int e = 0; e < 8; ++e) {
          unsigned int val = (unsigned short)vlo[u][e] |
                             ((unsigned int)(unsigned short)vhi[u][e] << 16);
          Vt32[(c0 + e) * 32 + (kvp ^ (e << 2))] = val;
        }
      }
    }

    // ---- O += P V ; denominator rides as o[8] = P x ones ----
    __builtin_amdgcn_s_setprio(1);
#pragma unroll
    for (int kc2 = 0; kc2 < 2; ++kc2) {
      bf8_t pa = *(const bf8_t*)&P[rsel * 64 + ((kc2 * 32 + kof) ^ ((rsel >> 1) << 3))];
#pragma unroll
      for (int nf = 0; nf < 8; ++nf) {
        int vrow = nf * 16 + rsel;
        bf8_t bv = *(const bf8_t*)&Vt[cur][vrow * 64 + ((kc2 * 32 + kof) ^ ((vrow & 7) << 3))];
        o[nf] = __builtin_amdgcn_mfma_f32_16x16x32_bf16(pa, bv, o[nf], 0, 0, 0);
      }
      o[8] = __builtin_amdgcn_mfma_f32_16x16x32_bf16(pa, vones, o[8], 0, 0, 0);
    }
    __builtin_amdgcn_s_setprio(0);

    // ---- end of iter: drains vmcnt(0) (K(t+1) landed) + lgkm, sync ----
    __syncthreads();
  }

  const int b = bh >> 4, h = bh & 15;
#pragma unroll
  for (int r = 0; r < 4; ++r) {
    float inv = 1.0f / o[8][r];
    int s = q0 + wv * 16 + qr0 + r;
    size_t rowo = ((size_t)b * S_ + s) * D_ + h * DH_;
#pragma unroll
    for (int nf = 0; nf < 8; ++nf)
      Z[rowo + nf * 16 + rsel] = f2bf(o[nf][r] * inv);
  }
}

// ---------------- orchestration ----------------
extern "C" void kernel_launch(void* const* d_in, const int* in_sizes, int n_in,
                              void* d_out, int out_size, void* d_ws, size_t ws_size,
                              hipStream_t stream) {
  const float* x    = (const float*)d_in[0];
  const float* Wqkv = (const float*)d_in[1];
  const float* Wo   = (const float*)d_in[2];
  float* out = (float*)d_out;

  const size_t QKV_ELEMS = (size_t)B_ * H_ * S_ * DH_;
  char* w = (char*)d_ws;
  unsigned short* xb = (unsigned short*)w;   // x bf16; z aliases it later
  unsigned short* z  = xb;
  w += (size_t)8192 * 2048 * 2;
  unsigned short* wqkvb = (unsigned short*)w; w += (size_t)6144 * 2048 * 2;
  unsigned short* wob   = (unsigned short*)w; w += (size_t)2048 * 2048 * 2;
  unsigned short* qq = (unsigned short*)w;    w += QKV_ELEMS * 2;
  unsigned short* kk = (unsigned short*)w;    w += QKV_ELEMS * 2;
  unsigned short* vv = (unsigned short*)w;    w += QKV_ELEMS * 2;
  float* tabc = (float*)w; w += (size_t)S_ * 64 * 4;
  float* tabs = (float*)w; w += (size_t)S_ * 64 * 4;
  if ((size_t)(w - (char*)d_ws) > ws_size) return;

  conv_bf16<<<16384, 256, 0, stream>>>(x, xb, 8192 * 2048 / 4);
  conv_bf16<<<12288, 256, 0, stream>>>(Wqkv, wqkvb, 6144 * 2048 / 4);
  conv_bf16<<<4096, 256, 0, stream>>>(Wo, wob, 2048 * 2048 / 4);
  gemm_bt<1><<<dim3(48, 64), 256, 0, stream>>>(xb, wqkvb, nullptr, qq, 8192, 6144, 2048);
  rope_tab<<<2048, 64, 0, stream>>>(tabc, tabs);
  rope_apply<<<65536, 256, 0, stream>>>(qq, kk, tabc, tabs);
  attn_fwd<<<dim3(S_ / 64, B_ * H_), 256, 0, stream>>>(qq, kk, vv, z);
  gemm_bt<0><<<dim3(16, 64), 256, 0, stream>>>(z, wob, out, nullptr, 8192, 2048, 2048);
}

// Round 7
// 567.343 us; speedup vs baseline: 2.3954x; 1.2051x over previous
//
#include <hip/hip_runtime.h>
#include <hip/hip_bf16.h>
#include <stdint.h>

#define B_ 4
#define S_ 2048
#define D_ 2048
#define H_ 16
#define DH_ 128

typedef short bf8_t __attribute__((ext_vector_type(8)));   // 8 bf16 (4 VGPRs)
typedef float f4_t  __attribute__((ext_vector_type(4)));   // MFMA C/D

__device__ __forceinline__ unsigned short f2bf(float f) {
  __hip_bfloat16 h = __float2bfloat16(f);   // RNE
  return *reinterpret_cast<const unsigned short*>(&h);
}
__device__ __forceinline__ float bf2f(unsigned short u) {
  return __uint_as_float(((unsigned int)u) << 16);
}

// async global->LDS, 16B per lane. LDS dest must be (wave-uniform base + lane*16).
__device__ __forceinline__ void gload_lds16(const void* g, void* lds) {
  __builtin_amdgcn_global_load_lds(
      (const __attribute__((address_space(1))) unsigned int*)(uintptr_t)g,
      (__attribute__((address_space(3))) unsigned int*)(unsigned int)(uintptr_t)lds,
      16, 0, 0);
}

// ---------------- f32 -> bf16 conversion (x4 vectorized) ----------------
__global__ __launch_bounds__(256) void conv_bf16(const float* __restrict__ in,
                                                 unsigned short* __restrict__ out,
                                                 int n4) {
  int i = blockIdx.x * 256 + threadIdx.x;
  if (i >= n4) return;
  float4 v = ((const float4*)in)[i];
  ushort4 u;
  u.x = f2bf(v.x); u.y = f2bf(v.y); u.z = f2bf(v.z); u.w = f2bf(v.w);
  ((ushort4*)out)[i] = u;
}

// ---------------- 256x256 deep-pipelined GEMM: C = A * Bt^T ----------------
// 8 waves (2M x 4N), BK=32 ring of 4 LDS slices (128 KB), counted vmcnt(8)
// (T3/T4), raw s_barrier (one per slice), T2 involutive swizzle (2-way reads),
// T5 setprio around the 32-MFMA cluster. EPI=0: f32 row-major. EPI=1: bf16
// scatter into qkv [c][b][h][s][dh].
template <int EPI>
__global__ __launch_bounds__(512, 2) void gemm256(
    const unsigned short* __restrict__ A, const unsigned short* __restrict__ Bt,
    float* __restrict__ Cf, unsigned short* __restrict__ Cb,
    int M, int N, int K) {
  __shared__ unsigned short AB[4][2][8192];   // [ring][A,B][256 rows x 32 k] = 128 KB
  const int tid  = threadIdx.x;
  const int lane = tid & 63;
  const int wv   = tid >> 6;     // 0..7
  const int wr   = wv >> 2;      // 0..1  (M half)
  const int wc   = wv & 3;       // 0..3  (N quarter)
  const int rsel = lane & 15;
  const int g    = lane >> 4;
  const int qr0  = g * 4;

  // bijective XCD swizzle (nwg % 8 == 0 for all our grids)
  int id  = blockIdx.y * gridDim.x + blockIdx.x;
  int cpx = (gridDim.x * gridDim.y) >> 3;
  int swz = (id & 7) * cpx + (id >> 3);
  const int bm = (swz / gridDim.x) * 256;
  const int bn = (swz % gridDim.x) * 256;

  const int NS = K >> 5;   // BK=32 slices

  // staging geometry: thread covers LDS bytes [tid*16] and [tid*16+8192] of a
  // 16 KB slice. Global source pre-swizzled (involution g' = slot ^ ((row>>1)&3)).
  const int ob0 = tid * 16, ob1 = ob0 + 8192;
  const int row0 = ob0 >> 6, row1 = ob1 >> 6;
  const int g0 = ((ob0 >> 4) & 3) ^ ((row0 >> 1) & 3);
  const int g1 = ((ob1 >> 4) & 3) ^ ((row1 >> 1) & 3);
  const unsigned short* Ag0 = A + (size_t)(bm + row0) * K + g0 * 8;
  const unsigned short* Ag1 = A + (size_t)(bm + row1) * K + g1 * 8;
  const unsigned short* Bg0 = Bt + (size_t)(bn + row0) * K + g0 * 8;
  const unsigned short* Bg1 = Bt + (size_t)(bn + row1) * K + g1 * 8;

  f4_t acc[8][4];
#pragma unroll
  for (int i = 0; i < 8; ++i)
#pragma unroll
    for (int j = 0; j < 4; ++j) acc[i][j] = (f4_t){0.f, 0.f, 0.f, 0.f};

  // swizzled read byte offsets (within a slice)
  int aoff[8], boff[4];
#pragma unroll
  for (int i = 0; i < 8; ++i) {
    int arow = wr * 128 + i * 16 + rsel;
    aoff[i] = arow * 64 + ((g * 16) ^ ((arow & 6) << 3));
  }
#pragma unroll
  for (int j = 0; j < 4; ++j) {
    int brow = wc * 64 + j * 16 + rsel;
    boff[j] = brow * 64 + ((g * 16) ^ ((brow & 6) << 3));
  }

#define STAGE(sl)                                                        \
  {                                                                      \
    int slot_ = (sl) & 3;                                                \
    int ks_   = (sl) << 5;                                               \
    gload_lds16(Ag0 + ks_, (char*)&AB[slot_][0][0] + ob0);               \
    gload_lds16(Ag1 + ks_, (char*)&AB[slot_][0][0] + ob1);               \
    gload_lds16(Bg0 + ks_, (char*)&AB[slot_][1][0] + ob0);               \
    gload_lds16(Bg1 + ks_, (char*)&AB[slot_][1][0] + ob1);               \
  }

  STAGE(0); STAGE(1); STAGE(2);   // 12 loads in flight

  for (int s = 0; s < NS; ++s) {
    // drain exactly slice s (oldest 4 loads); keep the rest in flight (T4)
    if (s < NS - 2)       asm volatile("s_waitcnt vmcnt(8)" ::: "memory");
    else if (s == NS - 2) asm volatile("s_waitcnt vmcnt(4)" ::: "memory");
    else                  asm volatile("s_waitcnt vmcnt(0)" ::: "memory");
    __builtin_amdgcn_s_barrier();
    asm volatile("" ::: "memory");

    const char* As_ = (const char*)&AB[s & 3][0][0];
    const char* Bs_ = (const char*)&AB[s & 3][1][0];
    bf8_t af[8], bfr[4];
#pragma unroll
    for (int i = 0; i < 8; ++i) af[i] = *(const bf8_t*)(As_ + aoff[i]);
#pragma unroll
    for (int j = 0; j < 4; ++j) bfr[j] = *(const bf8_t*)(Bs_ + boff[j]);

    if (s + 3 < NS) STAGE(s + 3);   // safe: slot (s+3)&3 last read in iter s-1

    __builtin_amdgcn_s_setprio(1);
#pragma unroll
    for (int i = 0; i < 8; ++i)
#pragma unroll
      for (int j = 0; j < 4; ++j)
        acc[i][j] = __builtin_amdgcn_mfma_f32_16x16x32_bf16(af[i], bfr[j], acc[i][j], 0, 0, 0);
    __builtin_amdgcn_s_setprio(0);
  }
#undef STAGE

  // epilogue: C/D layout col=lane&15, row=(lane>>4)*4+reg
#pragma unroll
  for (int i = 0; i < 8; ++i) {
#pragma unroll
    for (int j = 0; j < 4; ++j) {
#pragma unroll
      for (int r = 0; r < 4; ++r) {
        int row = bm + wr * 128 + i * 16 + qr0 + r;
        int col = bn + wc * 64 + j * 16 + rsel;
        float v = acc[i][j][r];
        if (EPI == 0) {
          Cf[(size_t)row * N + col] = v;
        } else {
          int c = col >> 11, h = (col >> 7) & (H_ - 1), dh = col & (DH_ - 1);
          int b = row >> 11, s = row & (S_ - 1);
          size_t dst = ((((size_t)c * B_ + b) * H_ + h) * S_ + s) * DH_ + dh;
          Cb[dst] = f2bf(v);
        }
      }
    }
  }
}

// ---------------- RoPE tables ----------------
__global__ void rope_tab(float* __restrict__ tc, float* __restrict__ ts) {
  int s = blockIdx.x;
  int i = threadIdx.x;   // 64 threads
  float inv = powf(10000.0f, -(float)i / 64.0f);
  float f   = (float)s * inv;
  tc[s * 64 + i] = cosf(f);
  ts[s * 64 + i] = sinf(f);
}

// ---------------- RoPE apply in-place on q and k ([b][h][s][dh] bf16)
__global__ __launch_bounds__(256) void rope_apply(
    unsigned short* __restrict__ Q, unsigned short* __restrict__ Kk,
    const float* __restrict__ tc, const float* __restrict__ ts) {
  int idx  = blockIdx.x * 256 + threadIdx.x;   // 2^24 total
  int i    = idx & 63;
  int s    = (idx >> 6) & (S_ - 1);
  int bh   = (idx >> 17) & 63;
  int tsel = idx >> 23;
  unsigned short* T = tsel ? Kk : Q;
  size_t base = ((size_t)bh * S_ + s) * DH_;
  float x1 = bf2f(T[base + i]);
  float x2 = bf2f(T[base + i + 64]);
  float c  = tc[s * 64 + i], sn = ts[s * 64 + i];
  T[base + i]      = f2bf(x1 * c - x2 * sn);
  T[base + i + 64] = f2bf(x2 * c + x1 * sn);
}

// ---------------- causal flash attention (unchanged from round 6) ----------------
__global__ __launch_bounds__(256) void attn_fwd(
    const unsigned short* __restrict__ Q, const unsigned short* __restrict__ Kk,
    const unsigned short* __restrict__ V, unsigned short* __restrict__ Z) {
  __shared__ unsigned short Ks[2][64 * 128];  // 32 KB, XOR-swizzled (src-side)
  __shared__ unsigned short Vt[2][128 * 64];  // 32 KB, [dh][kv], XOR-swizzled
  __shared__ unsigned short Pw[4][16 * 64];   // 8 KB, per-wave, swizzled
  const int tid  = threadIdx.x;
  const int lane = tid & 63;
  const int wv   = tid >> 6;
  const int bh   = blockIdx.y;
  const int q0   = (gridDim.x - 1 - blockIdx.x) * 64;   // longest blocks first
  const size_t base = (size_t)bh * S_ * DH_;
  const int rsel = lane & 15;
  const int g    = lane >> 4;
  const int kof  = g * 8;
  const int qr0  = g * 4;
  const int qrow = q0 + wv * 16 + rsel;
  const float sl2 = 0.08838834764831845f * 1.4426950408889634f;  // scale*log2(e)

  bf8_t aq[4];
#pragma unroll
  for (int kc = 0; kc < 4; ++kc) {
    aq[kc] = *(const bf8_t*)&Q[base + (size_t)qrow * DH_ + kc * 32 + kof];
#pragma unroll
    for (int e = 0; e < 8; ++e)
      aq[kc][e] = (short)f2bf(bf2f((unsigned short)aq[kc][e]) * sl2);
  }

  bf8_t vones;
#pragma unroll
  for (int e = 0; e < 8; ++e) vones[e] = (short)0x3F80;

  f4_t o[9];   // o[0..7] = output frags, o[8] = row-sum (softmax denom)
#pragma unroll
  for (int nf = 0; nf < 9; ++nf) o[nf] = (f4_t){0.f, 0.f, 0.f, 0.f};
  float mrow[4] = {-3e30f, -3e30f, -3e30f, -3e30f};
  const int nt = q0 / 64 + 1;

  const int kvp = tid & 31;
  const int vch = tid >> 5;

  bf8_t vlo[2], vhi[2];
#pragma unroll
  for (int u = 0; u < 2; ++u) {
    int c0 = (u * 8 + vch) * 8;
    vlo[u] = *(const bf8_t*)&V[base + (size_t)(2 * kvp) * DH_ + c0];
    vhi[u] = *(const bf8_t*)&V[base + (size_t)(2 * kvp + 1) * DH_ + c0];
  }
#pragma unroll
  for (int c = 0; c < 4; ++c) {
    int ob = (c * 256 + tid) * 16;
    int row = ob >> 8;
    int scol = (ob & 255) ^ ((row & 7) << 4);
    gload_lds16(Kk + base + (size_t)row * DH_ + (scol >> 1), (char*)&Ks[0][0] + ob);
  }
  {
    unsigned int* Vt32 = (unsigned int*)&Vt[0][0];
#pragma unroll
    for (int u = 0; u < 2; ++u) {
      int c0 = (u * 8 + vch) * 8;
#pragma unroll
      for (int e = 0; e < 8; ++e) {
        unsigned int val = (unsigned short)vlo[u][e] |
                           ((unsigned int)(unsigned short)vhi[u][e] << 16);
        Vt32[(c0 + e) * 32 + (kvp ^ (e << 2))] = val;
      }
    }
  }
  __syncthreads();

  for (int t = 0; t < nt; ++t) {
    const int cur = t & 1;
    const int kv0 = t * 64;
    const bool diag = (t == nt - 1);
    const bool pf   = (t + 1 < nt);

    if (pf) {
      const unsigned short* gV = V + base + (size_t)(kv0 + 64) * DH_;
#pragma unroll
      for (int u = 0; u < 2; ++u) {
        int c0 = (u * 8 + vch) * 8;
        vlo[u] = *(const bf8_t*)&gV[(size_t)(2 * kvp) * DH_ + c0];
        vhi[u] = *(const bf8_t*)&gV[(size_t)(2 * kvp + 1) * DH_ + c0];
      }
      const unsigned short* gK = Kk + base + (size_t)(kv0 + 64) * DH_;
#pragma unroll
      for (int c = 0; c < 4; ++c) {
        int ob = (c * 256 + tid) * 16;
        int row = ob >> 8;
        int scol = (ob & 255) ^ ((row & 7) << 4);
        gload_lds16(gK + (size_t)row * DH_ + (scol >> 1), (char*)&Ks[cur ^ 1][0] + ob);
      }
    }

    f4_t sacc[4];
#pragma unroll
    for (int cf = 0; cf < 4; ++cf) sacc[cf] = (f4_t){0.f, 0.f, 0.f, 0.f};
    __builtin_amdgcn_s_setprio(1);
#pragma unroll
    for (int cf = 0; cf < 4; ++cf)
#pragma unroll
      for (int kc = 0; kc < 4; ++kc) {
        int krow = cf * 16 + rsel;
        bf8_t bk = *(const bf8_t*)&Ks[cur][krow * 128 + ((kc * 32 + kof) ^ ((krow & 7) << 3))];
        sacc[cf] = __builtin_amdgcn_mfma_f32_16x16x32_bf16(aq[kc], bk, sacc[cf], 0, 0, 0);
      }
    __builtin_amdgcn_s_setprio(0);

    if (diag) {
#pragma unroll
      for (int cf = 0; cf < 4; ++cf) {
        int kvabs = kv0 + cf * 16 + rsel;
#pragma unroll
        for (int r = 0; r < 4; ++r) {
          int qabs = q0 + wv * 16 + qr0 + r;
          if (kvabs > qabs) sacc[cf][r] = -3e30f;
        }
      }
    }

    float tmr[4];
#pragma unroll
    for (int r = 0; r < 4; ++r)
      tmr[r] = fmaxf(fmaxf(sacc[0][r], sacc[1][r]), fmaxf(sacc[2][r], sacc[3][r]));
    bool needr = (tmr[0] > mrow[0] + 11.f) || (tmr[1] > mrow[1] + 11.f) ||
                 (tmr[2] > mrow[2] + 11.f) || (tmr[3] > mrow[3] + 11.f);
    if (__any(needr)) {
#pragma unroll
      for (int r = 0; r < 4; ++r) {
        float m = tmr[r];
#pragma unroll
        for (int d = 1; d < 16; d <<= 1) m = fmaxf(m, __shfl_xor(m, d, 16));
        float nm = fmaxf(mrow[r], m);
        float sc = exp2f(mrow[r] - nm);
        mrow[r] = nm;
#pragma unroll
        for (int nf = 0; nf < 9; ++nf) o[nf][r] *= sc;
      }
    }
#pragma unroll
    for (int cf = 0; cf < 4; ++cf)
#pragma unroll
      for (int r = 0; r < 4; ++r)
        sacc[cf][r] = exp2f(sacc[cf][r] - mrow[r]);

    unsigned short* P = &Pw[wv][0];
#pragma unroll
    for (int cf = 0; cf < 4; ++cf)
#pragma unroll
      for (int r = 0; r < 4; ++r) {
        int prow = qr0 + r;
        P[prow * 64 + ((cf * 16 + rsel) ^ ((prow >> 1) << 3))] = f2bf(sacc[cf][r]);
      }

    if (pf) {
      unsigned int* Vt32 = (unsigned int*)&Vt[cur ^ 1][0];
#pragma unroll
      for (int u = 0; u < 2; ++u) {
        int c0 = (u * 8 + vch) * 8;
#pragma unroll
        for (int e = 0; e < 8; ++e) {
          unsigned int val = (unsigned short)vlo[u][e] |
                             ((unsigned int)(unsigned short)vhi[u][e] << 16);
          Vt32[(c0 + e) * 32 + (kvp ^ (e << 2))] = val;
        }
      }
    }

    __builtin_amdgcn_s_setprio(1);
#pragma unroll
    for (int kc2 = 0; kc2 < 2; ++kc2) {
      bf8_t pa = *(const bf8_t*)&P[rsel * 64 + ((kc2 * 32 + kof) ^ ((rsel >> 1) << 3))];
#pragma unroll
      for (int nf = 0; nf < 8; ++nf) {
        int vrow = nf * 16 + rsel;
        bf8_t bv = *(const bf8_t*)&Vt[cur][vrow * 64 + ((kc2 * 32 + kof) ^ ((vrow & 7) << 3))];
        o[nf] = __builtin_amdgcn_mfma_f32_16x16x32_bf16(pa, bv, o[nf], 0, 0, 0);
      }
      o[8] = __builtin_amdgcn_mfma_f32_16x16x32_bf16(pa, vones, o[8], 0, 0, 0);
    }
    __builtin_amdgcn_s_setprio(0);

    __syncthreads();
  }

  const int b = bh >> 4, h = bh & 15;
#pragma unroll
  for (int r = 0; r < 4; ++r) {
    float inv = 1.0f / o[8][r];
    int s = q0 + wv * 16 + qr0 + r;
    size_t rowo = ((size_t)b * S_ + s) * D_ + h * DH_;
#pragma unroll
    for (int nf = 0; nf < 8; ++nf)
      Z[rowo + nf * 16 + rsel] = f2bf(o[nf][r] * inv);
  }
}

// ---------------- orchestration ----------------
extern "C" void kernel_launch(void* const* d_in, const int* in_sizes, int n_in,
                              void* d_out, int out_size, void* d_ws, size_t ws_size,
                              hipStream_t stream) {
  const float* x    = (const float*)d_in[0];
  const float* Wqkv = (const float*)d_in[1];
  const float* Wo   = (const float*)d_in[2];
  float* out = (float*)d_out;

  const size_t QKV_ELEMS = (size_t)B_ * H_ * S_ * DH_;
  char* w = (char*)d_ws;
  unsigned short* xb = (unsigned short*)w;   // x bf16; z aliases it later
  unsigned short* z  = xb;
  w += (size_t)8192 * 2048 * 2;
  unsigned short* wqkvb = (unsigned short*)w; w += (size_t)6144 * 2048 * 2;
  unsigned short* wob   = (unsigned short*)w; w += (size_t)2048 * 2048 * 2;
  unsigned short* qq = (unsigned short*)w;    w += QKV_ELEMS * 2;
  unsigned short* kk = (unsigned short*)w;    w += QKV_ELEMS * 2;
  unsigned short* vv = (unsigned short*)w;    w += QKV_ELEMS * 2;
  float* tabc = (float*)w; w += (size_t)S_ * 64 * 4;
  float* tabs = (float*)w; w += (size_t)S_ * 64 * 4;
  if ((size_t)(w - (char*)d_ws) > ws_size) return;

  conv_bf16<<<16384, 256, 0, stream>>>(x, xb, 8192 * 2048 / 4);
  conv_bf16<<<12288, 256, 0, stream>>>(Wqkv, wqkvb, 6144 * 2048 / 4);
  conv_bf16<<<4096, 256, 0, stream>>>(Wo, wob, 2048 * 2048 / 4);
  gemm256<1><<<dim3(24, 32), 512, 0, stream>>>(xb, wqkvb, nullptr, qq, 8192, 6144, 2048);
  rope_tab<<<2048, 64, 0, stream>>>(tabc, tabs);
  rope_apply<<<65536, 256, 0, stream>>>(qq, kk, tabc, tabs);
  attn_fwd<<<dim3(S_ / 64, B_ * H_), 256, 0, stream>>>(qq, kk, vv, z);
  gemm256<0><<<dim3(8, 32), 512, 0, stream>>>(z, wob, out, nullptr, 8192, 2048, 2048);
}

// Round 8
// 557.491 us; speedup vs baseline: 2.4378x; 1.0177x over previous
//
#include <hip/hip_runtime.h>
#include <hip/hip_bf16.h>
#include <stdint.h>

#define B_ 4
#define S_ 2048
#define D_ 2048
#define H_ 16
#define DH_ 128

typedef short bf8_t __attribute__((ext_vector_type(8)));   // 8 bf16 (4 VGPRs)
typedef float f4_t  __attribute__((ext_vector_type(4)));   // MFMA C/D

__device__ __forceinline__ unsigned short f2bf(float f) {
  __hip_bfloat16 h = __float2bfloat16(f);   // RNE
  return *reinterpret_cast<const unsigned short*>(&h);
}
__device__ __forceinline__ float bf2f(unsigned short u) {
  return __uint_as_float(((unsigned int)u) << 16);
}

// async global->LDS, 16B per lane. LDS dest must be (wave-uniform base + lane*16).
__device__ __forceinline__ void gload_lds16(const void* g, void* lds) {
  __builtin_amdgcn_global_load_lds(
      (const __attribute__((address_space(1))) unsigned int*)(uintptr_t)g,
      (__attribute__((address_space(3))) unsigned int*)(unsigned int)(uintptr_t)lds,
      16, 0, 0);
}

// ---------------- f32 -> bf16 conversion (x4 vectorized) ----------------
__global__ __launch_bounds__(256) void conv_bf16(const float* __restrict__ in,
                                                 unsigned short* __restrict__ out,
                                                 int n4) {
  int i = blockIdx.x * 256 + threadIdx.x;
  if (i >= n4) return;
  float4 v = ((const float4*)in)[i];
  ushort4 u;
  u.x = f2bf(v.x); u.y = f2bf(v.y); u.z = f2bf(v.z); u.w = f2bf(v.w);
  ((ushort4*)out)[i] = u;
}

// ---------------- 256x256 deep-pipelined GEMM: C = A * Bt^T ----------------
// 8 waves (2M x 4N), BK=32 ring of 4 LDS slices (128 KB), counted vmcnt(8)
// (T3/T4), raw s_barrier (one per slice), T2 involutive swizzle (2-way reads),
// T5 setprio around the 32-MFMA cluster.
template <int EPI>
__global__ __launch_bounds__(512, 2) void gemm256(
    const unsigned short* __restrict__ A, const unsigned short* __restrict__ Bt,
    float* __restrict__ Cf, unsigned short* __restrict__ Cb,
    int M, int N, int K) {
  __shared__ unsigned short AB[4][2][8192];   // [ring][A,B][256 rows x 32 k] = 128 KB
  const int tid  = threadIdx.x;
  const int lane = tid & 63;
  const int wv   = tid >> 6;     // 0..7
  const int wr   = wv >> 2;      // 0..1  (M half)
  const int wc   = wv & 3;       // 0..3  (N quarter)
  const int rsel = lane & 15;
  const int g    = lane >> 4;
  const int qr0  = g * 4;

  // bijective XCD swizzle (nwg % 8 == 0 for all our grids)
  int id  = blockIdx.y * gridDim.x + blockIdx.x;
  int cpx = (gridDim.x * gridDim.y) >> 3;
  int swz = (id & 7) * cpx + (id >> 3);
  const int bm = (swz / gridDim.x) * 256;
  const int bn = (swz % gridDim.x) * 256;

  const int NS = K >> 5;   // BK=32 slices

  const int ob0 = tid * 16, ob1 = ob0 + 8192;
  const int row0 = ob0 >> 6, row1 = ob1 >> 6;
  const int g0 = ((ob0 >> 4) & 3) ^ ((row0 >> 1) & 3);
  const int g1 = ((ob1 >> 4) & 3) ^ ((row1 >> 1) & 3);
  const unsigned short* Ag0 = A + (size_t)(bm + row0) * K + g0 * 8;
  const unsigned short* Ag1 = A + (size_t)(bm + row1) * K + g1 * 8;
  const unsigned short* Bg0 = Bt + (size_t)(bn + row0) * K + g0 * 8;
  const unsigned short* Bg1 = Bt + (size_t)(bn + row1) * K + g1 * 8;

  f4_t acc[8][4];
#pragma unroll
  for (int i = 0; i < 8; ++i)
#pragma unroll
    for (int j = 0; j < 4; ++j) acc[i][j] = (f4_t){0.f, 0.f, 0.f, 0.f};

  int aoff[8], boff[4];
#pragma unroll
  for (int i = 0; i < 8; ++i) {
    int arow = wr * 128 + i * 16 + rsel;
    aoff[i] = arow * 64 + ((g * 16) ^ ((arow & 6) << 3));
  }
#pragma unroll
  for (int j = 0; j < 4; ++j) {
    int brow = wc * 64 + j * 16 + rsel;
    boff[j] = brow * 64 + ((g * 16) ^ ((brow & 6) << 3));
  }

#define STAGE(sl)                                                        \
  {                                                                      \
    int slot_ = (sl) & 3;                                                \
    int ks_   = (sl) << 5;                                               \
    gload_lds16(Ag0 + ks_, (char*)&AB[slot_][0][0] + ob0);               \
    gload_lds16(Ag1 + ks_, (char*)&AB[slot_][0][0] + ob1);               \
    gload_lds16(Bg0 + ks_, (char*)&AB[slot_][1][0] + ob0);               \
    gload_lds16(Bg1 + ks_, (char*)&AB[slot_][1][0] + ob1);               \
  }

  STAGE(0); STAGE(1); STAGE(2);   // 12 loads in flight

  for (int s = 0; s < NS; ++s) {
    if (s < NS - 2)       asm volatile("s_waitcnt vmcnt(8)" ::: "memory");
    else if (s == NS - 2) asm volatile("s_waitcnt vmcnt(4)" ::: "memory");
    else                  asm volatile("s_waitcnt vmcnt(0)" ::: "memory");
    __builtin_amdgcn_s_barrier();
    asm volatile("" ::: "memory");

    const char* As_ = (const char*)&AB[s & 3][0][0];
    const char* Bs_ = (const char*)&AB[s & 3][1][0];
    bf8_t af[8], bfr[4];
#pragma unroll
    for (int i = 0; i < 8; ++i) af[i] = *(const bf8_t*)(As_ + aoff[i]);
#pragma unroll
    for (int j = 0; j < 4; ++j) bfr[j] = *(const bf8_t*)(Bs_ + boff[j]);

    if (s + 3 < NS) STAGE(s + 3);   // safe: slot (s+3)&3 last read in iter s-1

    __builtin_amdgcn_s_setprio(1);
#pragma unroll
    for (int i = 0; i < 8; ++i)
#pragma unroll
      for (int j = 0; j < 4; ++j)
        acc[i][j] = __builtin_amdgcn_mfma_f32_16x16x32_bf16(af[i], bfr[j], acc[i][j], 0, 0, 0);
    __builtin_amdgcn_s_setprio(0);
  }
#undef STAGE

#pragma unroll
  for (int i = 0; i < 8; ++i) {
#pragma unroll
    for (int j = 0; j < 4; ++j) {
#pragma unroll
      for (int r = 0; r < 4; ++r) {
        int row = bm + wr * 128 + i * 16 + qr0 + r;
        int col = bn + wc * 64 + j * 16 + rsel;
        float v = acc[i][j][r];
        if (EPI == 0) {
          Cf[(size_t)row * N + col] = v;
        } else {
          int c = col >> 11, h = (col >> 7) & (H_ - 1), dh = col & (DH_ - 1);
          int b = row >> 11, s = row & (S_ - 1);
          size_t dst = ((((size_t)c * B_ + b) * H_ + h) * S_ + s) * DH_ + dh;
          Cb[dst] = f2bf(v);
        }
      }
    }
  }
}

// ---------------- RoPE tables ----------------
__global__ void rope_tab(float* __restrict__ tc, float* __restrict__ ts) {
  int s = blockIdx.x;
  int i = threadIdx.x;   // 64 threads
  float inv = powf(10000.0f, -(float)i / 64.0f);
  float f   = (float)s * inv;
  tc[s * 64 + i] = cosf(f);
  ts[s * 64 + i] = sinf(f);
}

// ---------------- RoPE apply in-place on q and k ([b][h][s][dh] bf16)
__global__ __launch_bounds__(256) void rope_apply(
    unsigned short* __restrict__ Q, unsigned short* __restrict__ Kk,
    const float* __restrict__ tc, const float* __restrict__ ts) {
  int idx  = blockIdx.x * 256 + threadIdx.x;   // 2^24 total
  int i    = idx & 63;
  int s    = (idx >> 6) & (S_ - 1);
  int bh   = (idx >> 17) & 63;
  int tsel = idx >> 23;
  unsigned short* T = tsel ? Kk : Q;
  size_t base = ((size_t)bh * S_ + s) * DH_;
  float x1 = bf2f(T[base + i]);
  float x2 = bf2f(T[base + i + 64]);
  float c  = tc[s * 64 + i], sn = ts[s * 64 + i];
  T[base + i]      = f2bf(x1 * c - x2 * sn);
  T[base + i + 64] = f2bf(x2 * c + x1 * sn);
}

// ---------------- causal flash attention ----------------
// grid (S/128, B*H), 512 thr = 8 waves x 16 q-rows (QBLK=128). KVBLK=64.
// One 64-row K/V tile feeds 128 q-rows: staging bytes + barriers per unit of
// work halved vs QBLK=64. LDS 80KB -> 2 blocks/CU (16 waves). Waves skip
// fully-masked tiles (staging+barrier only); mask applied only near diagonal.
__global__ __launch_bounds__(512) void attn_fwd(
    const unsigned short* __restrict__ Q, const unsigned short* __restrict__ Kk,
    const unsigned short* __restrict__ V, unsigned short* __restrict__ Z) {
  __shared__ unsigned short Ks[2][64 * 128];  // 32 KB, XOR-swizzled (src-side)
  __shared__ unsigned short Vt[2][128 * 64];  // 32 KB, [dh][kv], XOR-swizzled
  __shared__ unsigned short Pw[8][16 * 64];   // 16 KB, per-wave, swizzled
  const int tid  = threadIdx.x;
  const int lane = tid & 63;
  const int wv   = tid >> 6;                  // 0..7
  const int bh   = blockIdx.y;
  const int q0   = (gridDim.x - 1 - blockIdx.x) * 128;   // longest blocks first
  const size_t base = (size_t)bh * S_ * DH_;
  const int rsel = lane & 15;
  const int g    = lane >> 4;
  const int kof  = g * 8;
  const int qr0  = g * 4;
  const int qlo  = q0 + wv * 16;
  const int qhi  = qlo + 15;
  const int qrow = qlo + rsel;
  const float sl2 = 0.08838834764831845f * 1.4426950408889634f;  // scale*log2(e)

  bf8_t aq[4];
#pragma unroll
  for (int kc = 0; kc < 4; ++kc) {
    aq[kc] = *(const bf8_t*)&Q[base + (size_t)qrow * DH_ + kc * 32 + kof];
#pragma unroll
    for (int e = 0; e < 8; ++e)
      aq[kc][e] = (short)f2bf(bf2f((unsigned short)aq[kc][e]) * sl2);
  }

  bf8_t vones;
#pragma unroll
  for (int e = 0; e < 8; ++e) vones[e] = (short)0x3F80;

  f4_t o[9];   // o[0..7] = output frags, o[8] = row-sum (softmax denom)
#pragma unroll
  for (int nf = 0; nf < 9; ++nf) o[nf] = (f4_t){0.f, 0.f, 0.f, 0.f};
  float mrow[4] = {-3e30f, -3e30f, -3e30f, -3e30f};
  const int nt = q0 / 64 + 2;   // kv tiles up to q0+128

  // V staging: one unit/thread: kv rows {2*kvp, 2*kvp+1} x dh [c0, c0+8)
  const int kvp = tid & 31;
  const int vc0 = (tid >> 5) * 8;   // 0..15 chunks

  bf8_t vlo, vhi;
  vlo = *(const bf8_t*)&V[base + (size_t)(2 * kvp) * DH_ + vc0];
  vhi = *(const bf8_t*)&V[base + (size_t)(2 * kvp + 1) * DH_ + vc0];
#pragma unroll
  for (int c = 0; c < 2; ++c) {
    int ob = (c * 512 + tid) * 16;
    int row = ob >> 8;
    int scol = (ob & 255) ^ ((row & 7) << 4);
    gload_lds16(Kk + base + (size_t)row * DH_ + (scol >> 1), (char*)&Ks[0][0] + ob);
  }
  {
    unsigned int* Vt32 = (unsigned int*)&Vt[0][0];
#pragma unroll
    for (int e = 0; e < 8; ++e) {
      unsigned int val = (unsigned short)vlo[e] |
                         ((unsigned int)(unsigned short)vhi[e] << 16);
      Vt32[(vc0 + e) * 32 + (kvp ^ (e << 2))] = val;
    }
  }
  __syncthreads();

  for (int t = 0; t < nt; ++t) {
    const int cur = t & 1;
    const int kv0 = t * 64;
    const bool pf = (t + 1 < nt);

    // ---- issue next tile's loads (V->regs first, then K->LDS) ----
    if (pf) {
      const unsigned short* gV = V + base + (size_t)(kv0 + 64) * DH_;
      vlo = *(const bf8_t*)&gV[(size_t)(2 * kvp) * DH_ + vc0];
      vhi = *(const bf8_t*)&gV[(size_t)(2 * kvp + 1) * DH_ + vc0];
      const unsigned short* gK = Kk + base + (size_t)(kv0 + 64) * DH_;
#pragma unroll
      for (int c = 0; c < 2; ++c) {
        int ob = (c * 512 + tid) * 16;
        int row = ob >> 8;
        int scol = (ob & 255) ^ ((row & 7) << 4);
        gload_lds16(gK + (size_t)row * DH_ + (scol >> 1), (char*)&Ks[cur ^ 1][0] + ob);
      }
    }

    // wave-uniform causal predicates
    const bool active = (kv0 <= qhi);          // any unmasked element?
    const bool domask = active && (kv0 + 63 > qlo);

    if (active) {
      // ---- S = Q K^T  (Q pre-scaled: result in log2 domain) ----
      f4_t sacc[4];
#pragma unroll
      for (int cf = 0; cf < 4; ++cf) sacc[cf] = (f4_t){0.f, 0.f, 0.f, 0.f};
      __builtin_amdgcn_s_setprio(1);
#pragma unroll
      for (int cf = 0; cf < 4; ++cf)
#pragma unroll
        for (int kc = 0; kc < 4; ++kc) {
          int krow = cf * 16 + rsel;
          bf8_t bk = *(const bf8_t*)&Ks[cur][krow * 128 + ((kc * 32 + kof) ^ ((krow & 7) << 3))];
          sacc[cf] = __builtin_amdgcn_mfma_f32_16x16x32_bf16(aq[kc], bk, sacc[cf], 0, 0, 0);
        }
      __builtin_amdgcn_s_setprio(0);

      if (domask) {
#pragma unroll
        for (int cf = 0; cf < 4; ++cf) {
          int kvabs = kv0 + cf * 16 + rsel;
#pragma unroll
          for (int r = 0; r < 4; ++r) {
            int qabs = qlo + qr0 + r;
            if (kvabs > qabs) sacc[cf][r] = -3e30f;
          }
        }
      }

      // ---- defer-max softmax: common path has NO cross-lane reduction ----
      float tmr[4];
#pragma unroll
      for (int r = 0; r < 4; ++r)
        tmr[r] = fmaxf(fmaxf(sacc[0][r], sacc[1][r]), fmaxf(sacc[2][r], sacc[3][r]));
      bool needr = (tmr[0] > mrow[0] + 11.f) || (tmr[1] > mrow[1] + 11.f) ||
                   (tmr[2] > mrow[2] + 11.f) || (tmr[3] > mrow[3] + 11.f);
      if (__any(needr)) {
#pragma unroll
        for (int r = 0; r < 4; ++r) {
          float m = tmr[r];
#pragma unroll
          for (int d = 1; d < 16; d <<= 1) m = fmaxf(m, __shfl_xor(m, d, 16));
          float nm = fmaxf(mrow[r], m);
          float sc = exp2f(mrow[r] - nm);
          mrow[r] = nm;
#pragma unroll
          for (int nf = 0; nf < 9; ++nf) o[nf][r] *= sc;
        }
      }
#pragma unroll
      for (int cf = 0; cf < 4; ++cf)
#pragma unroll
        for (int r = 0; r < 4; ++r)
          sacc[cf][r] = exp2f(sacc[cf][r] - mrow[r]);

      // ---- P -> per-wave LDS (swizzle ((prow>>1)<<3)) ----
      unsigned short* P = &Pw[wv][0];
#pragma unroll
      for (int cf = 0; cf < 4; ++cf)
#pragma unroll
        for (int r = 0; r < 4; ++r) {
          int prow = qr0 + r;
          P[prow * 64 + ((cf * 16 + rsel) ^ ((prow >> 1) << 3))] = f2bf(sacc[cf][r]);
        }
    }

    // ---- write V(t+1) into Vt[nxt] (u32 pair-packs) ----
    if (pf) {
      unsigned int* Vt32 = (unsigned int*)&Vt[cur ^ 1][0];
#pragma unroll
      for (int e = 0; e < 8; ++e) {
        unsigned int val = (unsigned short)vlo[e] |
                           ((unsigned int)(unsigned short)vhi[e] << 16);
        Vt32[(vc0 + e) * 32 + (kvp ^ (e << 2))] = val;
      }
    }

    if (active) {
      // ---- O += P V ; denominator rides as o[8] = P x ones ----
      unsigned short* P = &Pw[wv][0];
      __builtin_amdgcn_s_setprio(1);
#pragma unroll
      for (int kc2 = 0; kc2 < 2; ++kc2) {
        bf8_t pa = *(const bf8_t*)&P[rsel * 64 + ((kc2 * 32 + kof) ^ ((rsel >> 1) << 3))];
#pragma unroll
        for (int nf = 0; nf < 8; ++nf) {
          int vrow = nf * 16 + rsel;
          bf8_t bv = *(const bf8_t*)&Vt[cur][vrow * 64 + ((kc2 * 32 + kof) ^ ((vrow & 7) << 3))];
          o[nf] = __builtin_amdgcn_mfma_f32_16x16x32_bf16(pa, bv, o[nf], 0, 0, 0);
        }
        o[8] = __builtin_amdgcn_mfma_f32_16x16x32_bf16(pa, vones, o[8], 0, 0, 0);
      }
      __builtin_amdgcn_s_setprio(0);
    }

    // ---- end of iter: drains vmcnt(0) (K(t+1) landed) + lgkm, sync ----
    __syncthreads();
  }

  const int b = bh >> 4, h = bh & 15;
#pragma unroll
  for (int r = 0; r < 4; ++r) {
    float inv = 1.0f / o[8][r];
    int s = qlo + qr0 + r;
    size_t rowo = ((size_t)b * S_ + s) * D_ + h * DH_;
#pragma unroll
    for (int nf = 0; nf < 8; ++nf)
      Z[rowo + nf * 16 + rsel] = f2bf(o[nf][r] * inv);
  }
}

// ---------------- orchestration ----------------
extern "C" void kernel_launch(void* const* d_in, const int* in_sizes, int n_in,
                              void* d_out, int out_size, void* d_ws, size_t ws_size,
                              hipStream_t stream) {
  const float* x    = (const float*)d_in[0];
  const float* Wqkv = (const float*)d_in[1];
  const float* Wo   = (const float*)d_in[2];
  float* out = (float*)d_out;

  const size_t QKV_ELEMS = (size_t)B_ * H_ * S_ * DH_;
  char* w = (char*)d_ws;
  unsigned short* xb = (unsigned short*)w;   // x bf16; z aliases it later
  unsigned short* z  = xb;
  w += (size_t)8192 * 2048 * 2;
  unsigned short* wqkvb = (unsigned short*)w; w += (size_t)6144 * 2048 * 2;
  unsigned short* wob   = (unsigned short*)w; w += (size_t)2048 * 2048 * 2;
  unsigned short* qq = (unsigned short*)w;    w += QKV_ELEMS * 2;
  unsigned short* kk = (unsigned short*)w;    w += QKV_ELEMS * 2;
  unsigned short* vv = (unsigned short*)w;    w += QKV_ELEMS * 2;
  float* tabc = (float*)w; w += (size_t)S_ * 64 * 4;
  float* tabs = (float*)w; w += (size_t)S_ * 64 * 4;
  if ((size_t)(w - (char*)d_ws) > ws_size) return;

  conv_bf16<<<16384, 256, 0, stream>>>(x, xb, 8192 * 2048 / 4);
  conv_bf16<<<12288, 256, 0, stream>>>(Wqkv, wqkvb, 6144 * 2048 / 4);
  conv_bf16<<<4096, 256, 0, stream>>>(Wo, wob, 2048 * 2048 / 4);
  gemm256<1><<<dim3(24, 32), 512, 0, stream>>>(xb, wqkvb, nullptr, qq, 8192, 6144, 2048);
  rope_tab<<<2048, 64, 0, stream>>>(tabc, tabs);
  rope_apply<<<65536, 256, 0, stream>>>(qq, kk, tabc, tabs);
  attn_fwd<<<dim3(S_ / 128, B_ * H_), 512, 0, stream>>>(qq, kk, vv, z);
  gemm256<0><<<dim3(8, 32), 512, 0, stream>>>(z, wob, out, nullptr, 8192, 2048, 2048);
}

// Round 9
// 495.661 us; speedup vs baseline: 2.7419x; 1.1247x over previous
//
#include <hip/hip_runtime.h>
#include <hip/hip_bf16.h>
#include <stdint.h>

#define B_ 4
#define S_ 2048
#define D_ 2048
#define H_ 16
#define DH_ 128

typedef short bf8_t __attribute__((ext_vector_type(8)));   // 8 bf16 (4 VGPRs)
typedef float f4_t  __attribute__((ext_vector_type(4)));   // MFMA C/D

__device__ __forceinline__ unsigned short f2bf(float f) {
  __hip_bfloat16 h = __float2bfloat16(f);   // RNE
  return *reinterpret_cast<const unsigned short*>(&h);
}
__device__ __forceinline__ float bf2f(unsigned short u) {
  return __uint_as_float(((unsigned int)u) << 16);
}

// async global->LDS, 16B per lane. LDS dest must be (wave-uniform base + lane*16).
__device__ __forceinline__ void gload_lds16(const void* g, void* lds) {
  __builtin_amdgcn_global_load_lds(
      (const __attribute__((address_space(1))) unsigned int*)(uintptr_t)g,
      (__attribute__((address_space(3))) unsigned int*)(unsigned int)(uintptr_t)lds,
      16, 0, 0);
}

// ---------------- f32 -> bf16 conversion (x4 vectorized) ----------------
__global__ __launch_bounds__(256) void conv_bf16(const float* __restrict__ in,
                                                 unsigned short* __restrict__ out,
                                                 int n4) {
  int i = blockIdx.x * 256 + threadIdx.x;
  if (i >= n4) return;
  float4 v = ((const float4*)in)[i];
  ushort4 u;
  u.x = f2bf(v.x); u.y = f2bf(v.y); u.z = f2bf(v.z); u.w = f2bf(v.w);
  ((ushort4*)out)[i] = u;
}

// ---------------- 256x256 deep-pipelined GEMM: C = A * Bt^T ----------------
template <int EPI>
__global__ __launch_bounds__(512, 2) void gemm256(
    const unsigned short* __restrict__ A, const unsigned short* __restrict__ Bt,
    float* __restrict__ Cf, unsigned short* __restrict__ Cb,
    int M, int N, int K) {
  __shared__ unsigned short AB[4][2][8192];   // [ring][A,B][256 rows x 32 k] = 128 KB
  const int tid  = threadIdx.x;
  const int lane = tid & 63;
  const int wv   = tid >> 6;     // 0..7
  const int wr   = wv >> 2;      // 0..1  (M half)
  const int wc   = wv & 3;       // 0..3  (N quarter)
  const int rsel = lane & 15;
  const int g    = lane >> 4;
  const int qr0  = g * 4;

  // bijective XCD swizzle (nwg % 8 == 0 for all our grids)
  int id  = blockIdx.y * gridDim.x + blockIdx.x;
  int cpx = (gridDim.x * gridDim.y) >> 3;
  int swz = (id & 7) * cpx + (id >> 3);
  const int bm = (swz / gridDim.x) * 256;
  const int bn = (swz % gridDim.x) * 256;

  const int NS = K >> 5;   // BK=32 slices

  const int ob0 = tid * 16, ob1 = ob0 + 8192;
  const int row0 = ob0 >> 6, row1 = ob1 >> 6;
  const int g0 = ((ob0 >> 4) & 3) ^ ((row0 >> 1) & 3);
  const int g1 = ((ob1 >> 4) & 3) ^ ((row1 >> 1) & 3);
  const unsigned short* Ag0 = A + (size_t)(bm + row0) * K + g0 * 8;
  const unsigned short* Ag1 = A + (size_t)(bm + row1) * K + g1 * 8;
  const unsigned short* Bg0 = Bt + (size_t)(bn + row0) * K + g0 * 8;
  const unsigned short* Bg1 = Bt + (size_t)(bn + row1) * K + g1 * 8;

  f4_t acc[8][4];
#pragma unroll
  for (int i = 0; i < 8; ++i)
#pragma unroll
    for (int j = 0; j < 4; ++j) acc[i][j] = (f4_t){0.f, 0.f, 0.f, 0.f};

  int aoff[8], boff[4];
#pragma unroll
  for (int i = 0; i < 8; ++i) {
    int arow = wr * 128 + i * 16 + rsel;
    aoff[i] = arow * 64 + ((g * 16) ^ ((arow & 6) << 3));
  }
#pragma unroll
  for (int j = 0; j < 4; ++j) {
    int brow = wc * 64 + j * 16 + rsel;
    boff[j] = brow * 64 + ((g * 16) ^ ((brow & 6) << 3));
  }

#define STAGE(sl)                                                        \
  {                                                                      \
    int slot_ = (sl) & 3;                                                \
    int ks_   = (sl) << 5;                                               \
    gload_lds16(Ag0 + ks_, (char*)&AB[slot_][0][0] + ob0);               \
    gload_lds16(Ag1 + ks_, (char*)&AB[slot_][0][0] + ob1);               \
    gload_lds16(Bg0 + ks_, (char*)&AB[slot_][1][0] + ob0);               \
    gload_lds16(Bg1 + ks_, (char*)&AB[slot_][1][0] + ob1);               \
  }

  STAGE(0); STAGE(1); STAGE(2);   // 12 loads in flight

  for (int s = 0; s < NS; ++s) {
    if (s < NS - 2)       asm volatile("s_waitcnt vmcnt(8)" ::: "memory");
    else if (s == NS - 2) asm volatile("s_waitcnt vmcnt(4)" ::: "memory");
    else                  asm volatile("s_waitcnt vmcnt(0)" ::: "memory");
    __builtin_amdgcn_s_barrier();
    asm volatile("" ::: "memory");

    const char* As_ = (const char*)&AB[s & 3][0][0];
    const char* Bs_ = (const char*)&AB[s & 3][1][0];
    bf8_t af[8], bfr[4];
#pragma unroll
    for (int i = 0; i < 8; ++i) af[i] = *(const bf8_t*)(As_ + aoff[i]);
#pragma unroll
    for (int j = 0; j < 4; ++j) bfr[j] = *(const bf8_t*)(Bs_ + boff[j]);

    if (s + 3 < NS) STAGE(s + 3);   // safe: slot (s+3)&3 last read in iter s-1

    __builtin_amdgcn_s_setprio(1);
#pragma unroll
    for (int i = 0; i < 8; ++i)
#pragma unroll
      for (int j = 0; j < 4; ++j)
        acc[i][j] = __builtin_amdgcn_mfma_f32_16x16x32_bf16(af[i], bfr[j], acc[i][j], 0, 0, 0);
    __builtin_amdgcn_s_setprio(0);
  }
#undef STAGE

#pragma unroll
  for (int i = 0; i < 8; ++i) {
#pragma unroll
    for (int j = 0; j < 4; ++j) {
#pragma unroll
      for (int r = 0; r < 4; ++r) {
        int row = bm + wr * 128 + i * 16 + qr0 + r;
        int col = bn + wc * 64 + j * 16 + rsel;
        float v = acc[i][j][r];
        if (EPI == 0) {
          Cf[(size_t)row * N + col] = v;
        } else {
          int c = col >> 11, h = (col >> 7) & (H_ - 1), dh = col & (DH_ - 1);
          int b = row >> 11, s = row & (S_ - 1);
          size_t dst = ((((size_t)c * B_ + b) * H_ + h) * S_ + s) * DH_ + dh;
          Cb[dst] = f2bf(v);
        }
      }
    }
  }
}

// ---------------- RoPE tables ----------------
__global__ void rope_tab(float* __restrict__ tc, float* __restrict__ ts) {
  int s = blockIdx.x;
  int i = threadIdx.x;   // 64 threads
  float inv = powf(10000.0f, -(float)i / 64.0f);
  float f   = (float)s * inv;
  tc[s * 64 + i] = cosf(f);
  ts[s * 64 + i] = sinf(f);
}

// ---------------- RoPE apply in-place on q and k ([b][h][s][dh] bf16)
__global__ __launch_bounds__(256) void rope_apply(
    unsigned short* __restrict__ Q, unsigned short* __restrict__ Kk,
    const float* __restrict__ tc, const float* __restrict__ ts) {
  int idx  = blockIdx.x * 256 + threadIdx.x;   // 2^24 total
  int i    = idx & 63;
  int s    = (idx >> 6) & (S_ - 1);
  int bh   = (idx >> 17) & 63;
  int tsel = idx >> 23;
  unsigned short* T = tsel ? Kk : Q;
  size_t base = ((size_t)bh * S_ + s) * DH_;
  float x1 = bf2f(T[base + i]);
  float x2 = bf2f(T[base + i + 64]);
  float c  = tc[s * 64 + i], sn = ts[s * 64 + i];
  T[base + i]      = f2bf(x1 * c - x2 * sn);
  T[base + i + 64] = f2bf(x2 * c + x1 * sn);
}

// ---------------- causal flash attention ----------------
// grid (S/128, B*H) XCD-swizzled, 512 thr = 8 waves x 16 q-rows. KVBLK=64.
// K: 3-slot LDS ring, K(t+2) issued AFTER the top barrier (write-after-barrier
// slot safety, gemm256 pattern); top-wait vmcnt(2) steady state (never 0).
// V: reg-staged 1-deep, issued first so its mid-iter compiler wait leaves K
// loads in flight. One barrier per iter, counted drains only.
__global__ __launch_bounds__(512) void attn_fwd(
    const unsigned short* __restrict__ Q, const unsigned short* __restrict__ Kk,
    const unsigned short* __restrict__ V, unsigned short* __restrict__ Z) {
  __shared__ unsigned short Ks[3][64 * 128];  // 48 KB ring, XOR-swizzled (src-side)
  __shared__ unsigned short Vt[2][128 * 64];  // 32 KB, [dh][kv], XOR-swizzled
  __shared__ unsigned short Pw[8][16 * 64];   // 16 KB, per-wave, swizzled
  const int tid  = threadIdx.x;
  const int lane = tid & 63;
  const int wv   = tid >> 6;                  // 0..7

  // XCD swizzle: all 16 q-chunks of a bh land on one XCD (KV L2-resident);
  // within the XCD stream, longest q-chunk first.
  int id = blockIdx.y * gridDim.x + blockIdx.x;   // nwg = 1024
  int sw = (id & 7) * ((gridDim.x * gridDim.y) >> 3) + (id >> 3);
  const int bh = sw >> 4;                     // 16 q-chunks per bh
  const int q0 = (15 - (sw & 15)) * 128;

  const size_t base = (size_t)bh * S_ * DH_;
  const int rsel = lane & 15;
  const int g    = lane >> 4;
  const int kof  = g * 8;
  const int qr0  = g * 4;
  const int qlo  = q0 + wv * 16;
  const int qhi  = qlo + 15;
  const int qrow = qlo + rsel;
  const float sl2 = 0.08838834764831845f * 1.4426950408889634f;  // scale*log2(e)

  bf8_t aq[4];
#pragma unroll
  for (int kc = 0; kc < 4; ++kc) {
    aq[kc] = *(const bf8_t*)&Q[base + (size_t)qrow * DH_ + kc * 32 + kof];
#pragma unroll
    for (int e = 0; e < 8; ++e)
      aq[kc][e] = (short)f2bf(bf2f((unsigned short)aq[kc][e]) * sl2);
  }

  bf8_t vones;
#pragma unroll
  for (int e = 0; e < 8; ++e) vones[e] = (short)0x3F80;

  f4_t o[9];   // o[0..7] = output frags, o[8] = row-sum (softmax denom)
#pragma unroll
  for (int nf = 0; nf < 9; ++nf) o[nf] = (f4_t){0.f, 0.f, 0.f, 0.f};
  float mrow[4] = {-3e30f, -3e30f, -3e30f, -3e30f};
  const int nt = q0 / 64 + 2;   // kv tiles cover [0, q0+128); nt >= 2

  // V staging: one unit/thread: kv rows {2*kvp, 2*kvp+1} x dh [vc0, vc0+8)
  const int kvp = tid & 31;
  const int vc0 = (tid >> 5) * 8;

#define KSTAGE(tt)                                                            \
  {                                                                           \
    const unsigned short* gK_ = Kk + base + (size_t)(tt) * 64 * DH_;          \
    int slot_ = (tt) % 3;                                                     \
    _Pragma("unroll")                                                         \
    for (int c = 0; c < 2; ++c) {                                             \
      int ob = (c * 512 + tid) * 16;                                          \
      int row = ob >> 8;                                                      \
      int scol = (ob & 255) ^ ((row & 7) << 4);                               \
      gload_lds16(gK_ + (size_t)row * DH_ + (scol >> 1),                      \
                  (char*)&Ks[slot_][0] + ob);                                 \
    }                                                                         \
  }
#define VTWRITE(buf_)                                                         \
  {                                                                           \
    unsigned int* Vt32 = (unsigned int*)&Vt[buf_][0];                         \
    _Pragma("unroll")                                                         \
    for (int e = 0; e < 8; ++e) {                                             \
      unsigned int val = (unsigned short)vlo[e] |                             \
                         ((unsigned int)(unsigned short)vhi[e] << 16);        \
      Vt32[(vc0 + e) * 32 + (kvp ^ (e << 2))] = val;                          \
    }                                                                         \
  }

  // ---- prologue: V(0) regs FIRST, then K(0)->slot0, K(1)->slot1 ----
  bf8_t vlo, vhi;
  vlo = *(const bf8_t*)&V[base + (size_t)(2 * kvp) * DH_ + vc0];
  vhi = *(const bf8_t*)&V[base + (size_t)(2 * kvp + 1) * DH_ + vc0];
  KSTAGE(0);
  KSTAGE(1);              // nt >= 2 always
  VTWRITE(0);             // compiler waits V(0) only; K loads stay in flight

  for (int t = 0; t < nt; ++t) {
    const int curV = t & 1;
    const int curK = t % 3;
    const bool pfV = (t + 1 < nt);
    const bool pfK = (t + 2 < nt);

    // ---- top: counted drain (K(t) landed; K(t+1) stays in flight), sync ----
    if (pfV) asm volatile("s_waitcnt vmcnt(2)" ::: "memory");
    else     asm volatile("s_waitcnt vmcnt(0)" ::: "memory");
    asm volatile("s_waitcnt lgkmcnt(0)" ::: "memory");
    __builtin_amdgcn_s_barrier();
    asm volatile("" ::: "memory");

    // ---- issue next loads AFTER barrier (slot last read in iter t-1) ----
    if (pfV) {
      const unsigned short* gV = V + base + (size_t)(t + 1) * 64 * DH_;
      vlo = *(const bf8_t*)&gV[(size_t)(2 * kvp) * DH_ + vc0];
      vhi = *(const bf8_t*)&gV[(size_t)(2 * kvp + 1) * DH_ + vc0];
    }
    if (pfK) KSTAGE(t + 2);

    const int kv0 = t * 64;
    const bool active = (kv0 <= qhi);
    const bool domask = active && (kv0 + 63 > qlo);

    if (active) {
      // ---- S = Q K^T  (Q pre-scaled: result in log2 domain) ----
      f4_t sacc[4];
#pragma unroll
      for (int cf = 0; cf < 4; ++cf) sacc[cf] = (f4_t){0.f, 0.f, 0.f, 0.f};
      __builtin_amdgcn_s_setprio(1);
#pragma unroll
      for (int cf = 0; cf < 4; ++cf)
#pragma unroll
        for (int kc = 0; kc < 4; ++kc) {
          int krow = cf * 16 + rsel;
          bf8_t bk = *(const bf8_t*)&Ks[curK][krow * 128 + ((kc * 32 + kof) ^ ((krow & 7) << 3))];
          sacc[cf] = __builtin_amdgcn_mfma_f32_16x16x32_bf16(aq[kc], bk, sacc[cf], 0, 0, 0);
        }
      __builtin_amdgcn_s_setprio(0);

      if (domask) {
#pragma unroll
        for (int cf = 0; cf < 4; ++cf) {
          int kvabs = kv0 + cf * 16 + rsel;
#pragma unroll
          for (int r = 0; r < 4; ++r) {
            int qabs = qlo + qr0 + r;
            if (kvabs > qabs) sacc[cf][r] = -3e30f;
          }
        }
      }

      // ---- defer-max softmax: common path has NO cross-lane reduction ----
      float tmr[4];
#pragma unroll
      for (int r = 0; r < 4; ++r)
        tmr[r] = fmaxf(fmaxf(sacc[0][r], sacc[1][r]), fmaxf(sacc[2][r], sacc[3][r]));
      bool needr = (tmr[0] > mrow[0] + 11.f) || (tmr[1] > mrow[1] + 11.f) ||
                   (tmr[2] > mrow[2] + 11.f) || (tmr[3] > mrow[3] + 11.f);
      if (__any(needr)) {
#pragma unroll
        for (int r = 0; r < 4; ++r) {
          float m = tmr[r];
#pragma unroll
          for (int d = 1; d < 16; d <<= 1) m = fmaxf(m, __shfl_xor(m, d, 16));
          float nm = fmaxf(mrow[r], m);
          float sc = exp2f(mrow[r] - nm);
          mrow[r] = nm;
#pragma unroll
          for (int nf = 0; nf < 9; ++nf) o[nf][r] *= sc;
        }
      }
#pragma unroll
      for (int cf = 0; cf < 4; ++cf)
#pragma unroll
        for (int r = 0; r < 4; ++r)
          sacc[cf][r] = exp2f(sacc[cf][r] - mrow[r]);

      // ---- P -> per-wave LDS (swizzle ((prow>>1)<<3)) ----
      unsigned short* P = &Pw[wv][0];
#pragma unroll
      for (int cf = 0; cf < 4; ++cf)
#pragma unroll
        for (int r = 0; r < 4; ++r) {
          int prow = qr0 + r;
          P[prow * 64 + ((cf * 16 + rsel) ^ ((prow >> 1) << 3))] = f2bf(sacc[cf][r]);
        }
    }

    // ---- write V(t+1) into Vt[nxt] (last read in iter t-1; barrier-safe) ----
    if (pfV) VTWRITE(curV ^ 1);

    if (active) {
      // ---- O += P V ; denominator rides as o[8] = P x ones ----
      unsigned short* P = &Pw[wv][0];
      __builtin_amdgcn_s_setprio(1);
#pragma unroll
      for (int kc2 = 0; kc2 < 2; ++kc2) {
        bf8_t pa = *(const bf8_t*)&P[rsel * 64 + ((kc2 * 32 + kof) ^ ((rsel >> 1) << 3))];
#pragma unroll
        for (int nf = 0; nf < 8; ++nf) {
          int vrow = nf * 16 + rsel;
          bf8_t bv = *(const bf8_t*)&Vt[curV][vrow * 64 + ((kc2 * 32 + kof) ^ ((vrow & 7) << 3))];
          o[nf] = __builtin_amdgcn_mfma_f32_16x16x32_bf16(pa, bv, o[nf], 0, 0, 0);
        }
        o[8] = __builtin_amdgcn_mfma_f32_16x16x32_bf16(pa, vones, o[8], 0, 0, 0);
      }
      __builtin_amdgcn_s_setprio(0);
    }
  }
#undef KSTAGE
#undef VTWRITE

  const int b = bh >> 4, h = bh & 15;
#pragma unroll
  for (int r = 0; r < 4; ++r) {
    float inv = 1.0f / o[8][r];
    int s = qlo + qr0 + r;
    size_t rowo = ((size_t)b * S_ + s) * D_ + h * DH_;
#pragma unroll
    for (int nf = 0; nf < 8; ++nf)
      Z[rowo + nf * 16 + rsel] = f2bf(o[nf][r] * inv);
  }
}

// ---------------- orchestration ----------------
extern "C" void kernel_launch(void* const* d_in, const int* in_sizes, int n_in,
                              void* d_out, int out_size, void* d_ws, size_t ws_size,
                              hipStream_t stream) {
  const float* x    = (const float*)d_in[0];
  const float* Wqkv = (const float*)d_in[1];
  const float* Wo   = (const float*)d_in[2];
  float* out = (float*)d_out;

  const size_t QKV_ELEMS = (size_t)B_ * H_ * S_ * DH_;
  char* w = (char*)d_ws;
  unsigned short* xb = (unsigned short*)w;   // x bf16; z aliases it later
  unsigned short* z  = xb;
  w += (size_t)8192 * 2048 * 2;
  unsigned short* wqkvb = (unsigned short*)w; w += (size_t)6144 * 2048 * 2;
  unsigned short* wob   = (unsigned short*)w; w += (size_t)2048 * 2048 * 2;
  unsigned short* qq = (unsigned short*)w;    w += QKV_ELEMS * 2;
  unsigned short* kk = (unsigned short*)w;    w += QKV_ELEMS * 2;
  unsigned short* vv = (unsigned short*)w;    w += QKV_ELEMS * 2;
  float* tabc = (float*)w; w += (size_t)S_ * 64 * 4;
  float* tabs = (float*)w; w += (size_t)S_ * 64 * 4;
  if ((size_t)(w - (char*)d_ws) > ws_size) return;

  conv_bf16<<<16384, 256, 0, stream>>>(x, xb, 8192 * 2048 / 4);
  conv_bf16<<<12288, 256, 0, stream>>>(Wqkv, wqkvb, 6144 * 2048 / 4);
  conv_bf16<<<4096, 256, 0, stream>>>(Wo, wob, 2048 * 2048 / 4);
  gemm256<1><<<dim3(24, 32), 512, 0, stream>>>(xb, wqkvb, nullptr, qq, 8192, 6144, 2048);
  rope_tab<<<2048, 64, 0, stream>>>(tabc, tabs);
  rope_apply<<<65536, 256, 0, stream>>>(qq, kk, tabc, tabs);
  attn_fwd<<<dim3(S_ / 128, B_ * H_), 512, 0, stream>>>(qq, kk, vv, z);
  gemm256<0><<<dim3(8, 32), 512, 0, stream>>>(z, wob, out, nullptr, 8192, 2048, 2048);
}

// Round 10
// 431.130 us; speedup vs baseline: 3.1523x; 1.1497x over previous
//
#include <hip/hip_runtime.h>
#include <hip/hip_bf16.h>
#include <stdint.h>

#define B_ 4
#define S_ 2048
#define D_ 2048
#define H_ 16
#define DH_ 128

typedef short bf8_t __attribute__((ext_vector_type(8)));   // 8 bf16 (4 VGPRs)
typedef float f4_t  __attribute__((ext_vector_type(4)));   // MFMA C/D

__device__ __forceinline__ unsigned short f2bf(float f) {
  __hip_bfloat16 h = __float2bfloat16(f);   // RNE
  return *reinterpret_cast<const unsigned short*>(&h);
}
__device__ __forceinline__ float bf2f(unsigned short u) {
  return __uint_as_float(((unsigned int)u) << 16);
}

// async global->LDS, 16B per lane. LDS dest must be (wave-uniform base + lane*16).
__device__ __forceinline__ void gload_lds16(const void* g, void* lds) {
  __builtin_amdgcn_global_load_lds(
      (const __attribute__((address_space(1))) unsigned int*)(uintptr_t)g,
      (__attribute__((address_space(3))) unsigned int*)(unsigned int)(uintptr_t)lds,
      16, 0, 0);
}

// ---------------- f32 -> bf16 conversion (x4 vectorized) ----------------
__global__ __launch_bounds__(256) void conv_bf16(const float* __restrict__ in,
                                                 unsigned short* __restrict__ out,
                                                 int n4) {
  int i = blockIdx.x * 256 + threadIdx.x;
  if (i >= n4) return;
  float4 v = ((const float4*)in)[i];
  ushort4 u;
  u.x = f2bf(v.x); u.y = f2bf(v.y); u.z = f2bf(v.z); u.w = f2bf(v.w);
  ((ushort4*)out)[i] = u;
}

// ---------------- 256x256 deep-pipelined GEMM: C = A * Bt^T ----------------
template <int EPI>
__global__ __launch_bounds__(512, 2) void gemm256(
    const unsigned short* __restrict__ A, const unsigned short* __restrict__ Bt,
    float* __restrict__ Cf, unsigned short* __restrict__ Cb,
    int M, int N, int K) {
  __shared__ unsigned short AB[4][2][8192];   // [ring][A,B][256 rows x 32 k] = 128 KB
  const int tid  = threadIdx.x;
  const int lane = tid & 63;
  const int wv   = tid >> 6;     // 0..7
  const int wr   = wv >> 2;      // 0..1  (M half)
  const int wc   = wv & 3;       // 0..3  (N quarter)
  const int rsel = lane & 15;
  const int g    = lane >> 4;
  const int qr0  = g * 4;

  // bijective XCD swizzle (nwg % 8 == 0 for all our grids)
  int id  = blockIdx.y * gridDim.x + blockIdx.x;
  int cpx = (gridDim.x * gridDim.y) >> 3;
  int swz = (id & 7) * cpx + (id >> 3);
  const int bm = (swz / gridDim.x) * 256;
  const int bn = (swz % gridDim.x) * 256;

  const int NS = K >> 5;   // BK=32 slices

  const int ob0 = tid * 16, ob1 = ob0 + 8192;
  const int row0 = ob0 >> 6, row1 = ob1 >> 6;
  const int g0 = ((ob0 >> 4) & 3) ^ ((row0 >> 1) & 3);
  const int g1 = ((ob1 >> 4) & 3) ^ ((row1 >> 1) & 3);
  const unsigned short* Ag0 = A + (size_t)(bm + row0) * K + g0 * 8;
  const unsigned short* Ag1 = A + (size_t)(bm + row1) * K + g1 * 8;
  const unsigned short* Bg0 = Bt + (size_t)(bn + row0) * K + g0 * 8;
  const unsigned short* Bg1 = Bt + (size_t)(bn + row1) * K + g1 * 8;

  f4_t acc[8][4];
#pragma unroll
  for (int i = 0; i < 8; ++i)
#pragma unroll
    for (int j = 0; j < 4; ++j) acc[i][j] = (f4_t){0.f, 0.f, 0.f, 0.f};

  int aoff[8], boff[4];
#pragma unroll
  for (int i = 0; i < 8; ++i) {
    int arow = wr * 128 + i * 16 + rsel;
    aoff[i] = arow * 64 + ((g * 16) ^ ((arow & 6) << 3));
  }
#pragma unroll
  for (int j = 0; j < 4; ++j) {
    int brow = wc * 64 + j * 16 + rsel;
    boff[j] = brow * 64 + ((g * 16) ^ ((brow & 6) << 3));
  }

#define STAGE(sl)                                                        \
  {                                                                      \
    int slot_ = (sl) & 3;                                                \
    int ks_   = (sl) << 5;                                               \
    gload_lds16(Ag0 + ks_, (char*)&AB[slot_][0][0] + ob0);               \
    gload_lds16(Ag1 + ks_, (char*)&AB[slot_][0][0] + ob1);               \
    gload_lds16(Bg0 + ks_, (char*)&AB[slot_][1][0] + ob0);               \
    gload_lds16(Bg1 + ks_, (char*)&AB[slot_][1][0] + ob1);               \
  }

  STAGE(0); STAGE(1); STAGE(2);   // 12 loads in flight

  for (int s = 0; s < NS; ++s) {
    if (s < NS - 2)       asm volatile("s_waitcnt vmcnt(8)" ::: "memory");
    else if (s == NS - 2) asm volatile("s_waitcnt vmcnt(4)" ::: "memory");
    else                  asm volatile("s_waitcnt vmcnt(0)" ::: "memory");
    __builtin_amdgcn_s_barrier();
    asm volatile("" ::: "memory");

    const char* As_ = (const char*)&AB[s & 3][0][0];
    const char* Bs_ = (const char*)&AB[s & 3][1][0];
    bf8_t af[8], bfr[4];
#pragma unroll
    for (int i = 0; i < 8; ++i) af[i] = *(const bf8_t*)(As_ + aoff[i]);
#pragma unroll
    for (int j = 0; j < 4; ++j) bfr[j] = *(const bf8_t*)(Bs_ + boff[j]);

    if (s + 3 < NS) STAGE(s + 3);   // safe: slot (s+3)&3 last read in iter s-1

    __builtin_amdgcn_s_setprio(1);
#pragma unroll
    for (int i = 0; i < 8; ++i)
#pragma unroll
      for (int j = 0; j < 4; ++j)
        acc[i][j] = __builtin_amdgcn_mfma_f32_16x16x32_bf16(af[i], bfr[j], acc[i][j], 0, 0, 0);
    __builtin_amdgcn_s_setprio(0);
  }
#undef STAGE

#pragma unroll
  for (int i = 0; i < 8; ++i) {
#pragma unroll
    for (int j = 0; j < 4; ++j) {
#pragma unroll
      for (int r = 0; r < 4; ++r) {
        int row = bm + wr * 128 + i * 16 + qr0 + r;
        int col = bn + wc * 64 + j * 16 + rsel;
        float v = acc[i][j][r];
        if (EPI == 0) {
          Cf[(size_t)row * N + col] = v;
        } else {
          int c = col >> 11, h = (col >> 7) & (H_ - 1), dh = col & (DH_ - 1);
          int b = row >> 11, s = row & (S_ - 1);
          size_t dst = ((((size_t)c * B_ + b) * H_ + h) * S_ + s) * DH_ + dh;
          Cb[dst] = f2bf(v);
        }
      }
    }
  }
}

// ---------------- RoPE tables ----------------
__global__ void rope_tab(float* __restrict__ tc, float* __restrict__ ts) {
  int s = blockIdx.x;
  int i = threadIdx.x;   // 64 threads
  float inv = powf(10000.0f, -(float)i / 64.0f);
  float f   = (float)s * inv;
  tc[s * 64 + i] = cosf(f);
  ts[s * 64 + i] = sinf(f);
}

// ---------------- RoPE apply in-place on q and k ([b][h][s][dh] bf16)
__global__ __launch_bounds__(256) void rope_apply(
    unsigned short* __restrict__ Q, unsigned short* __restrict__ Kk,
    const float* __restrict__ tc, const float* __restrict__ ts) {
  int idx  = blockIdx.x * 256 + threadIdx.x;   // 2^24 total
  int i    = idx & 63;
  int s    = (idx >> 6) & (S_ - 1);
  int bh   = (idx >> 17) & 63;
  int tsel = idx >> 23;
  unsigned short* T = tsel ? Kk : Q;
  size_t base = ((size_t)bh * S_ + s) * DH_;
  float x1 = bf2f(T[base + i]);
  float x2 = bf2f(T[base + i + 64]);
  float c  = tc[s * 64 + i], sn = ts[s * 64 + i];
  T[base + i]      = f2bf(x1 * c - x2 * sn);
  T[base + i + 64] = f2bf(x2 * c + x1 * sn);
}

// ---------------- causal flash attention ----------------
// grid 512 blocks (8 q-chunks x B*H), 512 thr = 8 waves x 32 q-rows (QBLK=256).
// Each wave owns TWO 16-row groups: every K/V B-fragment read feeds 2 MFMAs
// (halves LDS bytes per MFMA — the r9 bottleneck), and each staged K/V tile
// feeds 256 q-rows (halves tile-iteration count). K: 3-slot ring, counted
// vmcnt (never 0 in steady state); V: reg-staged 1-deep. XCD swizzle keeps
// all 8 chunks of a bh on one XCD (KV L2-resident), chunk-major longest-first.
__global__ __launch_bounds__(512) void attn_fwd(
    const unsigned short* __restrict__ Q, const unsigned short* __restrict__ Kk,
    const unsigned short* __restrict__ V, unsigned short* __restrict__ Z) {
  __shared__ unsigned short Ks[3][64 * 128];  // 48 KB ring, XOR-swizzled (src-side)
  __shared__ unsigned short Vt[2][128 * 64];  // 32 KB, [dh][kv], XOR-swizzled
  __shared__ unsigned short Pw[8][32 * 64];   // 32 KB, per-wave 32 rows, swizzled
  const int tid  = threadIdx.x;
  const int lane = tid & 63;
  const int wv   = tid >> 6;                  // 0..7

  // XCD swizzle: id&7 = XCD stream; within it, 8 bh x 8 chunks, chunk-major
  // (longest chunks of all bh first -> 2-round CU pairing long+short).
  int id  = blockIdx.y * gridDim.x + blockIdx.x;   // nwg = 512
  int x   = id & 7;
  int idx = id >> 3;                               // 0..63
  const int bh = x * 8 + (idx & 7);
  const int q0 = (7 - (idx >> 3)) * 256;

  const size_t base = (size_t)bh * S_ * DH_;
  const int rsel = lane & 15;
  const int g    = lane >> 4;
  const int kof  = g * 8;
  const int qr0  = g * 4;
  const int qlo  = q0 + wv * 32;
  const int qhi  = qlo + 31;
  const float sl2 = 0.08838834764831845f * 1.4426950408889634f;  // scale*log2(e)

  // Q A-frags for both row-groups, pre-scaled by sl2
  bf8_t aq[2][4];
#pragma unroll
  for (int rg = 0; rg < 2; ++rg) {
    const int qrow = qlo + rg * 16 + rsel;
#pragma unroll
    for (int kc = 0; kc < 4; ++kc) {
      aq[rg][kc] = *(const bf8_t*)&Q[base + (size_t)qrow * DH_ + kc * 32 + kof];
#pragma unroll
      for (int e = 0; e < 8; ++e)
        aq[rg][kc][e] = (short)f2bf(bf2f((unsigned short)aq[rg][kc][e]) * sl2);
    }
  }

  bf8_t vones;
#pragma unroll
  for (int e = 0; e < 8; ++e) vones[e] = (short)0x3F80;

  f4_t o[2][9];   // [rg][0..7]=output frags, [rg][8]=row-sum (denominator)
#pragma unroll
  for (int rg = 0; rg < 2; ++rg)
#pragma unroll
    for (int nf = 0; nf < 9; ++nf) o[rg][nf] = (f4_t){0.f, 0.f, 0.f, 0.f};
  float mrow[2][4] = {{-3e30f, -3e30f, -3e30f, -3e30f},
                      {-3e30f, -3e30f, -3e30f, -3e30f}};
  const int nt = q0 / 64 + 4;   // kv tiles cover [0, q0+256); nt >= 4

  // V staging: one unit/thread: kv rows {2*kvp, 2*kvp+1} x dh [vc0, vc0+8)
  const int kvp = tid & 31;
  const int vc0 = (tid >> 5) * 8;

#define KSTAGE(tt)                                                            \
  {                                                                           \
    const unsigned short* gK_ = Kk + base + (size_t)(tt) * 64 * DH_;          \
    int slot_ = (tt) % 3;                                                     \
    _Pragma("unroll")                                                         \
    for (int c = 0; c < 2; ++c) {                                             \
      int ob = (c * 512 + tid) * 16;                                          \
      int row = ob >> 8;                                                      \
      int scol = (ob & 255) ^ ((row & 7) << 4);                               \
      gload_lds16(gK_ + (size_t)row * DH_ + (scol >> 1),                      \
                  (char*)&Ks[slot_][0] + ob);                                 \
    }                                                                         \
  }
#define VTWRITE(buf_)                                                         \
  {                                                                           \
    unsigned int* Vt32 = (unsigned int*)&Vt[buf_][0];                         \
    _Pragma("unroll")                                                         \
    for (int e = 0; e < 8; ++e) {                                             \
      unsigned int val = (unsigned short)vlo[e] |                             \
                         ((unsigned int)(unsigned short)vhi[e] << 16);        \
      Vt32[(vc0 + e) * 32 + (kvp ^ (e << 2))] = val;                          \
    }                                                                         \
  }

  // ---- prologue: V(0) regs FIRST, then K(0)->slot0, K(1)->slot1 ----
  bf8_t vlo, vhi;
  vlo = *(const bf8_t*)&V[base + (size_t)(2 * kvp) * DH_ + vc0];
  vhi = *(const bf8_t*)&V[base + (size_t)(2 * kvp + 1) * DH_ + vc0];
  KSTAGE(0);
  KSTAGE(1);              // nt >= 4 always
  VTWRITE(0);             // compiler waits V(0) only; K loads stay in flight

  for (int t = 0; t < nt; ++t) {
    const int curV = t & 1;
    const int curK = t % 3;
    const bool pfV = (t + 1 < nt);
    const bool pfK = (t + 2 < nt);

    // ---- top: counted drain (K(t) landed; K(t+1) stays in flight), sync ----
    if (pfV) asm volatile("s_waitcnt vmcnt(2)" ::: "memory");
    else     asm volatile("s_waitcnt vmcnt(0)" ::: "memory");
    asm volatile("s_waitcnt lgkmcnt(0)" ::: "memory");
    __builtin_amdgcn_s_barrier();
    asm volatile("" ::: "memory");

    // ---- issue next loads AFTER barrier (slot last read in iter t-1) ----
    if (pfV) {
      const unsigned short* gV = V + base + (size_t)(t + 1) * 64 * DH_;
      vlo = *(const bf8_t*)&gV[(size_t)(2 * kvp) * DH_ + vc0];
      vhi = *(const bf8_t*)&gV[(size_t)(2 * kvp + 1) * DH_ + vc0];
    }
    if (pfK) KSTAGE(t + 2);

    const int kv0 = t * 64;
    const bool active = (kv0 <= qhi);
    const bool domask = active && (kv0 + 63 > qlo);

    if (active) {
      // ---- S = Q K^T for both row-groups (bk shared) ----
      f4_t sacc[2][4];
#pragma unroll
      for (int rg = 0; rg < 2; ++rg)
#pragma unroll
        for (int cf = 0; cf < 4; ++cf) sacc[rg][cf] = (f4_t){0.f, 0.f, 0.f, 0.f};
      __builtin_amdgcn_s_setprio(1);
#pragma unroll
      for (int cf = 0; cf < 4; ++cf)
#pragma unroll
        for (int kc = 0; kc < 4; ++kc) {
          int krow = cf * 16 + rsel;
          bf8_t bk = *(const bf8_t*)&Ks[curK][krow * 128 + ((kc * 32 + kof) ^ ((krow & 7) << 3))];
          sacc[0][cf] = __builtin_amdgcn_mfma_f32_16x16x32_bf16(aq[0][kc], bk, sacc[0][cf], 0, 0, 0);
          sacc[1][cf] = __builtin_amdgcn_mfma_f32_16x16x32_bf16(aq[1][kc], bk, sacc[1][cf], 0, 0, 0);
        }
      __builtin_amdgcn_s_setprio(0);

      if (domask) {
#pragma unroll
        for (int rg = 0; rg < 2; ++rg)
#pragma unroll
          for (int cf = 0; cf < 4; ++cf) {
            int kvabs = kv0 + cf * 16 + rsel;
#pragma unroll
            for (int r = 0; r < 4; ++r) {
              int qabs = qlo + rg * 16 + qr0 + r;
              if (kvabs > qabs) sacc[rg][cf][r] = -3e30f;
            }
          }
      }

      // ---- defer-max softmax: common path has NO cross-lane reduction ----
      float tmr[2][4];
      bool needr = false;
#pragma unroll
      for (int rg = 0; rg < 2; ++rg)
#pragma unroll
        for (int r = 0; r < 4; ++r) {
          tmr[rg][r] = fmaxf(fmaxf(sacc[rg][0][r], sacc[rg][1][r]),
                             fmaxf(sacc[rg][2][r], sacc[rg][3][r]));
          needr = needr || (tmr[rg][r] > mrow[rg][r] + 11.f);
        }
      if (__any(needr)) {
#pragma unroll
        for (int rg = 0; rg < 2; ++rg)
#pragma unroll
          for (int r = 0; r < 4; ++r) {
            float m = tmr[rg][r];
#pragma unroll
            for (int d = 1; d < 16; d <<= 1) m = fmaxf(m, __shfl_xor(m, d, 16));
            float nm = fmaxf(mrow[rg][r], m);
            float sc = exp2f(mrow[rg][r] - nm);
            mrow[rg][r] = nm;
#pragma unroll
            for (int nf = 0; nf < 9; ++nf) o[rg][nf][r] *= sc;
          }
      }
#pragma unroll
      for (int rg = 0; rg < 2; ++rg)
#pragma unroll
        for (int cf = 0; cf < 4; ++cf)
#pragma unroll
          for (int r = 0; r < 4; ++r)
            sacc[rg][cf][r] = exp2f(sacc[rg][cf][r] - mrow[rg][r]);

      // ---- P -> per-wave LDS (32 rows, swizzle (((prow>>1)&7)<<3)) ----
      unsigned short* P = &Pw[wv][0];
#pragma unroll
      for (int rg = 0; rg < 2; ++rg)
#pragma unroll
        for (int cf = 0; cf < 4; ++cf)
#pragma unroll
          for (int r = 0; r < 4; ++r) {
            int prow = rg * 16 + qr0 + r;
            P[prow * 64 + ((cf * 16 + rsel) ^ (((prow >> 1) & 7) << 3))] = f2bf(sacc[rg][cf][r]);
          }
    }

    // ---- write V(t+1) into Vt[nxt] (last read in iter t-1; barrier-safe) ----
    if (pfV) VTWRITE(curV ^ 1);

    if (active) {
      // ---- O += P V for both row-groups (bv shared); denom rides o[rg][8] ----
      unsigned short* P = &Pw[wv][0];
      __builtin_amdgcn_s_setprio(1);
#pragma unroll
      for (int kc2 = 0; kc2 < 2; ++kc2) {
        bf8_t pa0, pa1;
        {
          int pr0 = rsel;           // rg 0
          int pr1 = 16 + rsel;      // rg 1
          pa0 = *(const bf8_t*)&P[pr0 * 64 + ((kc2 * 32 + kof) ^ (((pr0 >> 1) & 7) << 3))];
          pa1 = *(const bf8_t*)&P[pr1 * 64 + ((kc2 * 32 + kof) ^ (((pr1 >> 1) & 7) << 3))];
        }
#pragma unroll
        for (int nf = 0; nf < 8; ++nf) {
          int vrow = nf * 16 + rsel;
          bf8_t bv = *(const bf8_t*)&Vt[curV][vrow * 64 + ((kc2 * 32 + kof) ^ ((vrow & 7) << 3))];
          o[0][nf] = __builtin_amdgcn_mfma_f32_16x16x32_bf16(pa0, bv, o[0][nf], 0, 0, 0);
          o[1][nf] = __builtin_amdgcn_mfma_f32_16x16x32_bf16(pa1, bv, o[1][nf], 0, 0, 0);
        }
        o[0][8] = __builtin_amdgcn_mfma_f32_16x16x32_bf16(pa0, vones, o[0][8], 0, 0, 0);
        o[1][8] = __builtin_amdgcn_mfma_f32_16x16x32_bf16(pa1, vones, o[1][8], 0, 0, 0);
      }
      __builtin_amdgcn_s_setprio(0);
    }
  }
#undef KSTAGE
#undef VTWRITE

  const int b = bh >> 4, h = bh & 15;
#pragma unroll
  for (int rg = 0; rg < 2; ++rg)
#pragma unroll
    for (int r = 0; r < 4; ++r) {
      float inv = 1.0f / o[rg][8][r];
      int s = qlo + rg * 16 + qr0 + r;
      size_t rowo = ((size_t)b * S_ + s) * D_ + h * DH_;
#pragma unroll
      for (int nf = 0; nf < 8; ++nf)
        Z[rowo + nf * 16 + rsel] = f2bf(o[rg][nf][r] * inv);
    }
}

// ---------------- orchestration ----------------
extern "C" void kernel_launch(void* const* d_in, const int* in_sizes, int n_in,
                              void* d_out, int out_size, void* d_ws, size_t ws_size,
                              hipStream_t stream) {
  const float* x    = (const float*)d_in[0];
  const float* Wqkv = (const float*)d_in[1];
  const float* Wo   = (const float*)d_in[2];
  float* out = (float*)d_out;

  const size_t QKV_ELEMS = (size_t)B_ * H_ * S_ * DH_;
  char* w = (char*)d_ws;
  unsigned short* xb = (unsigned short*)w;   // x bf16; z aliases it later
  unsigned short* z  = xb;
  w += (size_t)8192 * 2048 * 2;
  unsigned short* wqkvb = (unsigned short*)w; w += (size_t)6144 * 2048 * 2;
  unsigned short* wob   = (unsigned short*)w; w += (size_t)2048 * 2048 * 2;
  unsigned short* qq = (unsigned short*)w;    w += QKV_ELEMS * 2;
  unsigned short* kk = (unsigned short*)w;    w += QKV_ELEMS * 2;
  unsigned short* vv = (unsigned short*)w;    w += QKV_ELEMS * 2;
  float* tabc = (float*)w; w += (size_t)S_ * 64 * 4;
  float* tabs = (float*)w; w += (size_t)S_ * 64 * 4;
  if ((size_t)(w - (char*)d_ws) > ws_size) return;

  conv_bf16<<<16384, 256, 0, stream>>>(x, xb, 8192 * 2048 / 4);
  conv_bf16<<<12288, 256, 0, stream>>>(Wqkv, wqkvb, 6144 * 2048 / 4);
  conv_bf16<<<4096, 256, 0, stream>>>(Wo, wob, 2048 * 2048 / 4);
  gemm256<1><<<dim3(24, 32), 512, 0, stream>>>(xb, wqkvb, nullptr, qq, 8192, 6144, 2048);
  rope_tab<<<2048, 64, 0, stream>>>(tabc, tabs);
  rope_apply<<<65536, 256, 0, stream>>>(qq, kk, tabc, tabs);
  attn_fwd<<<dim3(S_ / 256, B_ * H_), 512, 0, stream>>>(qq, kk, vv, z);
  gemm256<0><<<dim3(8, 32), 512, 0, stream>>>(z, wob, out, nullptr, 8192, 2048, 2048);
}

// Round 11
// 419.129 us; speedup vs baseline: 3.2425x; 1.0286x over previous
//
#include <hip/hip_runtime.h>
#include <hip/hip_bf16.h>
#include <stdint.h>

#define B_ 4
#define S_ 2048
#define D_ 2048
#define H_ 16
#define DH_ 128

typedef short bf8_t __attribute__((ext_vector_type(8)));   // 8 bf16 (4 VGPRs)
typedef float f4_t  __attribute__((ext_vector_type(4)));   // MFMA C/D

__device__ __forceinline__ unsigned short f2bf(float f) {
  __hip_bfloat16 h = __float2bfloat16(f);   // RNE
  return *reinterpret_cast<const unsigned short*>(&h);
}
__device__ __forceinline__ float bf2f(unsigned short u) {
  return __uint_as_float(((unsigned int)u) << 16);
}

// async global->LDS, 16B per lane. LDS dest must be (wave-uniform base + lane*16).
__device__ __forceinline__ void gload_lds16(const void* g, void* lds) {
  __builtin_amdgcn_global_load_lds(
      (const __attribute__((address_space(1))) unsigned int*)(uintptr_t)g,
      (__attribute__((address_space(3))) unsigned int*)(unsigned int)(uintptr_t)lds,
      16, 0, 0);
}

// ---------------- f32 -> bf16 conversion (x4 vectorized) ----------------
__global__ __launch_bounds__(256) void conv_bf16(const float* __restrict__ in,
                                                 unsigned short* __restrict__ out,
                                                 int n4) {
  int i = blockIdx.x * 256 + threadIdx.x;
  if (i >= n4) return;
  float4 v = ((const float4*)in)[i];
  ushort4 u;
  u.x = f2bf(v.x); u.y = f2bf(v.y); u.z = f2bf(v.z); u.w = f2bf(v.w);
  ((ushort4*)out)[i] = u;
}

// ---------------- 256x256 deep-pipelined GEMM: C = A * Bt^T ----------------
template <int EPI>
__global__ __launch_bounds__(512, 2) void gemm256(
    const unsigned short* __restrict__ A, const unsigned short* __restrict__ Bt,
    float* __restrict__ Cf, unsigned short* __restrict__ Cb,
    int M, int N, int K) {
  __shared__ unsigned short AB[4][2][8192];   // [ring][A,B][256 rows x 32 k] = 128 KB
  const int tid  = threadIdx.x;
  const int lane = tid & 63;
  const int wv   = tid >> 6;     // 0..7
  const int wr   = wv >> 2;      // 0..1  (M half)
  const int wc   = wv & 3;       // 0..3  (N quarter)
  const int rsel = lane & 15;
  const int g    = lane >> 4;
  const int qr0  = g * 4;

  // bijective XCD swizzle (nwg % 8 == 0 for all our grids)
  int id  = blockIdx.y * gridDim.x + blockIdx.x;
  int cpx = (gridDim.x * gridDim.y) >> 3;
  int swz = (id & 7) * cpx + (id >> 3);
  const int bm = (swz / gridDim.x) * 256;
  const int bn = (swz % gridDim.x) * 256;

  const int NS = K >> 5;   // BK=32 slices

  const int ob0 = tid * 16, ob1 = ob0 + 8192;
  const int row0 = ob0 >> 6, row1 = ob1 >> 6;
  const int g0 = ((ob0 >> 4) & 3) ^ ((row0 >> 1) & 3);
  const int g1 = ((ob1 >> 4) & 3) ^ ((row1 >> 1) & 3);
  const unsigned short* Ag0 = A + (size_t)(bm + row0) * K + g0 * 8;
  const unsigned short* Ag1 = A + (size_t)(bm + row1) * K + g1 * 8;
  const unsigned short* Bg0 = Bt + (size_t)(bn + row0) * K + g0 * 8;
  const unsigned short* Bg1 = Bt + (size_t)(bn + row1) * K + g1 * 8;

  f4_t acc[8][4];
#pragma unroll
  for (int i = 0; i < 8; ++i)
#pragma unroll
    for (int j = 0; j < 4; ++j) acc[i][j] = (f4_t){0.f, 0.f, 0.f, 0.f};

  int aoff[8], boff[4];
#pragma unroll
  for (int i = 0; i < 8; ++i) {
    int arow = wr * 128 + i * 16 + rsel;
    aoff[i] = arow * 64 + ((g * 16) ^ ((arow & 6) << 3));
  }
#pragma unroll
  for (int j = 0; j < 4; ++j) {
    int brow = wc * 64 + j * 16 + rsel;
    boff[j] = brow * 64 + ((g * 16) ^ ((brow & 6) << 3));
  }

#define STAGE(sl)                                                        \
  {                                                                      \
    int slot_ = (sl) & 3;                                                \
    int ks_   = (sl) << 5;                                               \
    gload_lds16(Ag0 + ks_, (char*)&AB[slot_][0][0] + ob0);               \
    gload_lds16(Ag1 + ks_, (char*)&AB[slot_][0][0] + ob1);               \
    gload_lds16(Bg0 + ks_, (char*)&AB[slot_][1][0] + ob0);               \
    gload_lds16(Bg1 + ks_, (char*)&AB[slot_][1][0] + ob1);               \
  }

  STAGE(0); STAGE(1); STAGE(2);   // 12 loads in flight

  for (int s = 0; s < NS; ++s) {
    if (s < NS - 2)       asm volatile("s_waitcnt vmcnt(8)" ::: "memory");
    else if (s == NS - 2) asm volatile("s_waitcnt vmcnt(4)" ::: "memory");
    else                  asm volatile("s_waitcnt vmcnt(0)" ::: "memory");
    __builtin_amdgcn_s_barrier();
    asm volatile("" ::: "memory");

    const char* As_ = (const char*)&AB[s & 3][0][0];
    const char* Bs_ = (const char*)&AB[s & 3][1][0];
    bf8_t af[8], bfr[4];
#pragma unroll
    for (int i = 0; i < 8; ++i) af[i] = *(const bf8_t*)(As_ + aoff[i]);
#pragma unroll
    for (int j = 0; j < 4; ++j) bfr[j] = *(const bf8_t*)(Bs_ + boff[j]);

    if (s + 3 < NS) STAGE(s + 3);   // safe: slot (s+3)&3 last read in iter s-1

    __builtin_amdgcn_s_setprio(1);
#pragma unroll
    for (int i = 0; i < 8; ++i)
#pragma unroll
      for (int j = 0; j < 4; ++j)
        acc[i][j] = __builtin_amdgcn_mfma_f32_16x16x32_bf16(af[i], bfr[j], acc[i][j], 0, 0, 0);
    __builtin_amdgcn_s_setprio(0);
  }
#undef STAGE

#pragma unroll
  for (int i = 0; i < 8; ++i) {
#pragma unroll
    for (int j = 0; j < 4; ++j) {
#pragma unroll
      for (int r = 0; r < 4; ++r) {
        int row = bm + wr * 128 + i * 16 + qr0 + r;
        int col = bn + wc * 64 + j * 16 + rsel;
        float v = acc[i][j][r];
        if (EPI == 0) {
          Cf[(size_t)row * N + col] = v;
        } else {
          int c = col >> 11, h = (col >> 7) & (H_ - 1), dh = col & (DH_ - 1);
          int b = row >> 11, s = row & (S_ - 1);
          size_t dst = ((((size_t)c * B_ + b) * H_ + h) * S_ + s) * DH_ + dh;
          Cb[dst] = f2bf(v);
        }
      }
    }
  }
}

// ---------------- RoPE tables ----------------
__global__ void rope_tab(float* __restrict__ tc, float* __restrict__ ts) {
  int s = blockIdx.x;
  int i = threadIdx.x;   // 64 threads
  float inv = powf(10000.0f, -(float)i / 64.0f);
  float f   = (float)s * inv;
  tc[s * 64 + i] = cosf(f);
  ts[s * 64 + i] = sinf(f);
}

// ---------------- RoPE apply in-place on K only, bf16x8 vectorized ----------
// (Q-RoPE is fused into the attn prologue: pair (dh, dh+64) = (aq[kc], aq[kc+2])
//  lives in the same lane, so rotation is register-local there.)
__global__ __launch_bounds__(256) void rope_k(
    unsigned short* __restrict__ Kk,
    const float* __restrict__ tc, const float* __restrict__ ts) {
  int idx = blockIdx.x * 256 + threadIdx.x;   // 2^20 total
  int iv  = idx & 7;                          // 8-wide chunk within dh[0,64)
  int s   = (idx >> 3) & (S_ - 1);
  int bh  = idx >> 14;                        // 0..63
  size_t base = ((size_t)bh * S_ + s) * DH_;
  int i0 = iv * 8;
  bf8_t x1 = *(const bf8_t*)&Kk[base + i0];
  bf8_t x2 = *(const bf8_t*)&Kk[base + i0 + 64];
  const float* tcp = tc + s * 64 + i0;
  const float* tsp = ts + s * 64 + i0;
  bf8_t y1, y2;
#pragma unroll
  for (int e = 0; e < 8; ++e) {
    float c = tcp[e], sn = tsp[e];
    float a = bf2f((unsigned short)x1[e]);
    float b = bf2f((unsigned short)x2[e]);
    y1[e] = (short)f2bf(a * c - b * sn);
    y2[e] = (short)f2bf(b * c + a * sn);
  }
  *(bf8_t*)&Kk[base + i0]      = y1;
  *(bf8_t*)&Kk[base + i0 + 64] = y2;
}

// ---------------- causal flash attention ----------------
// grid 512 blocks (8 q-chunks x B*H), 512 thr = 8 waves x 32 q-rows (QBLK=256).
// Q-RoPE fused into the prologue (register-local pair rotation + sl2 scale).
// K: 3-slot ring, counted vmcnt (never 0 steady); V: reg-staged 1-deep.
// XCD swizzle keeps all 8 chunks of a bh on one XCD (KV L2-resident).
__global__ __launch_bounds__(512) void attn_fwd(
    const unsigned short* __restrict__ Q, const unsigned short* __restrict__ Kk,
    const unsigned short* __restrict__ V, unsigned short* __restrict__ Z,
    const float* __restrict__ tabc, const float* __restrict__ tabs) {
  __shared__ unsigned short Ks[3][64 * 128];  // 48 KB ring, XOR-swizzled (src-side)
  __shared__ unsigned short Vt[2][128 * 64];  // 32 KB, [dh][kv], XOR-swizzled
  __shared__ unsigned short Pw[8][32 * 64];   // 32 KB, per-wave 32 rows, swizzled
  const int tid  = threadIdx.x;
  const int lane = tid & 63;
  const int wv   = tid >> 6;                  // 0..7

  // XCD swizzle: id&7 = XCD stream; within it, 8 bh x 8 chunks, chunk-major.
  int id  = blockIdx.y * gridDim.x + blockIdx.x;   // nwg = 512
  int x   = id & 7;
  int idx = id >> 3;                               // 0..63
  const int bh = x * 8 + (idx & 7);
  const int q0 = (7 - (idx >> 3)) * 256;

  const size_t base = (size_t)bh * S_ * DH_;
  const int rsel = lane & 15;
  const int g    = lane >> 4;
  const int kof  = g * 8;
  const int qr0  = g * 4;
  const int qlo  = q0 + wv * 32;
  const int qhi  = qlo + 31;
  const float sl2 = 0.08838834764831845f * 1.4426950408889634f;  // scale*log2(e)

  // Q A-frags for both row-groups: load raw, apply RoPE in-register
  // (pair (dh, dh+64) = (aq[kc][e], aq[kc+2][e]), dh = kc*32+kof+e), fold sl2.
  bf8_t aq[2][4];
#pragma unroll
  for (int rg = 0; rg < 2; ++rg) {
    const int qrow = qlo + rg * 16 + rsel;
#pragma unroll
    for (int kc = 0; kc < 4; ++kc)
      aq[rg][kc] = *(const bf8_t*)&Q[base + (size_t)qrow * DH_ + kc * 32 + kof];
    const float* tcr = tabc + (size_t)qrow * 64;
    const float* tsr = tabs + (size_t)qrow * 64;
#pragma unroll
    for (int kc = 0; kc < 2; ++kc)
#pragma unroll
      for (int e = 0; e < 8; ++e) {
        int i = kc * 32 + kof + e;   // dh in [0,64)
        float c  = tcr[i], sn = tsr[i];
        float x1 = bf2f((unsigned short)aq[rg][kc][e]);
        float x2 = bf2f((unsigned short)aq[rg][kc + 2][e]);
        aq[rg][kc][e]     = (short)f2bf((x1 * c - x2 * sn) * sl2);
        aq[rg][kc + 2][e] = (short)f2bf((x2 * c + x1 * sn) * sl2);
      }
  }

  bf8_t vones;
#pragma unroll
  for (int e = 0; e < 8; ++e) vones[e] = (short)0x3F80;

  f4_t o[2][9];   // [rg][0..7]=output frags, [rg][8]=row-sum (denominator)
#pragma unroll
  for (int rg = 0; rg < 2; ++rg)
#pragma unroll
    for (int nf = 0; nf < 9; ++nf) o[rg][nf] = (f4_t){0.f, 0.f, 0.f, 0.f};
  float mrow[2][4] = {{-3e30f, -3e30f, -3e30f, -3e30f},
                      {-3e30f, -3e30f, -3e30f, -3e30f}};
  const int nt = q0 / 64 + 4;   // kv tiles cover [0, q0+256); nt >= 4

  // V staging: one unit/thread: kv rows {2*kvp, 2*kvp+1} x dh [vc0, vc0+8)
  const int kvp = tid & 31;
  const int vc0 = (tid >> 5) * 8;

#define KSTAGE(tt)                                                            \
  {                                                                           \
    const unsigned short* gK_ = Kk + base + (size_t)(tt) * 64 * DH_;          \
    int slot_ = (tt) % 3;                                                     \
    _Pragma("unroll")                                                         \
    for (int c = 0; c < 2; ++c) {                                             \
      int ob = (c * 512 + tid) * 16;                                          \
      int row = ob >> 8;                                                      \
      int scol = (ob & 255) ^ ((row & 7) << 4);                               \
      gload_lds16(gK_ + (size_t)row * DH_ + (scol >> 1),                      \
                  (char*)&Ks[slot_][0] + ob);                                 \
    }                                                                         \
  }
#define VTWRITE(buf_)                                                         \
  {                                                                           \
    unsigned int* Vt32 = (unsigned int*)&Vt[buf_][0];                         \
    _Pragma("unroll")                                                         \
    for (int e = 0; e < 8; ++e) {                                             \
      unsigned int val = (unsigned short)vlo[e] |                             \
                         ((unsigned int)(unsigned short)vhi[e] << 16);        \
      Vt32[(vc0 + e) * 32 + (kvp ^ (e << 2))] = val;                          \
    }                                                                         \
  }

  // ---- prologue: V(0) regs FIRST, then K(0)->slot0, K(1)->slot1 ----
  bf8_t vlo, vhi;
  vlo = *(const bf8_t*)&V[base + (size_t)(2 * kvp) * DH_ + vc0];
  vhi = *(const bf8_t*)&V[base + (size_t)(2 * kvp + 1) * DH_ + vc0];
  KSTAGE(0);
  KSTAGE(1);              // nt >= 4 always
  VTWRITE(0);             // compiler waits V(0) only; K loads stay in flight

  for (int t = 0; t < nt; ++t) {
    const int curV = t & 1;
    const int curK = t % 3;
    const bool pfV = (t + 1 < nt);
    const bool pfK = (t + 2 < nt);

    // ---- top: counted drain (K(t) landed; K(t+1) stays in flight), sync ----
    if (pfV) asm volatile("s_waitcnt vmcnt(2)" ::: "memory");
    else     asm volatile("s_waitcnt vmcnt(0)" ::: "memory");
    asm volatile("s_waitcnt lgkmcnt(0)" ::: "memory");
    __builtin_amdgcn_s_barrier();
    asm volatile("" ::: "memory");

    // ---- issue next loads AFTER barrier (slot last read in iter t-1) ----
    if (pfV) {
      const unsigned short* gV = V + base + (size_t)(t + 1) * 64 * DH_;
      vlo = *(const bf8_t*)&gV[(size_t)(2 * kvp) * DH_ + vc0];
      vhi = *(const bf8_t*)&gV[(size_t)(2 * kvp + 1) * DH_ + vc0];
    }
    if (pfK) KSTAGE(t + 2);

    const int kv0 = t * 64;
    const bool active = (kv0 <= qhi);
    const bool domask = active && (kv0 + 63 > qlo);

    if (active) {
      // ---- S = Q K^T for both row-groups (bk shared) ----
      f4_t sacc[2][4];
#pragma unroll
      for (int rg = 0; rg < 2; ++rg)
#pragma unroll
        for (int cf = 0; cf < 4; ++cf) sacc[rg][cf] = (f4_t){0.f, 0.f, 0.f, 0.f};
      __builtin_amdgcn_s_setprio(1);
#pragma unroll
      for (int cf = 0; cf < 4; ++cf)
#pragma unroll
        for (int kc = 0; kc < 4; ++kc) {
          int krow = cf * 16 + rsel;
          bf8_t bk = *(const bf8_t*)&Ks[curK][krow * 128 + ((kc * 32 + kof) ^ ((krow & 7) << 3))];
          sacc[0][cf] = __builtin_amdgcn_mfma_f32_16x16x32_bf16(aq[0][kc], bk, sacc[0][cf], 0, 0, 0);
          sacc[1][cf] = __builtin_amdgcn_mfma_f32_16x16x32_bf16(aq[1][kc], bk, sacc[1][cf], 0, 0, 0);
        }
      __builtin_amdgcn_s_setprio(0);

      if (domask) {
#pragma unroll
        for (int rg = 0; rg < 2; ++rg)
#pragma unroll
          for (int cf = 0; cf < 4; ++cf) {
            int kvabs = kv0 + cf * 16 + rsel;
#pragma unroll
            for (int r = 0; r < 4; ++r) {
              int qabs = qlo + rg * 16 + qr0 + r;
              if (kvabs > qabs) sacc[rg][cf][r] = -3e30f;
            }
          }
      }

      // ---- defer-max softmax: common path has NO cross-lane reduction ----
      float tmr[2][4];
      bool needr = false;
#pragma unroll
      for (int rg = 0; rg < 2; ++rg)
#pragma unroll
        for (int r = 0; r < 4; ++r) {
          tmr[rg][r] = fmaxf(fmaxf(sacc[rg][0][r], sacc[rg][1][r]),
                             fmaxf(sacc[rg][2][r], sacc[rg][3][r]));
          needr = needr || (tmr[rg][r] > mrow[rg][r] + 11.f);
        }
      if (__any(needr)) {
#pragma unroll
        for (int rg = 0; rg < 2; ++rg)
#pragma unroll
          for (int r = 0; r < 4; ++r) {
            float m = tmr[rg][r];
#pragma unroll
            for (int d = 1; d < 16; d <<= 1) m = fmaxf(m, __shfl_xor(m, d, 16));
            float nm = fmaxf(mrow[rg][r], m);
            float sc = exp2f(mrow[rg][r] - nm);
            mrow[rg][r] = nm;
#pragma unroll
            for (int nf = 0; nf < 9; ++nf) o[rg][nf][r] *= sc;
          }
      }
#pragma unroll
      for (int rg = 0; rg < 2; ++rg)
#pragma unroll
        for (int cf = 0; cf < 4; ++cf)
#pragma unroll
          for (int r = 0; r < 4; ++r)
            sacc[rg][cf][r] = exp2f(sacc[rg][cf][r] - mrow[rg][r]);

      // ---- P -> per-wave LDS (32 rows, swizzle (((prow>>1)&7)<<3)) ----
      unsigned short* P = &Pw[wv][0];
#pragma unroll
      for (int rg = 0; rg < 2; ++rg)
#pragma unroll
        for (int cf = 0; cf < 4; ++cf)
#pragma unroll
          for (int r = 0; r < 4; ++r) {
            int prow = rg * 16 + qr0 + r;
            P[prow * 64 + ((cf * 16 + rsel) ^ (((prow >> 1) & 7) << 3))] = f2bf(sacc[rg][cf][r]);
          }
    }

    // ---- write V(t+1) into Vt[nxt] (last read in iter t-1; barrier-safe) ----
    if (pfV) VTWRITE(curV ^ 1);

    if (active) {
      // ---- O += P V for both row-groups (bv shared); denom rides o[rg][8] ----
      unsigned short* P = &Pw[wv][0];
      __builtin_amdgcn_s_setprio(1);
#pragma unroll
      for (int kc2 = 0; kc2 < 2; ++kc2) {
        bf8_t pa0, pa1;
        {
          int pr0 = rsel;           // rg 0
          int pr1 = 16 + rsel;      // rg 1
          pa0 = *(const bf8_t*)&P[pr0 * 64 + ((kc2 * 32 + kof) ^ (((pr0 >> 1) & 7) << 3))];
          pa1 = *(const bf8_t*)&P[pr1 * 64 + ((kc2 * 32 + kof) ^ (((pr1 >> 1) & 7) << 3))];
        }
#pragma unroll
        for (int nf = 0; nf < 8; ++nf) {
          int vrow = nf * 16 + rsel;
          bf8_t bv = *(const bf8_t*)&Vt[curV][vrow * 64 + ((kc2 * 32 + kof) ^ ((vrow & 7) << 3))];
          o[0][nf] = __builtin_amdgcn_mfma_f32_16x16x32_bf16(pa0, bv, o[0][nf], 0, 0, 0);
          o[1][nf] = __builtin_amdgcn_mfma_f32_16x16x32_bf16(pa1, bv, o[1][nf], 0, 0, 0);
        }
        o[0][8] = __builtin_amdgcn_mfma_f32_16x16x32_bf16(pa0, vones, o[0][8], 0, 0, 0);
        o[1][8] = __builtin_amdgcn_mfma_f32_16x16x32_bf16(pa1, vones, o[1][8], 0, 0, 0);
      }
      __builtin_amdgcn_s_setprio(0);
    }
  }
#undef KSTAGE
#undef VTWRITE

  const int b = bh >> 4, h = bh & 15;
#pragma unroll
  for (int rg = 0; rg < 2; ++rg)
#pragma unroll
    for (int r = 0; r < 4; ++r) {
      float inv = 1.0f / o[rg][8][r];
      int s = qlo + rg * 16 + qr0 + r;
      size_t rowo = ((size_t)b * S_ + s) * D_ + h * DH_;
#pragma unroll
      for (int nf = 0; nf < 8; ++nf)
        Z[rowo + nf * 16 + rsel] = f2bf(o[rg][nf][r] * inv);
    }
}

// ---------------- orchestration ----------------
extern "C" void kernel_launch(void* const* d_in, const int* in_sizes, int n_in,
                              void* d_out, int out_size, void* d_ws, size_t ws_size,
                              hipStream_t stream) {
  const float* x    = (const float*)d_in[0];
  const float* Wqkv = (const float*)d_in[1];
  const float* Wo   = (const float*)d_in[2];
  float* out = (float*)d_out;

  const size_t QKV_ELEMS = (size_t)B_ * H_ * S_ * DH_;
  char* w = (char*)d_ws;
  unsigned short* xb = (unsigned short*)w;   // x bf16; z aliases it later
  unsigned short* z  = xb;
  w += (size_t)8192 * 2048 * 2;
  unsigned short* wqkvb = (unsigned short*)w; w += (size_t)6144 * 2048 * 2;
  unsigned short* wob   = (unsigned short*)w; w += (size_t)2048 * 2048 * 2;
  unsigned short* qq = (unsigned short*)w;    w += QKV_ELEMS * 2;
  unsigned short* kk = (unsigned short*)w;    w += QKV_ELEMS * 2;
  unsigned short* vv = (unsigned short*)w;    w += QKV_ELEMS * 2;
  float* tabc = (float*)w; w += (size_t)S_ * 64 * 4;
  float* tabs = (float*)w; w += (size_t)S_ * 64 * 4;
  if ((size_t)(w - (char*)d_ws) > ws_size) return;

  conv_bf16<<<16384, 256, 0, stream>>>(x, xb, 8192 * 2048 / 4);
  conv_bf16<<<12288, 256, 0, stream>>>(Wqkv, wqkvb, 6144 * 2048 / 4);
  conv_bf16<<<4096, 256, 0, stream>>>(Wo, wob, 2048 * 2048 / 4);
  gemm256<1><<<dim3(24, 32), 512, 0, stream>>>(xb, wqkvb, nullptr, qq, 8192, 6144, 2048);
  rope_tab<<<2048, 64, 0, stream>>>(tabc, tabs);
  rope_k<<<4096, 256, 0, stream>>>(kk, tabc, tabs);
  attn_fwd<<<dim3(S_ / 256, B_ * H_), 512, 0, stream>>>(qq, kk, vv, z, tabc, tabs);
  gemm256<0><<<dim3(8, 32), 512, 0, stream>>>(z, wob, out, nullptr, 8192, 2048, 2048);
}